// Round 5
// baseline (178.287 us; speedup 1.0000x reference)
//
#include <hip/hip_runtime.h>
#include <hip/hip_bf16.h>

#define D_MODEL 256
#define LQ 4800
#define NB 2
#define MROWS (NB * LQ)       // 9600
#define LN_EPS 1e-5f

typedef unsigned int u32;
typedef unsigned short u16;
typedef __attribute__((ext_vector_type(8))) short bf16x8;
typedef __attribute__((ext_vector_type(4))) float f32x4;
typedef __attribute__((ext_vector_type(2))) __bf16 bf16x2v;

__device__ __forceinline__ float bf2f(u32 bits16) {
    return __uint_as_float(bits16 << 16);
}
__device__ __forceinline__ u16 f2bf(float f) {
    __hip_bfloat16 h = __float2bfloat16(f);
    return *reinterpret_cast<u16*>(&h);
}

// dot2 of two bf16 pairs (packed in u32) accumulating into f32.
__device__ __forceinline__ float dot2bf(u32 a, u32 b, float c) {
#if __has_builtin(__builtin_amdgcn_fdot2_f32_bf16)
    return __builtin_amdgcn_fdot2_f32_bf16(__builtin_bit_cast(bf16x2v, a),
                                           __builtin_bit_cast(bf16x2v, b), c, false);
#else
    c = fmaf(bf2f(a & 0xffff), bf2f(b & 0xffff), c);
    return fmaf(bf2f(a >> 16), bf2f(b >> 16), c);
#endif
}

// ---------------------------------------------------------------------------
// Fused prep: cast x & source to bf16; transpose+cast all weights.
// grid: [0,2400) cast x, [2400,4800) cast source, [4800,7360) weight tiles.
// Wqkvt is [768][256]: rows 0..255 Wq^T, 256..511 Wk^T, 512..767 Wv^T.
// ---------------------------------------------------------------------------
__global__ __launch_bounds__(256) void prep_kernel(
    const float* __restrict__ x, const float* __restrict__ source,
    const float* __restrict__ Wq, const float* __restrict__ Wk,
    const float* __restrict__ Wv, const float* __restrict__ Wm,
    const float* __restrict__ W1, const float* __restrict__ W2,
    u16* __restrict__ xb, u16* __restrict__ sb,
    u16* __restrict__ Wqkvt, u16* __restrict__ Wmt,
    u16* __restrict__ W1t, u16* __restrict__ W2t)
{
    __shared__ float tile[16][17];
    const int t = threadIdx.x;
    int bid = blockIdx.x;

    if (bid < 4800) {
        const float* src = bid < 2400 ? x : source;
        u16* dst = bid < 2400 ? xb : sb;
        int b = bid < 2400 ? bid : bid - 2400;
        int i = (b * 256 + t) * 4;
        float4 v = *reinterpret_cast<const float4*>(src + i);
        ushort4 o; o.x = f2bf(v.x); o.y = f2bf(v.y); o.z = f2bf(v.z); o.w = f2bf(v.w);
        *reinterpret_cast<ushort4*>(dst + i) = o;
        return;
    }
    int sub = bid - 4800;
    const float* W; u16* Wt; int Nd, ldt, rowoff;
    if      (sub < 256)  { W = Wq; Wt = Wqkvt; Nd = 256; ldt = 256; rowoff = 0;   }
    else if (sub < 512)  { W = Wk; Wt = Wqkvt; Nd = 256; ldt = 256; rowoff = 256; sub -= 256; }
    else if (sub < 768)  { W = Wv; Wt = Wqkvt; Nd = 256; ldt = 256; rowoff = 512; sub -= 512; }
    else if (sub < 1024) { W = Wm; Wt = Wmt;   Nd = 256; ldt = 256; rowoff = 0;   sub -= 768; }
    else if (sub < 2048) { W = W1; Wt = W1t;   Nd = 512; ldt = 512; rowoff = 0;   sub -= 1024; }
    else                 { W = W2; Wt = W2t;   Nd = 256; ldt = 512; rowoff = 0;   sub -= 2048; }
    int ntiles = Nd >> 4;
    int tn = sub % ntiles, tk = sub / ntiles;
    int tx = t & 15, ty = t >> 4;
    tile[ty][tx] = W[(size_t)(tk * 16 + ty) * Nd + tn * 16 + tx];
    __syncthreads();
    Wt[(size_t)(rowoff + tn * 16 + ty) * ldt + tk * 16 + tx] = f2bf(tile[tx][ty]);
}

// ---------------------------------------------------------------------------
// bf16 MFMA GEMM: C = act(A @ Bt^T). 128x128 tile, BK=32, 256 threads.
// splitK: A = concat(A0 cols<splitK, A1 cols>=splitK) along K.
// nsel:   blocks with n0>=nsel use A1 as the whole A (qkv fusion).
// flags: 1=relu, 2=bf16 out, 4=route output to 3 consecutive [M,256] buffers.
// ---------------------------------------------------------------------------
__global__ __launch_bounds__(256) void gemm_mfma_kernel(
    const u16* __restrict__ A0, int lda0,
    const u16* __restrict__ A1, int lda1, int splitK, int nsel,
    const u16* __restrict__ Bt, int ldb,
    void* __restrict__ Cout,
    int M, int N, int K, int flags)
{
    __shared__ __align__(16) u16 As[128 * 32];
    __shared__ __align__(16) u16 Bs[128 * 32];

    const int t  = threadIdx.x;
    const int l  = t & 63;
    const int w  = t >> 6;
    const int m0 = blockIdx.y * 128;
    const int n0 = blockIdx.x * 128;
    const int wr = w >> 1, wc = w & 1;

    if (nsel && n0 >= nsel) { A0 = A1; lda0 = lda1; }

    const int srow = l >> 2;
    const int sch  = (l & 3) ^ (srow & 3);

    f32x4 acc[4][4];
#pragma unroll
    for (int i = 0; i < 4; ++i)
#pragma unroll
        for (int j = 0; j < 4; ++j) acc[i][j] = (f32x4){0.f, 0.f, 0.f, 0.f};

    for (int k0 = 0; k0 < K; k0 += 32) {
        const u16* Ap; int kk, lda;
        if (splitK && k0 >= splitK) { Ap = A1; kk = k0 - splitK; lda = lda1; }
        else                        { Ap = A0; kk = k0;          lda = lda0; }

#pragma unroll
        for (int g = 0; g < 2; ++g) {
            int grp = w * 2 + g;
            int row = grp * 16 + srow;
            const u16* asrc = Ap + (size_t)(m0 + row) * lda + kk + sch * 8;
            u32* adst = (u32*)(As + grp * 512);
            __builtin_amdgcn_global_load_lds(
                (const __attribute__((address_space(1))) u32*)asrc,
                (__attribute__((address_space(3))) u32*)adst, 16, 0, 0);
            const u16* bsrc = Bt + (size_t)(n0 + row) * ldb + k0 + sch * 8;
            u32* bdst = (u32*)(Bs + grp * 512);
            __builtin_amdgcn_global_load_lds(
                (const __attribute__((address_space(1))) u32*)bsrc,
                (__attribute__((address_space(3))) u32*)bdst, 16, 0, 0);
        }
        __syncthreads();

        const int r  = l & 15;
        const int ch = l >> 4;
        bf16x8 af[4], bfr[4];
#pragma unroll
        for (int i = 0; i < 4; ++i) {
            int ar = wr * 64 + i * 16 + r;
            af[i] = *(const bf16x8*)((const char*)As + ar * 64 + ((ch ^ (r & 3)) * 16));
        }
#pragma unroll
        for (int j = 0; j < 4; ++j) {
            int br = wc * 64 + j * 16 + r;
            bfr[j] = *(const bf16x8*)((const char*)Bs + br * 64 + ((ch ^ (r & 3)) * 16));
        }
#pragma unroll
        for (int i = 0; i < 4; ++i)
#pragma unroll
            for (int j = 0; j < 4; ++j)
                acc[i][j] = __builtin_amdgcn_mfma_f32_16x16x32_bf16(af[i], bfr[j], acc[i][j], 0, 0, 0);
        __syncthreads();
    }

    const int r  = l & 15;
    const int q4 = l >> 4;
#pragma unroll
    for (int i = 0; i < 4; ++i)
#pragma unroll
        for (int j = 0; j < 4; ++j) {
            int col = n0 + wc * 64 + j * 16 + r;
#pragma unroll
            for (int reg = 0; reg < 4; ++reg) {
                int row = m0 + wr * 64 + i * 16 + q4 * 4 + reg;
                float vv = acc[i][j][reg];
                if (flags & 1) vv = fmaxf(vv, 0.f);
                size_t off;
                int colw, Nw;
                if (flags & 4) { off = (size_t)(col >> 8) * M * 256; colw = col & 255; Nw = 256; }
                else           { off = 0; colw = col; Nw = N; }
                if (flags & 2) ((u16*)Cout)[off + (size_t)row * Nw + colw] = f2bf(vv);
                else           ((float*)Cout)[off + (size_t)row * Nw + colw] = vv;
            }
        }
}

// ---------------------------------------------------------------------------
// Gathered attention, wave-per-(query, head-pair). NO cross-wave barriers.
// Block = 1 query (4 waves); wave w owns heads {2w, 2w+1} = dims [w*64, w*64+64).
// Lane = key for gather/scores/softmax (K in registers, Q replicated, dot2).
// PV: V staged in wave-private LDS with 16B-chunk XOR swizzle; lane = dim-pair.
// ---------------------------------------------------------------------------
__global__ __launch_bounds__(256) void attn_kernel(
    const u16* __restrict__ q, const u16* __restrict__ k,
    const u16* __restrict__ v, const int* __restrict__ idx,
    u16* __restrict__ msg)
{
    __shared__ u32   v_lds[4][2048];     // per-wave [64 keys][64 dims] bf16, swizzled
    __shared__ float p_lds[4][64][2];    // per-wave attn weights

    const int t  = threadIdx.x;
    const int l  = t & 63;
    const int w  = t >> 6;               // head-pair
    const int qi = blockIdx.x;
    const int n  = qi / LQ;

    const int row = idx[(size_t)qi * 64 + l];
    const u16* kp = k + ((size_t)n * LQ + row) * 256 + w * 64;
    const u16* vp = v + ((size_t)n * LQ + row) * 256 + w * 64;
    const u16* qp = q + (size_t)qi * 256 + w * 64;

    u32 kd[32], vd[32], qd[32];
#pragma unroll
    for (int u = 0; u < 8; ++u) {
        uint4 tk = ((const uint4*)kp)[u];
        kd[4*u] = tk.x; kd[4*u+1] = tk.y; kd[4*u+2] = tk.z; kd[4*u+3] = tk.w;
    }
#pragma unroll
    for (int u = 0; u < 8; ++u) {
        uint4 tv = ((const uint4*)vp)[u];
        vd[4*u] = tv.x; vd[4*u+1] = tv.y; vd[4*u+2] = tv.z; vd[4*u+3] = tv.w;
    }
#pragma unroll
    for (int u = 0; u < 8; ++u) {
        uint4 tq = ((const uint4*)qp)[u];
        qd[4*u] = tq.x; qd[4*u+1] = tq.y; qd[4*u+2] = tq.z; qd[4*u+3] = tq.w;
    }

    // ---- scores: lane l = key l; two heads ----
    float s0 = 0.f, s1 = 0.f;
#pragma unroll
    for (int j = 0; j < 16; ++j) s0 = dot2bf(kd[j], qd[j], s0);
#pragma unroll
    for (int j = 16; j < 32; ++j) s1 = dot2bf(kd[j], qd[j], s1);
    const float scale = 0.17677669529663687f;
    s0 *= scale; s1 *= scale;

    // ---- softmax across the 64 lanes (keys) ----
    float m0 = s0, m1 = s1;
#pragma unroll
    for (int off = 32; off; off >>= 1) {
        m0 = fmaxf(m0, __shfl_xor(m0, off));
        m1 = fmaxf(m1, __shfl_xor(m1, off));
    }
    float p0 = __expf(s0 - m0), p1 = __expf(s1 - m1);
    float t0 = p0, t1 = p1;
#pragma unroll
    for (int off = 32; off; off >>= 1) {
        t0 += __shfl_xor(t0, off);
        t1 += __shfl_xor(t1, off);
    }
    p0 /= t0; p1 /= t1;
    p_lds[w][l][0] = p0;
    p_lds[w][l][1] = p1;

    // ---- stage V: row l (128 B), 16B chunks XOR-swizzled by key ----
    {
        u32* vbase = v_lds[w] + l * 32;
#pragma unroll
        for (int u = 0; u < 8; ++u) {
            int c = u ^ (l & 7);
            *(uint4*)(vbase + c * 4) = make_uint4(vd[4*u], vd[4*u+1], vd[4*u+2], vd[4*u+3]);
        }
    }

    // ---- PV: lane covers dim-pair (2m, 2m+1); key-half kh; combine at end ----
    const int m  = l & 31;
    const int kh = l >> 5;
    const int hh = m >> 4;               // which head of the pair
    float a0 = 0.f, a1 = 0.f;
#pragma unroll
    for (int i = 0; i < 32; ++i) {
        int key = kh * 32 + i;
        float pw = p_lds[w][key][hh];
        int c = (m >> 2) ^ (key & 7);
        u32 vv = v_lds[w][key * 32 + c * 4 + (m & 3)];
        a0 = fmaf(pw, bf2f(vv & 0xffff), a0);
        a1 = fmaf(pw, bf2f(vv >> 16), a1);
    }
    a0 += __shfl_xor(a0, 32);
    a1 += __shfl_xor(a1, 32);
    if (l < 32) {
        u32 packed = (u32)f2bf(a0) | ((u32)f2bf(a1) << 16);
        *(u32*)(msg + (size_t)qi * 256 + w * 64 + 2 * m) = packed;
    }
}

// ---------------------------------------------------------------------------
// LayerNorm over last dim (256), fp32 input. One block per row.
// ---------------------------------------------------------------------------
__global__ __launch_bounds__(256) void ln_kernel(
    const float* __restrict__ in, const float* __restrict__ g,
    const float* __restrict__ b, const float* __restrict__ xadd,
    void* __restrict__ out, int out_bf16)
{
    __shared__ float red[8];
    const int t = threadIdx.x;
    const size_t row = blockIdx.x;
    float val = in[row * 256 + t];

    float s = val;
#pragma unroll
    for (int off = 32; off; off >>= 1) s += __shfl_down(s, off, 64);
    if ((t & 63) == 0) red[t >> 6] = s;
    __syncthreads();
    float mu = (red[0] + red[1] + red[2] + red[3]) * 0.00390625f;

    float dv = val - mu;
    float s2 = dv * dv;
#pragma unroll
    for (int off = 32; off; off >>= 1) s2 += __shfl_down(s2, off, 64);
    if ((t & 63) == 0) red[4 + (t >> 6)] = s2;
    __syncthreads();
    float var = (red[4] + red[5] + red[6] + red[7]) * 0.00390625f;
    float rstd = rsqrtf(var + LN_EPS);

    float r = dv * rstd * g[t] + b[t];
    if (xadd) r += xadd[row * 256 + t];
    if (out_bf16) ((u16*)out)[row * 256 + t] = f2bf(r);
    else          ((float*)out)[row * 256 + t] = r;
}

// ---------------------------------------------------------------------------
extern "C" void kernel_launch(void* const* d_in, const int* in_sizes, int n_in,
                              void* d_out, int out_size, void* d_ws, size_t ws_size,
                              hipStream_t stream)
{
    const float* x      = (const float*)d_in[0];
    const float* source = (const float*)d_in[1];
    const int*   eidx   = (const int*)d_in[2];
    const float* Wq     = (const float*)d_in[3];
    const float* Wk     = (const float*)d_in[4];
    const float* Wv     = (const float*)d_in[5];
    const float* Wm     = (const float*)d_in[6];
    const float* W1     = (const float*)d_in[7];
    const float* W2     = (const float*)d_in[8];
    const float* g1     = (const float*)d_in[9];
    const float* b1     = (const float*)d_in[10];
    const float* g2     = (const float*)d_in[11];
    const float* b2     = (const float*)d_in[12];
    float* out = (float*)d_out;

    char* ws = (char*)d_ws;
    const size_t SZB = (size_t)MROWS * 256 * 2;    // 4.9 MB
    u16* xb     = (u16*)(ws);                      // live until W1 gemm
    u16* sb     = (u16*)(ws + SZB);                // dead after qkv gemm
    u16* qb     = (u16*)(ws + 2 * SZB);            // qkv gemm routes here (seg 0)
    u16* kb     = (u16*)(ws + 3 * SZB);            // seg 1
    u16* vb     = (u16*)(ws + 4 * SZB);            // seg 2
    u16* msgb   = (u16*)(ws + 5 * SZB);            // dead after Wm gemm
    float* msgW = (float*)(ws + SZB);              // overlays sb+qb (dead)
    u16* msglnb = (u16*)(ws + 3 * SZB);            // overlays kb (dead)
    u16* h1b    = (u16*)(ws + 4 * SZB);            // [9600][512] overlays vb+msgb
    float* h2   = (float*)(ws + SZB);              // overlays msgW (dead)
    u16* Wqkvt  = (u16*)(ws + 6 * SZB);            // [768][256]
    u16* Wmt    = Wqkvt + 768 * 256;
    u16* W1t    = Wmt + 256 * 256;                 // [512][512]
    u16* W2t    = W1t + 512 * 512;                 // [256][512]

    dim3 blk(256);

    // fused prep: casts + all weight transposes
    prep_kernel<<<dim3(7360), blk, 0, stream>>>(x, source, Wq, Wk, Wv, Wm, W1, W2,
                                                xb, sb, Wqkvt, Wmt, W1t, W2t);

    // fused q|k|v projection (A = xb for cols<256, sb for cols>=256)
    gemm_mfma_kernel<<<dim3(6, 75), blk, 0, stream>>>(xb, 256, sb, 256, 0, 256,
                                                      Wqkvt, 256, qb, MROWS, 768, 256, 2 | 4);

    // gathered attention -> msg (bf16)
    attn_kernel<<<dim3(MROWS), blk, 0, stream>>>(qb, kb, vb, eidx, msgb);

    // msg @ Wm -> fp32
    gemm_mfma_kernel<<<dim3(2, 75), blk, 0, stream>>>(msgb, 256, nullptr, 0, 0, 0,
                                                      Wmt, 256, msgW, MROWS, 256, 256, 0);

    // LN1 -> bf16
    ln_kernel<<<dim3(MROWS), blk, 0, stream>>>(msgW, g1, b1, nullptr, msglnb, 1);

    // concat(x, msgln) @ W1, relu -> bf16 [9600,512]
    gemm_mfma_kernel<<<dim3(4, 75), blk, 0, stream>>>(xb, 256, msglnb, 256, 256, 0,
                                                      W1t, 512, h1b, MROWS, 512, 512, 1 | 2);

    // h1 @ W2 -> fp32
    gemm_mfma_kernel<<<dim3(2, 75), blk, 0, stream>>>(h1b, 512, nullptr, 0, 0, 0,
                                                      W2t, 512, h2, MROWS, 256, 512, 0);

    // out = x + LN2(h2)
    ln_kernel<<<dim3(MROWS), blk, 0, stream>>>(h2, g2, b2, x, out, 0);
}

// Round 6
// 163.255 us; speedup vs baseline: 1.0921x; 1.0921x over previous
//
#include <hip/hip_runtime.h>
#include <hip/hip_bf16.h>

#define D_MODEL 256
#define LQ 4800
#define NB 2
#define MROWS (NB * LQ)       // 9600
#define LN_EPS 1e-5f

typedef unsigned int u32;
typedef unsigned short u16;
typedef __attribute__((ext_vector_type(8))) short bf16x8;
typedef __attribute__((ext_vector_type(4))) float f32x4;
typedef __attribute__((ext_vector_type(2))) __bf16 bf16x2v;

__device__ __forceinline__ float bf2f(u32 bits16) {
    return __uint_as_float(bits16 << 16);
}
__device__ __forceinline__ u16 f2bf(float f) {
    __hip_bfloat16 h = __float2bfloat16(f);
    return *reinterpret_cast<u16*>(&h);
}

// dot2 of two bf16 pairs (packed in u32) accumulating into f32.
__device__ __forceinline__ float dot2bf(u32 a, u32 b, float c) {
#if __has_builtin(__builtin_amdgcn_fdot2_f32_bf16)
    return __builtin_amdgcn_fdot2_f32_bf16(__builtin_bit_cast(bf16x2v, a),
                                           __builtin_bit_cast(bf16x2v, b), c, false);
#else
    c = fmaf(bf2f(a & 0xffff), bf2f(b & 0xffff), c);
    return fmaf(bf2f(a >> 16), bf2f(b >> 16), c);
#endif
}

// ---------------------------------------------------------------------------
// Fused prep: cast x & source to bf16; transpose+cast all weights.
// grid: [0,2400) cast x, [2400,4800) cast source, [4800,7360) weight tiles.
// Wqkvt is [768][256]: rows 0..255 Wq^T, 256..511 Wk^T, 512..767 Wv^T.
// ---------------------------------------------------------------------------
__global__ __launch_bounds__(256) void prep_kernel(
    const float* __restrict__ x, const float* __restrict__ source,
    const float* __restrict__ Wq, const float* __restrict__ Wk,
    const float* __restrict__ Wv, const float* __restrict__ Wm,
    const float* __restrict__ W1, const float* __restrict__ W2,
    u16* __restrict__ xb, u16* __restrict__ sb,
    u16* __restrict__ Wqkvt, u16* __restrict__ Wmt,
    u16* __restrict__ W1t, u16* __restrict__ W2t)
{
    __shared__ float tile[16][17];
    const int t = threadIdx.x;
    int bid = blockIdx.x;

    if (bid < 4800) {
        const float* src = bid < 2400 ? x : source;
        u16* dst = bid < 2400 ? xb : sb;
        int b = bid < 2400 ? bid : bid - 2400;
        int i = (b * 256 + t) * 4;
        float4 v = *reinterpret_cast<const float4*>(src + i);
        ushort4 o; o.x = f2bf(v.x); o.y = f2bf(v.y); o.z = f2bf(v.z); o.w = f2bf(v.w);
        *reinterpret_cast<ushort4*>(dst + i) = o;
        return;
    }
    int sub = bid - 4800;
    const float* W; u16* Wt; int Nd, ldt, rowoff;
    if      (sub < 256)  { W = Wq; Wt = Wqkvt; Nd = 256; ldt = 256; rowoff = 0;   }
    else if (sub < 512)  { W = Wk; Wt = Wqkvt; Nd = 256; ldt = 256; rowoff = 256; sub -= 256; }
    else if (sub < 768)  { W = Wv; Wt = Wqkvt; Nd = 256; ldt = 256; rowoff = 512; sub -= 512; }
    else if (sub < 1024) { W = Wm; Wt = Wmt;   Nd = 256; ldt = 256; rowoff = 0;   sub -= 768; }
    else if (sub < 2048) { W = W1; Wt = W1t;   Nd = 512; ldt = 512; rowoff = 0;   sub -= 1024; }
    else                 { W = W2; Wt = W2t;   Nd = 256; ldt = 512; rowoff = 0;   sub -= 2048; }
    int ntiles = Nd >> 4;
    int tn = sub % ntiles, tk = sub / ntiles;
    int tx = t & 15, ty = t >> 4;
    tile[ty][tx] = W[(size_t)(tk * 16 + ty) * Nd + tn * 16 + tx];
    __syncthreads();
    Wt[(size_t)(rowoff + tn * 16 + ty) * ldt + tk * 16 + tx] = f2bf(tile[tx][ty]);
}

// ---------------------------------------------------------------------------
// bf16 MFMA GEMM: C = act(A @ Bt^T). 128x128 tile, BK=32, 256 threads.
// splitK: A = concat(A0 cols<splitK, A1 cols>=splitK) along K.
// nsel:   blocks with n0>=nsel use A1 as the whole A (qkv fusion).
// flags: 1=relu, 2=bf16 out, 4=route output to 3 consecutive [M,256] buffers.
// ---------------------------------------------------------------------------
__global__ __launch_bounds__(256) void gemm_mfma_kernel(
    const u16* __restrict__ A0, int lda0,
    const u16* __restrict__ A1, int lda1, int splitK, int nsel,
    const u16* __restrict__ Bt, int ldb,
    void* __restrict__ Cout,
    int M, int N, int K, int flags)
{
    __shared__ __align__(16) u16 As[128 * 32];
    __shared__ __align__(16) u16 Bs[128 * 32];

    const int t  = threadIdx.x;
    const int l  = t & 63;
    const int w  = t >> 6;
    const int m0 = blockIdx.y * 128;
    const int n0 = blockIdx.x * 128;
    const int wr = w >> 1, wc = w & 1;

    if (nsel && n0 >= nsel) { A0 = A1; lda0 = lda1; }

    const int srow = l >> 2;
    const int sch  = (l & 3) ^ (srow & 3);

    f32x4 acc[4][4];
#pragma unroll
    for (int i = 0; i < 4; ++i)
#pragma unroll
        for (int j = 0; j < 4; ++j) acc[i][j] = (f32x4){0.f, 0.f, 0.f, 0.f};

    for (int k0 = 0; k0 < K; k0 += 32) {
        const u16* Ap; int kk, lda;
        if (splitK && k0 >= splitK) { Ap = A1; kk = k0 - splitK; lda = lda1; }
        else                        { Ap = A0; kk = k0;          lda = lda0; }

#pragma unroll
        for (int g = 0; g < 2; ++g) {
            int grp = w * 2 + g;
            int row = grp * 16 + srow;
            const u16* asrc = Ap + (size_t)(m0 + row) * lda + kk + sch * 8;
            u32* adst = (u32*)(As + grp * 512);
            __builtin_amdgcn_global_load_lds(
                (const __attribute__((address_space(1))) u32*)asrc,
                (__attribute__((address_space(3))) u32*)adst, 16, 0, 0);
            const u16* bsrc = Bt + (size_t)(n0 + row) * ldb + k0 + sch * 8;
            u32* bdst = (u32*)(Bs + grp * 512);
            __builtin_amdgcn_global_load_lds(
                (const __attribute__((address_space(1))) u32*)bsrc,
                (__attribute__((address_space(3))) u32*)bdst, 16, 0, 0);
        }
        __syncthreads();

        const int r  = l & 15;
        const int ch = l >> 4;
        bf16x8 af[4], bfr[4];
#pragma unroll
        for (int i = 0; i < 4; ++i) {
            int ar = wr * 64 + i * 16 + r;
            af[i] = *(const bf16x8*)((const char*)As + ar * 64 + ((ch ^ (r & 3)) * 16));
        }
#pragma unroll
        for (int j = 0; j < 4; ++j) {
            int br = wc * 64 + j * 16 + r;
            bfr[j] = *(const bf16x8*)((const char*)Bs + br * 64 + ((ch ^ (r & 3)) * 16));
        }
#pragma unroll
        for (int i = 0; i < 4; ++i)
#pragma unroll
            for (int j = 0; j < 4; ++j)
                acc[i][j] = __builtin_amdgcn_mfma_f32_16x16x32_bf16(af[i], bfr[j], acc[i][j], 0, 0, 0);
        __syncthreads();
    }

    const int r  = l & 15;
    const int q4 = l >> 4;
#pragma unroll
    for (int i = 0; i < 4; ++i)
#pragma unroll
        for (int j = 0; j < 4; ++j) {
            int col = n0 + wc * 64 + j * 16 + r;
#pragma unroll
            for (int reg = 0; reg < 4; ++reg) {
                int row = m0 + wr * 64 + i * 16 + q4 * 4 + reg;
                float vv = acc[i][j][reg];
                if (flags & 1) vv = fmaxf(vv, 0.f);
                size_t off;
                int colw, Nw;
                if (flags & 4) { off = (size_t)(col >> 8) * M * 256; colw = col & 255; Nw = 256; }
                else           { off = 0; colw = col; Nw = N; }
                if (flags & 2) ((u16*)Cout)[off + (size_t)row * Nw + colw] = f2bf(vv);
                else           ((float*)Cout)[off + (size_t)row * Nw + colw] = vv;
            }
        }
}

// ---------------------------------------------------------------------------
// Gathered attention, wave-per-(query, head). NO barriers, no spills.
// grid = 2*MROWS blocks of 256: block covers query qi = bid>>1,
// heads (bid&1)*4 + wave. Lane = key for gather/scores/softmax (K slice in
// 16 VGPRs, Q broadcast in 16 VGPRs, dot2). V is gathered straight into
// wave-private LDS via global_load_lds (zero register cost), consumed by PV
// after an explicit vmcnt wait. LDS reads are broadcast or 2-way (free).
// ---------------------------------------------------------------------------
__global__ __launch_bounds__(256) void attn_kernel(
    const u16* __restrict__ q, const u16* __restrict__ k,
    const u16* __restrict__ v, const int* __restrict__ idx,
    u16* __restrict__ msg)
{
    __shared__ u32   v_lds[4][1024];   // per-wave [64 keys][16 u32 = 32 dims]
    __shared__ float p_lds[4][64];     // per-wave attn weights

    const int t    = threadIdx.x;
    const int l    = t & 63;
    const int w    = t >> 6;
    const int qi   = blockIdx.x >> 1;
    const int head = ((blockIdx.x & 1) << 2) | w;
    const int n    = qi / LQ;
    const size_t srcbase = (size_t)n * LQ * 256;    // u16 units

    const int* idxp = idx + (size_t)qi * 64;

    // ---- issue V gather -> wave-private LDS first (latency hides below) ----
    {
        const int sub   = l >> 2;   // key-within-group 0..15
        const int chunk = l & 3;    // 16B chunk of the 64B head slice
#pragma unroll
        for (int u = 0; u < 4; ++u) {
            int row = idxp[u * 16 + sub];
            const u16* src = v + srcbase + (size_t)row * 256 + head * 32 + chunk * 8;
            u32* dst = (u32*)&v_lds[w][u * 256];    // wave-uniform base
            __builtin_amdgcn_global_load_lds(
                (const __attribute__((address_space(1))) u32*)src,
                (__attribute__((address_space(3))) u32*)dst, 16, 0, 0);
        }
    }

    // ---- K slice for this lane's key; Q slice (one cache line, broadcast) ----
    const int myrow = idxp[l];
    u32 kd[16], qd[16];
    {
        const uint4* kp = (const uint4*)(k + srcbase + (size_t)myrow * 256 + head * 32);
        const uint4* qp = (const uint4*)(q + (size_t)qi * 256 + head * 32);
#pragma unroll
        for (int u = 0; u < 4; ++u) {
            uint4 tk = kp[u];
            kd[4*u] = tk.x; kd[4*u+1] = tk.y; kd[4*u+2] = tk.z; kd[4*u+3] = tk.w;
            uint4 tq = qp[u];
            qd[4*u] = tq.x; qd[4*u+1] = tq.y; qd[4*u+2] = tq.z; qd[4*u+3] = tq.w;
        }
    }

    // ---- score (lane = key) ----
    float s = 0.f;
#pragma unroll
    for (int j = 0; j < 16; ++j) s = dot2bf(kd[j], qd[j], s);
    s *= 0.17677669529663687f;

    // ---- softmax across 64 lanes (keys) ----
    float mm = s;
#pragma unroll
    for (int off = 32; off; off >>= 1) mm = fmaxf(mm, __shfl_xor(mm, off));
    float p = __expf(s - mm);
    float sum = p;
#pragma unroll
    for (int off = 32; off; off >>= 1) sum += __shfl_xor(sum, off);
    p_lds[w][l] = p / sum;

    // ---- V staged? (intra-wave wait; no barrier needed) ----
    asm volatile("s_waitcnt vmcnt(0)" ::: "memory");

    // ---- PV: lane = (dim-pair m, key-group ks); 16 keys per lane ----
    const int m  = l & 15;
    const int ks = l >> 4;
    float a0 = 0.f, a1 = 0.f;
#pragma unroll
    for (int i = 0; i < 16; ++i) {
        int key = i * 4 + ks;
        float pw = p_lds[w][key];          // 4 addrs/wave -> broadcast, free
        u32 vv = v_lds[w][key * 16 + m];   // 2-way bank alias -> free
        a0 = fmaf(pw, bf2f(vv & 0xffff), a0);
        a1 = fmaf(pw, bf2f(vv >> 16),    a1);
    }
    a0 += __shfl_xor(a0, 16); a0 += __shfl_xor(a0, 32);
    a1 += __shfl_xor(a1, 16); a1 += __shfl_xor(a1, 32);
    if (ks == 0) {
        u32 packed = (u32)f2bf(a0) | ((u32)f2bf(a1) << 16);
        *(u32*)(msg + (size_t)qi * 256 + head * 32 + 2 * m) = packed;
    }
}

// ---------------------------------------------------------------------------
// LayerNorm over last dim (256), fp32 input. One block per row.
// ---------------------------------------------------------------------------
__global__ __launch_bounds__(256) void ln_kernel(
    const float* __restrict__ in, const float* __restrict__ g,
    const float* __restrict__ b, const float* __restrict__ xadd,
    void* __restrict__ out, int out_bf16)
{
    __shared__ float red[8];
    const int t = threadIdx.x;
    const size_t row = blockIdx.x;
    float val = in[row * 256 + t];

    float s = val;
#pragma unroll
    for (int off = 32; off; off >>= 1) s += __shfl_down(s, off, 64);
    if ((t & 63) == 0) red[t >> 6] = s;
    __syncthreads();
    float mu = (red[0] + red[1] + red[2] + red[3]) * 0.00390625f;

    float dv = val - mu;
    float s2 = dv * dv;
#pragma unroll
    for (int off = 32; off; off >>= 1) s2 += __shfl_down(s2, off, 64);
    if ((t & 63) == 0) red[4 + (t >> 6)] = s2;
    __syncthreads();
    float var = (red[4] + red[5] + red[6] + red[7]) * 0.00390625f;
    float rstd = rsqrtf(var + LN_EPS);

    float r = dv * rstd * g[t] + b[t];
    if (xadd) r += xadd[row * 256 + t];
    if (out_bf16) ((u16*)out)[row * 256 + t] = f2bf(r);
    else          ((float*)out)[row * 256 + t] = r;
}

// ---------------------------------------------------------------------------
extern "C" void kernel_launch(void* const* d_in, const int* in_sizes, int n_in,
                              void* d_out, int out_size, void* d_ws, size_t ws_size,
                              hipStream_t stream)
{
    const float* x      = (const float*)d_in[0];
    const float* source = (const float*)d_in[1];
    const int*   eidx   = (const int*)d_in[2];
    const float* Wq     = (const float*)d_in[3];
    const float* Wk     = (const float*)d_in[4];
    const float* Wv     = (const float*)d_in[5];
    const float* Wm     = (const float*)d_in[6];
    const float* W1     = (const float*)d_in[7];
    const float* W2     = (const float*)d_in[8];
    const float* g1     = (const float*)d_in[9];
    const float* b1     = (const float*)d_in[10];
    const float* g2     = (const float*)d_in[11];
    const float* b2     = (const float*)d_in[12];
    float* out = (float*)d_out;

    char* ws = (char*)d_ws;
    const size_t SZB = (size_t)MROWS * 256 * 2;    // 4.9 MB
    u16* xb     = (u16*)(ws);                      // live until W1 gemm
    u16* sb     = (u16*)(ws + SZB);                // dead after qkv gemm
    u16* qb     = (u16*)(ws + 2 * SZB);            // qkv gemm routes here (seg 0)
    u16* kb     = (u16*)(ws + 3 * SZB);            // seg 1
    u16* vb     = (u16*)(ws + 4 * SZB);            // seg 2
    u16* msgb   = (u16*)(ws + 5 * SZB);            // dead after Wm gemm
    float* msgW = (float*)(ws + SZB);              // overlays sb+qb (dead)
    u16* msglnb = (u16*)(ws + 3 * SZB);            // overlays kb (dead)
    u16* h1b    = (u16*)(ws + 4 * SZB);            // [9600][512] overlays vb+msgb
    float* h2   = (float*)(ws + SZB);              // overlays msgW (dead)
    u16* Wqkvt  = (u16*)(ws + 6 * SZB);            // [768][256]
    u16* Wmt    = Wqkvt + 768 * 256;
    u16* W1t    = Wmt + 256 * 256;                 // [512][512]
    u16* W2t    = W1t + 512 * 512;                 // [256][512]

    dim3 blk(256);

    // fused prep: casts + all weight transposes
    prep_kernel<<<dim3(7360), blk, 0, stream>>>(x, source, Wq, Wk, Wv, Wm, W1, W2,
                                                xb, sb, Wqkvt, Wmt, W1t, W2t);

    // fused q|k|v projection (A = xb for cols<256, sb for cols>=256)
    gemm_mfma_kernel<<<dim3(6, 75), blk, 0, stream>>>(xb, 256, sb, 256, 0, 256,
                                                      Wqkvt, 256, qb, MROWS, 768, 256, 2 | 4);

    // gathered attention -> msg (bf16); 2 blocks per query (4 heads each)
    attn_kernel<<<dim3(2 * MROWS), blk, 0, stream>>>(qb, kb, vb, eidx, msgb);

    // msg @ Wm -> fp32
    gemm_mfma_kernel<<<dim3(2, 75), blk, 0, stream>>>(msgb, 256, nullptr, 0, 0, 0,
                                                      Wmt, 256, msgW, MROWS, 256, 256, 0);

    // LN1 -> bf16
    ln_kernel<<<dim3(MROWS), blk, 0, stream>>>(msgW, g1, b1, nullptr, msglnb, 1);

    // concat(x, msgln) @ W1, relu -> bf16 [9600,512]
    gemm_mfma_kernel<<<dim3(4, 75), blk, 0, stream>>>(xb, 256, msglnb, 256, 256, 0,
                                                      W1t, 512, h1b, MROWS, 512, 512, 1 | 2);

    // h1 @ W2 -> fp32
    gemm_mfma_kernel<<<dim3(2, 75), blk, 0, stream>>>(h1b, 512, nullptr, 0, 0, 0,
                                                      W2t, 512, h2, MROWS, 256, 512, 0);

    // out = x + LN2(h2)
    ln_kernel<<<dim3(MROWS), blk, 0, stream>>>(h2, g2, b2, x, out, 0);
}

// Round 7
// 140.631 us; speedup vs baseline: 1.2678x; 1.1609x over previous
//
#include <hip/hip_runtime.h>
#include <hip/hip_bf16.h>

#define D_MODEL 256
#define LQ 4800
#define NB 2
#define MROWS (NB * LQ)       // 9600
#define LN_EPS 1e-5f

typedef unsigned int u32;
typedef unsigned short u16;
typedef __attribute__((ext_vector_type(8))) short bf16x8;
typedef __attribute__((ext_vector_type(4))) float f32x4;
typedef __attribute__((ext_vector_type(2))) __bf16 bf16x2v;

__device__ __forceinline__ float bf2f(u32 bits16) {
    return __uint_as_float(bits16 << 16);
}
__device__ __forceinline__ float bf2f_lo(u32 v) { return __uint_as_float(v << 16); }
__device__ __forceinline__ float bf2f_hi(u32 v) { return __uint_as_float(v & 0xffff0000u); }
__device__ __forceinline__ u16 f2bf(float f) {
    __hip_bfloat16 h = __float2bfloat16(f);
    return *reinterpret_cast<u16*>(&h);
}

// dot2 of two bf16 pairs (packed in u32) accumulating into f32.
__device__ __forceinline__ float dot2bf(u32 a, u32 b, float c) {
#if __has_builtin(__builtin_amdgcn_fdot2_f32_bf16)
    return __builtin_amdgcn_fdot2_f32_bf16(__builtin_bit_cast(bf16x2v, a),
                                           __builtin_bit_cast(bf16x2v, b), c, false);
#else
    c = fmaf(bf2f_lo(a), bf2f_lo(b), c);
    return fmaf(bf2f_hi(a), bf2f_hi(b), c);
#endif
}

// ---------------------------------------------------------------------------
// Fused prep: cast x & source to bf16; transpose+cast all weights.
// grid: [0,2400) cast x, [2400,4800) cast source, [4800,7360) weight tiles.
// Wqkvt is [768][256]: rows 0..255 Wq^T, 256..511 Wk^T, 512..767 Wv^T.
// ---------------------------------------------------------------------------
__global__ __launch_bounds__(256) void prep_kernel(
    const float* __restrict__ x, const float* __restrict__ source,
    const float* __restrict__ Wq, const float* __restrict__ Wk,
    const float* __restrict__ Wv, const float* __restrict__ Wm,
    const float* __restrict__ W1, const float* __restrict__ W2,
    u16* __restrict__ xb, u16* __restrict__ sb,
    u16* __restrict__ Wqkvt, u16* __restrict__ Wmt,
    u16* __restrict__ W1t, u16* __restrict__ W2t)
{
    __shared__ float tile[16][17];
    const int t = threadIdx.x;
    int bid = blockIdx.x;

    if (bid < 4800) {
        const float* src = bid < 2400 ? x : source;
        u16* dst = bid < 2400 ? xb : sb;
        int b = bid < 2400 ? bid : bid - 2400;
        int i = (b * 256 + t) * 4;
        float4 v = *reinterpret_cast<const float4*>(src + i);
        ushort4 o; o.x = f2bf(v.x); o.y = f2bf(v.y); o.z = f2bf(v.z); o.w = f2bf(v.w);
        *reinterpret_cast<ushort4*>(dst + i) = o;
        return;
    }
    int sub = bid - 4800;
    const float* W; u16* Wt; int Nd, ldt, rowoff;
    if      (sub < 256)  { W = Wq; Wt = Wqkvt; Nd = 256; ldt = 256; rowoff = 0;   }
    else if (sub < 512)  { W = Wk; Wt = Wqkvt; Nd = 256; ldt = 256; rowoff = 256; sub -= 256; }
    else if (sub < 768)  { W = Wv; Wt = Wqkvt; Nd = 256; ldt = 256; rowoff = 512; sub -= 512; }
    else if (sub < 1024) { W = Wm; Wt = Wmt;   Nd = 256; ldt = 256; rowoff = 0;   sub -= 768; }
    else if (sub < 2048) { W = W1; Wt = W1t;   Nd = 512; ldt = 512; rowoff = 0;   sub -= 1024; }
    else                 { W = W2; Wt = W2t;   Nd = 256; ldt = 512; rowoff = 0;   sub -= 2048; }
    int ntiles = Nd >> 4;
    int tn = sub % ntiles, tk = sub / ntiles;
    int tx = t & 15, ty = t >> 4;
    tile[ty][tx] = W[(size_t)(tk * 16 + ty) * Nd + tn * 16 + tx];
    __syncthreads();
    Wt[(size_t)(rowoff + tn * 16 + ty) * ldt + tk * 16 + tx] = f2bf(tile[tx][ty]);
}

// ---------------------------------------------------------------------------
// bf16 MFMA GEMM: C = act(A @ Bt^T). 128x128 tile, BK=32, 256 threads.
// splitK: A = concat(A0 cols<splitK, A1 cols>=splitK) along K.
// nsel:   blocks with n0>=nsel use A1 as the whole A (qkv fusion).
// flags: 1=relu, 2=bf16 out, 4=route output to 3 consecutive [M,256] buffers.
// ---------------------------------------------------------------------------
__global__ __launch_bounds__(256) void gemm_mfma_kernel(
    const u16* __restrict__ A0, int lda0,
    const u16* __restrict__ A1, int lda1, int splitK, int nsel,
    const u16* __restrict__ Bt, int ldb,
    void* __restrict__ Cout,
    int M, int N, int K, int flags)
{
    __shared__ __align__(16) u16 As[128 * 32];
    __shared__ __align__(16) u16 Bs[128 * 32];

    const int t  = threadIdx.x;
    const int l  = t & 63;
    const int w  = t >> 6;
    const int m0 = blockIdx.y * 128;
    const int n0 = blockIdx.x * 128;
    const int wr = w >> 1, wc = w & 1;

    if (nsel && n0 >= nsel) { A0 = A1; lda0 = lda1; }

    const int srow = l >> 2;
    const int sch  = (l & 3) ^ (srow & 3);

    f32x4 acc[4][4];
#pragma unroll
    for (int i = 0; i < 4; ++i)
#pragma unroll
        for (int j = 0; j < 4; ++j) acc[i][j] = (f32x4){0.f, 0.f, 0.f, 0.f};

    for (int k0 = 0; k0 < K; k0 += 32) {
        const u16* Ap; int kk, lda;
        if (splitK && k0 >= splitK) { Ap = A1; kk = k0 - splitK; lda = lda1; }
        else                        { Ap = A0; kk = k0;          lda = lda0; }

#pragma unroll
        for (int g = 0; g < 2; ++g) {
            int grp = w * 2 + g;
            int row = grp * 16 + srow;
            const u16* asrc = Ap + (size_t)(m0 + row) * lda + kk + sch * 8;
            u32* adst = (u32*)(As + grp * 512);
            __builtin_amdgcn_global_load_lds(
                (const __attribute__((address_space(1))) u32*)asrc,
                (__attribute__((address_space(3))) u32*)adst, 16, 0, 0);
            const u16* bsrc = Bt + (size_t)(n0 + row) * ldb + k0 + sch * 8;
            u32* bdst = (u32*)(Bs + grp * 512);
            __builtin_amdgcn_global_load_lds(
                (const __attribute__((address_space(1))) u32*)bsrc,
                (__attribute__((address_space(3))) u32*)bdst, 16, 0, 0);
        }
        __syncthreads();

        const int r  = l & 15;
        const int ch = l >> 4;
        bf16x8 af[4], bfr[4];
#pragma unroll
        for (int i = 0; i < 4; ++i) {
            int ar = wr * 64 + i * 16 + r;
            af[i] = *(const bf16x8*)((const char*)As + ar * 64 + ((ch ^ (r & 3)) * 16));
        }
#pragma unroll
        for (int j = 0; j < 4; ++j) {
            int br = wc * 64 + j * 16 + r;
            bfr[j] = *(const bf16x8*)((const char*)Bs + br * 64 + ((ch ^ (r & 3)) * 16));
        }
#pragma unroll
        for (int i = 0; i < 4; ++i)
#pragma unroll
            for (int j = 0; j < 4; ++j)
                acc[i][j] = __builtin_amdgcn_mfma_f32_16x16x32_bf16(af[i], bfr[j], acc[i][j], 0, 0, 0);
        __syncthreads();
    }

    const int r  = l & 15;
    const int q4 = l >> 4;
#pragma unroll
    for (int i = 0; i < 4; ++i)
#pragma unroll
        for (int j = 0; j < 4; ++j) {
            int col = n0 + wc * 64 + j * 16 + r;
#pragma unroll
            for (int reg = 0; reg < 4; ++reg) {
                int row = m0 + wr * 64 + i * 16 + q4 * 4 + reg;
                float vv = acc[i][j][reg];
                if (flags & 1) vv = fmaxf(vv, 0.f);
                size_t off;
                int colw, Nw;
                if (flags & 4) { off = (size_t)(col >> 8) * M * 256; colw = col & 255; Nw = 256; }
                else           { off = 0; colw = col; Nw = N; }
                if (flags & 2) ((u16*)Cout)[off + (size_t)row * Nw + colw] = f2bf(vv);
                else           ((float*)Cout)[off + (size_t)row * Nw + colw] = vv;
            }
        }
}

// ---------------------------------------------------------------------------
// Gathered attention, all-register, quad-coalesced gather. No LDS, no barriers.
// grid = 2*MROWS blocks of 256: qi = bid>>1, head = (bid&1)*4 + wave.
// Lane role: quad = l>>2 (key-quad), c = l&3 (16B chunk of 64B head slice).
// Lane's keys: {quad, quad+16, quad+32, quad+48}. 4 lanes of a quad read
// contiguous 16B chunks of the same row -> coalesced 64B segments (4x fewer
// TA requests than lane=key). Scores: partial dot2 + intra-quad shfl reduce.
// Softmax & PV reduced via xor-4/8/16/32 (quads hold disjoint key sets).
// ---------------------------------------------------------------------------
__global__ __launch_bounds__(256) void attn_kernel(
    const u16* __restrict__ q, const u16* __restrict__ k,
    const u16* __restrict__ v, const int* __restrict__ idx,
    u16* __restrict__ msg)
{
    const int t    = threadIdx.x;
    const int l    = t & 63;
    const int w    = t >> 6;
    const int qi   = blockIdx.x >> 1;
    const int head = ((blockIdx.x & 1) << 2) | w;
    const int n    = qi / LQ;
    const size_t srcbase = (size_t)n * LQ * 256;    // u16 units

    const int quad = l >> 2;   // 0..15
    const int c    = l & 3;    // 16B chunk

    // all 64 key indices, one per lane; distribute to quads via shfl
    int idxv = idx[(size_t)qi * 64 + l];
    int row0 = __shfl(idxv, quad);
    int row1 = __shfl(idxv, 16 + quad);
    int row2 = __shfl(idxv, 32 + quad);
    int row3 = __shfl(idxv, 48 + quad);

    const size_t hoff = (size_t)head * 32 + c * 8;  // u16 offset within a row

    // issue all gathers up front (quad-coalesced)
    uint4 k0 = *(const uint4*)(k + srcbase + (size_t)row0 * 256 + hoff);
    uint4 k1 = *(const uint4*)(k + srcbase + (size_t)row1 * 256 + hoff);
    uint4 k2 = *(const uint4*)(k + srcbase + (size_t)row2 * 256 + hoff);
    uint4 k3 = *(const uint4*)(k + srcbase + (size_t)row3 * 256 + hoff);
    uint4 v0 = *(const uint4*)(v + srcbase + (size_t)row0 * 256 + hoff);
    uint4 v1 = *(const uint4*)(v + srcbase + (size_t)row1 * 256 + hoff);
    uint4 v2 = *(const uint4*)(v + srcbase + (size_t)row2 * 256 + hoff);
    uint4 v3 = *(const uint4*)(v + srcbase + (size_t)row3 * 256 + hoff);
    uint4 qc = *(const uint4*)(q + (size_t)qi * 256 + hoff);

    // ---- scores: partial 8-dim dots, completed within quad ----
    float s0 = 0.f, s1 = 0.f, s2 = 0.f, s3 = 0.f;
    s0 = dot2bf(k0.x, qc.x, s0); s0 = dot2bf(k0.y, qc.y, s0);
    s0 = dot2bf(k0.z, qc.z, s0); s0 = dot2bf(k0.w, qc.w, s0);
    s1 = dot2bf(k1.x, qc.x, s1); s1 = dot2bf(k1.y, qc.y, s1);
    s1 = dot2bf(k1.z, qc.z, s1); s1 = dot2bf(k1.w, qc.w, s1);
    s2 = dot2bf(k2.x, qc.x, s2); s2 = dot2bf(k2.y, qc.y, s2);
    s2 = dot2bf(k2.z, qc.z, s2); s2 = dot2bf(k2.w, qc.w, s2);
    s3 = dot2bf(k3.x, qc.x, s3); s3 = dot2bf(k3.y, qc.y, s3);
    s3 = dot2bf(k3.z, qc.z, s3); s3 = dot2bf(k3.w, qc.w, s3);

    s0 += __shfl_xor(s0, 1); s0 += __shfl_xor(s0, 2);
    s1 += __shfl_xor(s1, 1); s1 += __shfl_xor(s1, 2);
    s2 += __shfl_xor(s2, 1); s2 += __shfl_xor(s2, 2);
    s3 += __shfl_xor(s3, 1); s3 += __shfl_xor(s3, 2);

    const float scale = 0.17677669529663687f;
    s0 *= scale; s1 *= scale; s2 *= scale; s3 *= scale;

    // ---- softmax over 64 keys (quads hold disjoint key sets) ----
    float mx = fmaxf(fmaxf(s0, s1), fmaxf(s2, s3));
    mx = fmaxf(mx, __shfl_xor(mx, 4));
    mx = fmaxf(mx, __shfl_xor(mx, 8));
    mx = fmaxf(mx, __shfl_xor(mx, 16));
    mx = fmaxf(mx, __shfl_xor(mx, 32));
    float p0 = __expf(s0 - mx), p1 = __expf(s1 - mx);
    float p2 = __expf(s2 - mx), p3 = __expf(s3 - mx);
    float sum = p0 + p1 + p2 + p3;
    sum += __shfl_xor(sum, 4);
    sum += __shfl_xor(sum, 8);
    sum += __shfl_xor(sum, 16);
    sum += __shfl_xor(sum, 32);
    float inv = 1.f / sum;
    p0 *= inv; p1 *= inv; p2 *= inv; p3 *= inv;

    // ---- PV: per-lane 4 keys x 8 dims, then cross-quad reduce ----
    float a0 = 0.f, a1 = 0.f, a2 = 0.f, a3 = 0.f;
    float a4 = 0.f, a5 = 0.f, a6 = 0.f, a7 = 0.f;
#define PVU(vv, p)                                        \
    a0 = fmaf(p, bf2f_lo(vv.x), a0); a1 = fmaf(p, bf2f_hi(vv.x), a1); \
    a2 = fmaf(p, bf2f_lo(vv.y), a2); a3 = fmaf(p, bf2f_hi(vv.y), a3); \
    a4 = fmaf(p, bf2f_lo(vv.z), a4); a5 = fmaf(p, bf2f_hi(vv.z), a5); \
    a6 = fmaf(p, bf2f_lo(vv.w), a6); a7 = fmaf(p, bf2f_hi(vv.w), a7);
    PVU(v0, p0) PVU(v1, p1) PVU(v2, p2) PVU(v3, p3)
#undef PVU

#pragma unroll
    for (int off = 4; off <= 32; off <<= 1) {
        a0 += __shfl_xor(a0, off); a1 += __shfl_xor(a1, off);
        a2 += __shfl_xor(a2, off); a3 += __shfl_xor(a3, off);
        a4 += __shfl_xor(a4, off); a5 += __shfl_xor(a5, off);
        a6 += __shfl_xor(a6, off); a7 += __shfl_xor(a7, off);
    }

    if (quad == 0) {
        uint4 o;
        o.x = (u32)f2bf(a0) | ((u32)f2bf(a1) << 16);
        o.y = (u32)f2bf(a2) | ((u32)f2bf(a3) << 16);
        o.z = (u32)f2bf(a4) | ((u32)f2bf(a5) << 16);
        o.w = (u32)f2bf(a6) | ((u32)f2bf(a7) << 16);
        *(uint4*)(msg + (size_t)qi * 256 + hoff) = o;
    }
}

// ---------------------------------------------------------------------------
// LayerNorm over last dim (256), fp32 input. One block per row.
// ---------------------------------------------------------------------------
__global__ __launch_bounds__(256) void ln_kernel(
    const float* __restrict__ in, const float* __restrict__ g,
    const float* __restrict__ b, const float* __restrict__ xadd,
    void* __restrict__ out, int out_bf16)
{
    __shared__ float red[8];
    const int t = threadIdx.x;
    const size_t row = blockIdx.x;
    float val = in[row * 256 + t];

    float s = val;
#pragma unroll
    for (int off = 32; off; off >>= 1) s += __shfl_down(s, off, 64);
    if ((t & 63) == 0) red[t >> 6] = s;
    __syncthreads();
    float mu = (red[0] + red[1] + red[2] + red[3]) * 0.00390625f;

    float dv = val - mu;
    float s2 = dv * dv;
#pragma unroll
    for (int off = 32; off; off >>= 1) s2 += __shfl_down(s2, off, 64);
    if ((t & 63) == 0) red[4 + (t >> 6)] = s2;
    __syncthreads();
    float var = (red[4] + red[5] + red[6] + red[7]) * 0.00390625f;
    float rstd = rsqrtf(var + LN_EPS);

    float r = dv * rstd * g[t] + b[t];
    if (xadd) r += xadd[row * 256 + t];
    if (out_bf16) ((u16*)out)[row * 256 + t] = f2bf(r);
    else          ((float*)out)[row * 256 + t] = r;
}

// ---------------------------------------------------------------------------
extern "C" void kernel_launch(void* const* d_in, const int* in_sizes, int n_in,
                              void* d_out, int out_size, void* d_ws, size_t ws_size,
                              hipStream_t stream)
{
    const float* x      = (const float*)d_in[0];
    const float* source = (const float*)d_in[1];
    const int*   eidx   = (const int*)d_in[2];
    const float* Wq     = (const float*)d_in[3];
    const float* Wk     = (const float*)d_in[4];
    const float* Wv     = (const float*)d_in[5];
    const float* Wm     = (const float*)d_in[6];
    const float* W1     = (const float*)d_in[7];
    const float* W2     = (const float*)d_in[8];
    const float* g1     = (const float*)d_in[9];
    const float* b1     = (const float*)d_in[10];
    const float* g2     = (const float*)d_in[11];
    const float* b2     = (const float*)d_in[12];
    float* out = (float*)d_out;

    char* ws = (char*)d_ws;
    const size_t SZB = (size_t)MROWS * 256 * 2;    // 4.9 MB
    u16* xb     = (u16*)(ws);                      // live until W1 gemm
    u16* sb     = (u16*)(ws + SZB);                // dead after qkv gemm
    u16* qb     = (u16*)(ws + 2 * SZB);            // qkv gemm routes here (seg 0)
    u16* kb     = (u16*)(ws + 3 * SZB);            // seg 1
    u16* vb     = (u16*)(ws + 4 * SZB);            // seg 2
    u16* msgb   = (u16*)(ws + 5 * SZB);            // dead after Wm gemm
    float* msgW = (float*)(ws + SZB);              // overlays sb+qb (dead)
    u16* msglnb = (u16*)(ws + 3 * SZB);            // overlays kb (dead)
    u16* h1b    = (u16*)(ws + 4 * SZB);            // [9600][512] overlays vb+msgb
    float* h2   = (float*)(ws + SZB);              // overlays msgW (dead)
    u16* Wqkvt  = (u16*)(ws + 6 * SZB);            // [768][256]
    u16* Wmt    = Wqkvt + 768 * 256;
    u16* W1t    = Wmt + 256 * 256;                 // [512][512]
    u16* W2t    = W1t + 512 * 512;                 // [256][512]

    dim3 blk(256);

    // fused prep: casts + all weight transposes
    prep_kernel<<<dim3(7360), blk, 0, stream>>>(x, source, Wq, Wk, Wv, Wm, W1, W2,
                                                xb, sb, Wqkvt, Wmt, W1t, W2t);

    // fused q|k|v projection (A = xb for cols<256, sb for cols>=256)
    gemm_mfma_kernel<<<dim3(6, 75), blk, 0, stream>>>(xb, 256, sb, 256, 0, 256,
                                                      Wqkvt, 256, qb, MROWS, 768, 256, 2 | 4);

    // gathered attention -> msg (bf16); 2 blocks per query (4 heads each)
    attn_kernel<<<dim3(2 * MROWS), blk, 0, stream>>>(qb, kb, vb, eidx, msgb);

    // msg @ Wm -> fp32
    gemm_mfma_kernel<<<dim3(2, 75), blk, 0, stream>>>(msgb, 256, nullptr, 0, 0, 0,
                                                      Wmt, 256, msgW, MROWS, 256, 256, 0);

    // LN1 -> bf16
    ln_kernel<<<dim3(MROWS), blk, 0, stream>>>(msgW, g1, b1, nullptr, msglnb, 1);

    // concat(x, msgln) @ W1, relu -> bf16 [9600,512]
    gemm_mfma_kernel<<<dim3(4, 75), blk, 0, stream>>>(xb, 256, msglnb, 256, 256, 0,
                                                      W1t, 512, h1b, MROWS, 512, 512, 1 | 2);

    // h1 @ W2 -> fp32
    gemm_mfma_kernel<<<dim3(2, 75), blk, 0, stream>>>(h1b, 512, nullptr, 0, 0, 0,
                                                      W2t, 512, h2, MROWS, 256, 512, 0);

    // out = x + LN2(h2)
    ln_kernel<<<dim3(MROWS), blk, 0, stream>>>(h2, g2, b2, x, out, 0);
}

// Round 8
// 135.524 us; speedup vs baseline: 1.3155x; 1.0377x over previous
//
#include <hip/hip_runtime.h>
#include <hip/hip_bf16.h>

#define D_MODEL 256
#define LQ 4800
#define NB 2
#define MROWS (NB * LQ)       // 9600
#define LN_EPS 1e-5f

typedef unsigned int u32;
typedef unsigned short u16;
typedef __attribute__((ext_vector_type(8))) short bf16x8;
typedef __attribute__((ext_vector_type(4))) float f32x4;
typedef __attribute__((ext_vector_type(2))) float f32x2;
typedef __attribute__((ext_vector_type(2))) __bf16 bf16x2v;

__device__ __forceinline__ float bf2f(u32 bits16) {
    return __uint_as_float(bits16 << 16);
}
__device__ __forceinline__ float bf2f_lo(u32 v) { return __uint_as_float(v << 16); }
__device__ __forceinline__ float bf2f_hi(u32 v) { return __uint_as_float(v & 0xffff0000u); }
__device__ __forceinline__ u16 f2bf(float f) {
    __hip_bfloat16 h = __float2bfloat16(f);
    return *reinterpret_cast<u16*>(&h);
}

// dot2 of two bf16 pairs (packed in u32) accumulating into f32.
__device__ __forceinline__ float dot2bf(u32 a, u32 b, float c) {
#if __has_builtin(__builtin_amdgcn_fdot2_f32_bf16)
    return __builtin_amdgcn_fdot2_f32_bf16(__builtin_bit_cast(bf16x2v, a),
                                           __builtin_bit_cast(bf16x2v, b), c, false);
#else
    c = fmaf(bf2f_lo(a), bf2f_lo(b), c);
    return fmaf(bf2f_hi(a), bf2f_hi(b), c);
#endif
}

// ---------------------------------------------------------------------------
// Fused prep: cast x & source to bf16; transpose+cast all weights.
// grid: [0,2400) cast x, [2400,4800) cast source, [4800,7360) weight tiles.
// Wqkvt is [768][256]: rows 0..255 Wq^T, 256..511 Wk^T, 512..767 Wv^T.
// ---------------------------------------------------------------------------
__global__ __launch_bounds__(256) void prep_kernel(
    const float* __restrict__ x, const float* __restrict__ source,
    const float* __restrict__ Wq, const float* __restrict__ Wk,
    const float* __restrict__ Wv, const float* __restrict__ Wm,
    const float* __restrict__ W1, const float* __restrict__ W2,
    u16* __restrict__ xb, u16* __restrict__ sb,
    u16* __restrict__ Wqkvt, u16* __restrict__ Wmt,
    u16* __restrict__ W1t, u16* __restrict__ W2t)
{
    __shared__ float tile[16][17];
    const int t = threadIdx.x;
    int bid = blockIdx.x;

    if (bid < 4800) {
        const float* src = bid < 2400 ? x : source;
        u16* dst = bid < 2400 ? xb : sb;
        int b = bid < 2400 ? bid : bid - 2400;
        int i = (b * 256 + t) * 4;
        float4 v = *reinterpret_cast<const float4*>(src + i);
        ushort4 o; o.x = f2bf(v.x); o.y = f2bf(v.y); o.z = f2bf(v.z); o.w = f2bf(v.w);
        *reinterpret_cast<ushort4*>(dst + i) = o;
        return;
    }
    int sub = bid - 4800;
    const float* W; u16* Wt; int Nd, ldt, rowoff;
    if      (sub < 256)  { W = Wq; Wt = Wqkvt; Nd = 256; ldt = 256; rowoff = 0;   }
    else if (sub < 512)  { W = Wk; Wt = Wqkvt; Nd = 256; ldt = 256; rowoff = 256; sub -= 256; }
    else if (sub < 768)  { W = Wv; Wt = Wqkvt; Nd = 256; ldt = 256; rowoff = 512; sub -= 512; }
    else if (sub < 1024) { W = Wm; Wt = Wmt;   Nd = 256; ldt = 256; rowoff = 0;   sub -= 768; }
    else if (sub < 2048) { W = W1; Wt = W1t;   Nd = 512; ldt = 512; rowoff = 0;   sub -= 1024; }
    else                 { W = W2; Wt = W2t;   Nd = 256; ldt = 512; rowoff = 0;   sub -= 2048; }
    int ntiles = Nd >> 4;
    int tn = sub % ntiles, tk = sub / ntiles;
    int tx = t & 15, ty = t >> 4;
    tile[ty][tx] = W[(size_t)(tk * 16 + ty) * Nd + tn * 16 + tx];
    __syncthreads();
    Wt[(size_t)(rowoff + tn * 16 + ty) * ldt + tk * 16 + tx] = f2bf(tile[tx][ty]);
}

// ---------------------------------------------------------------------------
// bf16 MFMA GEMM: C = act(A @ Bt^T). 128x128 tile, BK=32, 256 threads.
// splitK: A = concat(A0 cols<splitK, A1 cols>=splitK) along K.
// nsel:   blocks with n0>=nsel use A1 as the whole A (qkv fusion).
// flags: 1=relu, 2=bf16 out, 4=route output to 3 consecutive [M,256] buffers.
// ---------------------------------------------------------------------------
__global__ __launch_bounds__(256) void gemm_mfma_kernel(
    const u16* __restrict__ A0, int lda0,
    const u16* __restrict__ A1, int lda1, int splitK, int nsel,
    const u16* __restrict__ Bt, int ldb,
    void* __restrict__ Cout,
    int M, int N, int K, int flags)
{
    __shared__ __align__(16) u16 As[128 * 32];
    __shared__ __align__(16) u16 Bs[128 * 32];

    const int t  = threadIdx.x;
    const int l  = t & 63;
    const int w  = t >> 6;
    const int m0 = blockIdx.y * 128;
    const int n0 = blockIdx.x * 128;
    const int wr = w >> 1, wc = w & 1;

    if (nsel && n0 >= nsel) { A0 = A1; lda0 = lda1; }

    const int srow = l >> 2;
    const int sch  = (l & 3) ^ (srow & 3);

    f32x4 acc[4][4];
#pragma unroll
    for (int i = 0; i < 4; ++i)
#pragma unroll
        for (int j = 0; j < 4; ++j) acc[i][j] = (f32x4){0.f, 0.f, 0.f, 0.f};

    for (int k0 = 0; k0 < K; k0 += 32) {
        const u16* Ap; int kk, lda;
        if (splitK && k0 >= splitK) { Ap = A1; kk = k0 - splitK; lda = lda1; }
        else                        { Ap = A0; kk = k0;          lda = lda0; }

#pragma unroll
        for (int g = 0; g < 2; ++g) {
            int grp = w * 2 + g;
            int row = grp * 16 + srow;
            const u16* asrc = Ap + (size_t)(m0 + row) * lda + kk + sch * 8;
            u32* adst = (u32*)(As + grp * 512);
            __builtin_amdgcn_global_load_lds(
                (const __attribute__((address_space(1))) u32*)asrc,
                (__attribute__((address_space(3))) u32*)adst, 16, 0, 0);
            const u16* bsrc = Bt + (size_t)(n0 + row) * ldb + k0 + sch * 8;
            u32* bdst = (u32*)(Bs + grp * 512);
            __builtin_amdgcn_global_load_lds(
                (const __attribute__((address_space(1))) u32*)bsrc,
                (__attribute__((address_space(3))) u32*)bdst, 16, 0, 0);
        }
        __syncthreads();

        const int r  = l & 15;
        const int ch = l >> 4;
        bf16x8 af[4], bfr[4];
#pragma unroll
        for (int i = 0; i < 4; ++i) {
            int ar = wr * 64 + i * 16 + r;
            af[i] = *(const bf16x8*)((const char*)As + ar * 64 + ((ch ^ (r & 3)) * 16));
        }
#pragma unroll
        for (int j = 0; j < 4; ++j) {
            int br = wc * 64 + j * 16 + r;
            bfr[j] = *(const bf16x8*)((const char*)Bs + br * 64 + ((ch ^ (r & 3)) * 16));
        }
#pragma unroll
        for (int i = 0; i < 4; ++i)
#pragma unroll
            for (int j = 0; j < 4; ++j)
                acc[i][j] = __builtin_amdgcn_mfma_f32_16x16x32_bf16(af[i], bfr[j], acc[i][j], 0, 0, 0);
        __syncthreads();
    }

    const int r  = l & 15;
    const int q4 = l >> 4;
#pragma unroll
    for (int i = 0; i < 4; ++i)
#pragma unroll
        for (int j = 0; j < 4; ++j) {
            int col = n0 + wc * 64 + j * 16 + r;
#pragma unroll
            for (int reg = 0; reg < 4; ++reg) {
                int row = m0 + wr * 64 + i * 16 + q4 * 4 + reg;
                float vv = acc[i][j][reg];
                if (flags & 1) vv = fmaxf(vv, 0.f);
                size_t off;
                int colw, Nw;
                if (flags & 4) { off = (size_t)(col >> 8) * M * 256; colw = col & 255; Nw = 256; }
                else           { off = 0; colw = col; Nw = N; }
                if (flags & 2) ((u16*)Cout)[off + (size_t)row * Nw + colw] = f2bf(vv);
                else           ((float*)Cout)[off + (size_t)row * Nw + colw] = vv;
            }
        }
}

// ---------------------------------------------------------------------------
// Gathered attention, all-register, quad-coalesced gather. No LDS, no barriers.
// grid = 2*MROWS blocks of 256: qi = bid>>1, head = (bid&1)*4 + wave.
// Lane role: quad = l>>2 (key-quad), c = l&3 (16B chunk of 64B head slice).
// Lane's keys: {quad, quad+16, quad+32, quad+48}.
// PV accumulates float2 dim-pairs (pk_fma-eligible), then a butterfly-SPLIT
// reduce: xor4 moves 4 floats, xor8 moves 2, xor16/32 exchange 2 each =
// 10 shuffles total (vs 32 for the naive all-acc reduce). Each lane ends
// owning one dim-pair; lanes l<16 store one u32 (one 64B segment).
// ---------------------------------------------------------------------------
__global__ __launch_bounds__(256) void attn_kernel(
    const u16* __restrict__ q, const u16* __restrict__ k,
    const u16* __restrict__ v, const int* __restrict__ idx,
    u16* __restrict__ msg)
{
    const int t    = threadIdx.x;
    const int l    = t & 63;
    const int w    = t >> 6;
    const int qi   = blockIdx.x >> 1;
    const int head = ((blockIdx.x & 1) << 2) | w;
    const int n    = qi / LQ;
    const size_t srcbase = (size_t)n * LQ * 256;    // u16 units

    const int quad = l >> 2;   // 0..15
    const int c    = l & 3;    // 16B chunk

    // all 64 key indices, one per lane; distribute to quads via shfl
    int idxv = idx[(size_t)qi * 64 + l];
    int row0 = __shfl(idxv, quad);
    int row1 = __shfl(idxv, 16 + quad);
    int row2 = __shfl(idxv, 32 + quad);
    int row3 = __shfl(idxv, 48 + quad);

    const size_t hoff = (size_t)head * 32 + c * 8;  // u16 offset within a row

    // issue all gathers up front (quad-coalesced)
    uint4 k0 = *(const uint4*)(k + srcbase + (size_t)row0 * 256 + hoff);
    uint4 k1 = *(const uint4*)(k + srcbase + (size_t)row1 * 256 + hoff);
    uint4 k2 = *(const uint4*)(k + srcbase + (size_t)row2 * 256 + hoff);
    uint4 k3 = *(const uint4*)(k + srcbase + (size_t)row3 * 256 + hoff);
    uint4 v0 = *(const uint4*)(v + srcbase + (size_t)row0 * 256 + hoff);
    uint4 v1 = *(const uint4*)(v + srcbase + (size_t)row1 * 256 + hoff);
    uint4 v2 = *(const uint4*)(v + srcbase + (size_t)row2 * 256 + hoff);
    uint4 v3 = *(const uint4*)(v + srcbase + (size_t)row3 * 256 + hoff);
    uint4 qc = *(const uint4*)(q + (size_t)qi * 256 + hoff);

    // ---- scores: partial 8-dim dots, completed within quad ----
    float s0 = 0.f, s1 = 0.f, s2 = 0.f, s3 = 0.f;
    s0 = dot2bf(k0.x, qc.x, s0); s0 = dot2bf(k0.y, qc.y, s0);
    s0 = dot2bf(k0.z, qc.z, s0); s0 = dot2bf(k0.w, qc.w, s0);
    s1 = dot2bf(k1.x, qc.x, s1); s1 = dot2bf(k1.y, qc.y, s1);
    s1 = dot2bf(k1.z, qc.z, s1); s1 = dot2bf(k1.w, qc.w, s1);
    s2 = dot2bf(k2.x, qc.x, s2); s2 = dot2bf(k2.y, qc.y, s2);
    s2 = dot2bf(k2.z, qc.z, s2); s2 = dot2bf(k2.w, qc.w, s2);
    s3 = dot2bf(k3.x, qc.x, s3); s3 = dot2bf(k3.y, qc.y, s3);
    s3 = dot2bf(k3.z, qc.z, s3); s3 = dot2bf(k3.w, qc.w, s3);

    s0 += __shfl_xor(s0, 1); s0 += __shfl_xor(s0, 2);
    s1 += __shfl_xor(s1, 1); s1 += __shfl_xor(s1, 2);
    s2 += __shfl_xor(s2, 1); s2 += __shfl_xor(s2, 2);
    s3 += __shfl_xor(s3, 1); s3 += __shfl_xor(s3, 2);

    const float scale = 0.17677669529663687f;
    s0 *= scale; s1 *= scale; s2 *= scale; s3 *= scale;

    // ---- softmax over 64 keys (quads hold disjoint key sets) ----
    float mx = fmaxf(fmaxf(s0, s1), fmaxf(s2, s3));
    mx = fmaxf(mx, __shfl_xor(mx, 4));
    mx = fmaxf(mx, __shfl_xor(mx, 8));
    mx = fmaxf(mx, __shfl_xor(mx, 16));
    mx = fmaxf(mx, __shfl_xor(mx, 32));
    float p0 = __expf(s0 - mx), p1 = __expf(s1 - mx);
    float p2 = __expf(s2 - mx), p3 = __expf(s3 - mx);
    float sum = p0 + p1 + p2 + p3;
    sum += __shfl_xor(sum, 4);
    sum += __shfl_xor(sum, 8);
    sum += __shfl_xor(sum, 16);
    sum += __shfl_xor(sum, 32);
    float inv = 1.f / sum;
    p0 *= inv; p1 *= inv; p2 *= inv; p3 *= inv;

    // ---- PV: per-lane 4 keys x 4 dim-pairs (float2, pk_fma-eligible) ----
    f32x2 A0 = {0.f, 0.f}, A1 = {0.f, 0.f}, A2 = {0.f, 0.f}, A3 = {0.f, 0.f};
#define PVU(vv, p) {                                                   \
    f32x2 p2_ = {p, p};                                                \
    f32x2 d0_ = {bf2f_lo(vv.x), bf2f_hi(vv.x)};                        \
    f32x2 d1_ = {bf2f_lo(vv.y), bf2f_hi(vv.y)};                        \
    f32x2 d2_ = {bf2f_lo(vv.z), bf2f_hi(vv.z)};                        \
    f32x2 d3_ = {bf2f_lo(vv.w), bf2f_hi(vv.w)};                        \
    A0 = __builtin_elementwise_fma(p2_, d0_, A0);                      \
    A1 = __builtin_elementwise_fma(p2_, d1_, A1);                      \
    A2 = __builtin_elementwise_fma(p2_, d2_, A2);                      \
    A3 = __builtin_elementwise_fma(p2_, d3_, A3);                      \
}
    PVU(v0, p0) PVU(v1, p1) PVU(v2, p2) PVU(v3, p3)
#undef PVU

    // ---- butterfly-SPLIT reduce over the 16 lanes sharing chunk c ----
    const bool qb0 = (quad & 1) != 0;
    const bool qb1 = (quad & 2) != 0;

    // step 1 (xor 4): halve pairs 4 -> 2.  send our non-kept half.
    {
        float t0 = qb0 ? A0.x : A2.x;
        float t1 = qb0 ? A0.y : A2.y;
        float t2 = qb0 ? A1.x : A3.x;
        float t3 = qb0 ? A1.y : A3.y;
        t0 = __shfl_xor(t0, 4); t1 = __shfl_xor(t1, 4);
        t2 = __shfl_xor(t2, 4); t3 = __shfl_xor(t3, 4);
        f32x2 B0, B1;
        if (!qb0) { B0.x = A0.x + t0; B0.y = A0.y + t1; B1.x = A1.x + t2; B1.y = A1.y + t3; }
        else      { B0.x = A2.x + t0; B0.y = A2.y + t1; B1.x = A3.x + t2; B1.y = A3.y + t3; }
        A0 = B0; A1 = B1;
    }
    // step 2 (xor 8): halve pairs 2 -> 1.
    {
        float u0 = qb1 ? A0.x : A1.x;
        float u1 = qb1 ? A0.y : A1.y;
        u0 = __shfl_xor(u0, 8); u1 = __shfl_xor(u1, 8);
        f32x2 Cc;
        if (!qb1) { Cc.x = A0.x + u0; Cc.y = A0.y + u1; }
        else      { Cc.x = A1.x + u0; Cc.y = A1.y + u1; }
        A0 = Cc;
    }
    // steps 3,4 (xor 16, 32): full exchange of the surviving pair.
    A0.x += __shfl_xor(A0.x, 16); A0.y += __shfl_xor(A0.y, 16);
    A0.x += __shfl_xor(A0.x, 32); A0.y += __shfl_xor(A0.y, 32);

    // lane (quad<4, c) owns dim-pair p = 2*(quad&1) + ((quad>>1)&1) of chunk c
    if (quad < 4) {
        int p = 2 * (quad & 1) + ((quad >> 1) & 1);
        u32 packed = (u32)f2bf(A0.x) | ((u32)f2bf(A0.y) << 16);
        *(u32*)(msg + (size_t)qi * 256 + head * 32 + c * 8 + p * 2) = packed;
    }
}

// ---------------------------------------------------------------------------
// LayerNorm over last dim (256), fp32 input. One block per row.
// ---------------------------------------------------------------------------
__global__ __launch_bounds__(256) void ln_kernel(
    const float* __restrict__ in, const float* __restrict__ g,
    const float* __restrict__ b, const float* __restrict__ xadd,
    void* __restrict__ out, int out_bf16)
{
    __shared__ float red[8];
    const int t = threadIdx.x;
    const size_t row = blockIdx.x;
    float val = in[row * 256 + t];

    float s = val;
#pragma unroll
    for (int off = 32; off; off >>= 1) s += __shfl_down(s, off, 64);
    if ((t & 63) == 0) red[t >> 6] = s;
    __syncthreads();
    float mu = (red[0] + red[1] + red[2] + red[3]) * 0.00390625f;

    float dv = val - mu;
    float s2 = dv * dv;
#pragma unroll
    for (int off = 32; off; off >>= 1) s2 += __shfl_down(s2, off, 64);
    if ((t & 63) == 0) red[4 + (t >> 6)] = s2;
    __syncthreads();
    float var = (red[4] + red[5] + red[6] + red[7]) * 0.00390625f;
    float rstd = rsqrtf(var + LN_EPS);

    float r = dv * rstd * g[t] + b[t];
    if (xadd) r += xadd[row * 256 + t];
    if (out_bf16) ((u16*)out)[row * 256 + t] = f2bf(r);
    else          ((float*)out)[row * 256 + t] = r;
}

// ---------------------------------------------------------------------------
extern "C" void kernel_launch(void* const* d_in, const int* in_sizes, int n_in,
                              void* d_out, int out_size, void* d_ws, size_t ws_size,
                              hipStream_t stream)
{
    const float* x      = (const float*)d_in[0];
    const float* source = (const float*)d_in[1];
    const int*   eidx   = (const int*)d_in[2];
    const float* Wq     = (const float*)d_in[3];
    const float* Wk     = (const float*)d_in[4];
    const float* Wv     = (const float*)d_in[5];
    const float* Wm     = (const float*)d_in[6];
    const float* W1     = (const float*)d_in[7];
    const float* W2     = (const float*)d_in[8];
    const float* g1     = (const float*)d_in[9];
    const float* b1     = (const float*)d_in[10];
    const float* g2     = (const float*)d_in[11];
    const float* b2     = (const float*)d_in[12];
    float* out = (float*)d_out;

    char* ws = (char*)d_ws;
    const size_t SZB = (size_t)MROWS * 256 * 2;    // 4.9 MB
    u16* xb     = (u16*)(ws);                      // live until W1 gemm
    u16* sb     = (u16*)(ws + SZB);                // dead after qkv gemm
    u16* qb     = (u16*)(ws + 2 * SZB);            // qkv gemm routes here (seg 0)
    u16* kb     = (u16*)(ws + 3 * SZB);            // seg 1
    u16* vb     = (u16*)(ws + 4 * SZB);            // seg 2
    u16* msgb   = (u16*)(ws + 5 * SZB);            // dead after Wm gemm
    float* msgW = (float*)(ws + SZB);              // overlays sb+qb (dead)
    u16* msglnb = (u16*)(ws + 3 * SZB);            // overlays kb (dead)
    u16* h1b    = (u16*)(ws + 4 * SZB);            // [9600][512] overlays vb+msgb
    float* h2   = (float*)(ws + SZB);              // overlays msgW (dead)
    u16* Wqkvt  = (u16*)(ws + 6 * SZB);            // [768][256]
    u16* Wmt    = Wqkvt + 768 * 256;
    u16* W1t    = Wmt + 256 * 256;                 // [512][512]
    u16* W2t    = W1t + 512 * 512;                 // [256][512]

    dim3 blk(256);

    // fused prep: casts + all weight transposes
    prep_kernel<<<dim3(7360), blk, 0, stream>>>(x, source, Wq, Wk, Wv, Wm, W1, W2,
                                                xb, sb, Wqkvt, Wmt, W1t, W2t);

    // fused q|k|v projection (A = xb for cols<256, sb for cols>=256)
    gemm_mfma_kernel<<<dim3(6, 75), blk, 0, stream>>>(xb, 256, sb, 256, 0, 256,
                                                      Wqkvt, 256, qb, MROWS, 768, 256, 2 | 4);

    // gathered attention -> msg (bf16); 2 blocks per query (4 heads each)
    attn_kernel<<<dim3(2 * MROWS), blk, 0, stream>>>(qb, kb, vb, eidx, msgb);

    // msg @ Wm -> fp32
    gemm_mfma_kernel<<<dim3(2, 75), blk, 0, stream>>>(msgb, 256, nullptr, 0, 0, 0,
                                                      Wmt, 256, msgW, MROWS, 256, 256, 0);

    // LN1 -> bf16
    ln_kernel<<<dim3(MROWS), blk, 0, stream>>>(msgW, g1, b1, nullptr, msglnb, 1);

    // concat(x, msgln) @ W1, relu -> bf16 [9600,512]
    gemm_mfma_kernel<<<dim3(4, 75), blk, 0, stream>>>(xb, 256, msglnb, 256, 256, 0,
                                                      W1t, 512, h1b, MROWS, 512, 512, 1 | 2);

    // h1 @ W2 -> fp32
    gemm_mfma_kernel<<<dim3(2, 75), blk, 0, stream>>>(h1b, 512, nullptr, 0, 0, 0,
                                                      W2t, 512, h2, MROWS, 256, 512, 0);

    // out = x + LN2(h2)
    ln_kernel<<<dim3(MROWS), blk, 0, stream>>>(h2, g2, b2, x, out, 0);
}

// Round 9
// 126.116 us; speedup vs baseline: 1.4137x; 1.0746x over previous
//
#include <hip/hip_runtime.h>
#include <hip/hip_bf16.h>

#define D_MODEL 256
#define LQ 4800
#define NB 2
#define MROWS (NB * LQ)       // 9600
#define LN_EPS 1e-5f

typedef unsigned int u32;
typedef unsigned short u16;
typedef __attribute__((ext_vector_type(8))) short bf16x8;
typedef __attribute__((ext_vector_type(4))) float f32x4;
typedef __attribute__((ext_vector_type(2))) _Float16 f16x2;

__device__ __forceinline__ float bf2f(u32 bits16) {
    return __uint_as_float(bits16 << 16);
}
__device__ __forceinline__ u16 f2bf(float f) {
    __hip_bfloat16 h = __float2bfloat16(f);
    return *reinterpret_cast<u16*>(&h);
}

// f16 pair dot into f32 (v_dot2_f32_f16)
__device__ __forceinline__ float dot2f16(u32 a, u32 b, float c) {
#if __has_builtin(__builtin_amdgcn_fdot2)
    return __builtin_amdgcn_fdot2(__builtin_bit_cast(f16x2, a),
                                  __builtin_bit_cast(f16x2, b), c, false);
#else
    f16x2 av = __builtin_bit_cast(f16x2, a), bv = __builtin_bit_cast(f16x2, b);
    c = fmaf((float)av.x, (float)bv.x, c);
    return fmaf((float)av.y, (float)bv.y, c);
#endif
}
__device__ __forceinline__ u32 pk_fma16(u32 a, u32 b, u32 c) {
    u32 d;
    asm("v_pk_fma_f16 %0, %1, %2, %3" : "=v"(d) : "v"(a), "v"(b), "v"(c));
    return d;
}
__device__ __forceinline__ u32 pk_add16(u32 a, u32 b) {
    u32 d;
    asm("v_pk_add_f16 %0, %1, %2" : "=v"(d) : "v"(a), "v"(b));
    return d;
}
__device__ __forceinline__ u32 pkrtz(float a, float b) {
    return __builtin_bit_cast(u32, __builtin_amdgcn_cvt_pkrtz(a, b));
}

// ---------------------------------------------------------------------------
// Fused prep: cast x & source to bf16; transpose+cast all weights.
// grid: [0,2400) cast x, [2400,4800) cast source, [4800,7360) weight tiles.
// Wqkvt is [768][256]: rows 0..255 Wq^T, 256..511 Wk^T, 512..767 Wv^T.
// ---------------------------------------------------------------------------
__global__ __launch_bounds__(256) void prep_kernel(
    const float* __restrict__ x, const float* __restrict__ source,
    const float* __restrict__ Wq, const float* __restrict__ Wk,
    const float* __restrict__ Wv, const float* __restrict__ Wm,
    const float* __restrict__ W1, const float* __restrict__ W2,
    u16* __restrict__ xb, u16* __restrict__ sb,
    u16* __restrict__ Wqkvt, u16* __restrict__ Wmt,
    u16* __restrict__ W1t, u16* __restrict__ W2t)
{
    __shared__ float tile[16][17];
    const int t = threadIdx.x;
    int bid = blockIdx.x;

    if (bid < 4800) {
        const float* src = bid < 2400 ? x : source;
        u16* dst = bid < 2400 ? xb : sb;
        int b = bid < 2400 ? bid : bid - 2400;
        int i = (b * 256 + t) * 4;
        float4 v = *reinterpret_cast<const float4*>(src + i);
        ushort4 o; o.x = f2bf(v.x); o.y = f2bf(v.y); o.z = f2bf(v.z); o.w = f2bf(v.w);
        *reinterpret_cast<ushort4*>(dst + i) = o;
        return;
    }
    int sub = bid - 4800;
    const float* W; u16* Wt; int Nd, ldt, rowoff;
    if      (sub < 256)  { W = Wq; Wt = Wqkvt; Nd = 256; ldt = 256; rowoff = 0;   }
    else if (sub < 512)  { W = Wk; Wt = Wqkvt; Nd = 256; ldt = 256; rowoff = 256; sub -= 256; }
    else if (sub < 768)  { W = Wv; Wt = Wqkvt; Nd = 256; ldt = 256; rowoff = 512; sub -= 512; }
    else if (sub < 1024) { W = Wm; Wt = Wmt;   Nd = 256; ldt = 256; rowoff = 0;   sub -= 768; }
    else if (sub < 2048) { W = W1; Wt = W1t;   Nd = 512; ldt = 512; rowoff = 0;   sub -= 1024; }
    else                 { W = W2; Wt = W2t;   Nd = 256; ldt = 512; rowoff = 0;   sub -= 2048; }
    int ntiles = Nd >> 4;
    int tn = sub % ntiles, tk = sub / ntiles;
    int tx = t & 15, ty = t >> 4;
    tile[ty][tx] = W[(size_t)(tk * 16 + ty) * Nd + tn * 16 + tx];
    __syncthreads();
    Wt[(size_t)(rowoff + tn * 16 + ty) * ldt + tk * 16 + tx] = f2bf(tile[tx][ty]);
}

// ---------------------------------------------------------------------------
// bf16 MFMA GEMM, templated tile: C = act(A @ Bt^T). BK=32, 256 threads,
// 2x2 waves, each wave (BM/2)x(BN/2). BM,BN in {64,128}.
// splitK: A = concat(A0 cols<splitK, A1 cols>=splitK) along K.
// nsel:   blocks with n0>=nsel use A1 as the whole A (qkv fusion).
// flags: 1=relu, 2=bf16 out, 4=route output to 3 consecutive [M,256] buffers,
//        8=f16 out.
// ---------------------------------------------------------------------------
template<int BM, int BN>
__global__ __launch_bounds__(256) void gemm_mfma_kernel(
    const u16* __restrict__ A0, int lda0,
    const u16* __restrict__ A1, int lda1, int splitK, int nsel,
    const u16* __restrict__ Bt, int ldb,
    void* __restrict__ Cout,
    int M, int N, int K, int flags)
{
    __shared__ __align__(16) u16 As[BM * 32];
    __shared__ __align__(16) u16 Bs[BN * 32];

    constexpr int WM = BM / 2, WN = BN / 2;
    constexpr int FI = WM / 16, FJ = WN / 16;

    const int t  = threadIdx.x;
    const int l  = t & 63;
    const int w  = t >> 6;
    const int m0 = blockIdx.y * BM;
    const int n0 = blockIdx.x * BN;
    const int wr = w >> 1, wc = w & 1;

    if (nsel && n0 >= nsel) { A0 = A1; lda0 = lda1; }

    const int srow = l >> 2;
    const int sch  = (l & 3) ^ (srow & 3);

    f32x4 acc[FI][FJ];
#pragma unroll
    for (int i = 0; i < FI; ++i)
#pragma unroll
        for (int j = 0; j < FJ; ++j) acc[i][j] = (f32x4){0.f, 0.f, 0.f, 0.f};

    for (int k0 = 0; k0 < K; k0 += 32) {
        const u16* Ap; int kk, lda;
        if (splitK && k0 >= splitK) { Ap = A1; kk = k0 - splitK; lda = lda1; }
        else                        { Ap = A0; kk = k0;          lda = lda0; }

#pragma unroll
        for (int g = 0; g < BM / 64; ++g) {
            int grp = w * (BM / 64) + g;
            int row = grp * 16 + srow;
            const u16* asrc = Ap + (size_t)(m0 + row) * lda + kk + sch * 8;
            u32* adst = (u32*)(As + grp * 512);
            __builtin_amdgcn_global_load_lds(
                (const __attribute__((address_space(1))) u32*)asrc,
                (__attribute__((address_space(3))) u32*)adst, 16, 0, 0);
        }
#pragma unroll
        for (int g = 0; g < BN / 64; ++g) {
            int grp = w * (BN / 64) + g;
            int row = grp * 16 + srow;
            const u16* bsrc = Bt + (size_t)(n0 + row) * ldb + k0 + sch * 8;
            u32* bdst = (u32*)(Bs + grp * 512);
            __builtin_amdgcn_global_load_lds(
                (const __attribute__((address_space(1))) u32*)bsrc,
                (__attribute__((address_space(3))) u32*)bdst, 16, 0, 0);
        }
        __syncthreads();

        const int r  = l & 15;
        const int ch = l >> 4;
        bf16x8 af[FI], bfr[FJ];
#pragma unroll
        for (int i = 0; i < FI; ++i) {
            int ar = wr * WM + i * 16 + r;
            af[i] = *(const bf16x8*)((const char*)As + ar * 64 + ((ch ^ (r & 3)) * 16));
        }
#pragma unroll
        for (int j = 0; j < FJ; ++j) {
            int br = wc * WN + j * 16 + r;
            bfr[j] = *(const bf16x8*)((const char*)Bs + br * 64 + ((ch ^ (r & 3)) * 16));
        }
#pragma unroll
        for (int i = 0; i < FI; ++i)
#pragma unroll
            for (int j = 0; j < FJ; ++j)
                acc[i][j] = __builtin_amdgcn_mfma_f32_16x16x32_bf16(af[i], bfr[j], acc[i][j], 0, 0, 0);
        __syncthreads();
    }

    const int r  = l & 15;
    const int q4 = l >> 4;
#pragma unroll
    for (int i = 0; i < FI; ++i)
#pragma unroll
        for (int j = 0; j < FJ; ++j) {
            int col = n0 + wc * WN + j * 16 + r;
#pragma unroll
            for (int reg = 0; reg < 4; ++reg) {
                int row = m0 + wr * WM + i * 16 + q4 * 4 + reg;
                float vv = acc[i][j][reg];
                if (flags & 1) vv = fmaxf(vv, 0.f);
                size_t off;
                int colw, Nw;
                if (flags & 4) { off = (size_t)(col >> 8) * M * 256; colw = col & 255; Nw = 256; }
                else           { off = 0; colw = col; Nw = N; }
                if (flags & 8) {
                    _Float16 hv = (_Float16)vv;
                    ((u16*)Cout)[off + (size_t)row * Nw + colw] = __builtin_bit_cast(u16, hv);
                } else if (flags & 2) {
                    ((u16*)Cout)[off + (size_t)row * Nw + colw] = f2bf(vv);
                } else {
                    ((float*)Cout)[off + (size_t)row * Nw + colw] = vv;
                }
            }
        }
}

// ---------------------------------------------------------------------------
// Gathered attention, all-register, quad-coalesced, fp16 packed math.
// q,k,v: [MROWS,256] fp16 head-major. msg out: bf16.
// grid = 2*MROWS blocks of 256: qi = bid>>1, head = (bid&1)*4 + wave.
// Lane role: quad = l>>2 (key-quad), c = l&3 (16B chunk of 64B head slice).
// Lane's keys: {quad, quad+16, quad+32, quad+48}.
// Scores: v_dot2_f32_f16 partials + intra-quad shfl. Softmax f32.
// PV: p -> f16 pairs once, 16x v_pk_fma_f16 (no unpacking), butterfly-split
// reduce on packed u32s (5 shuffles + 5 pk_add).
// ---------------------------------------------------------------------------
__global__ __launch_bounds__(256) void attn_kernel(
    const u16* __restrict__ q, const u16* __restrict__ k,
    const u16* __restrict__ v, const int* __restrict__ idx,
    u16* __restrict__ msg)
{
    const int t    = threadIdx.x;
    const int l    = t & 63;
    const int w    = t >> 6;
    const int qi   = blockIdx.x >> 1;
    const int head = ((blockIdx.x & 1) << 2) | w;
    const int n    = qi / LQ;
    const size_t srcbase = (size_t)n * LQ * 256;    // u16 units

    const int quad = l >> 2;   // 0..15
    const int c    = l & 3;    // 16B chunk

    // per-lane broadcast loads of the 4 key indices this quad needs
    const int* idxp = idx + (size_t)qi * 64;
    int row0 = idxp[quad];
    int row1 = idxp[16 + quad];
    int row2 = idxp[32 + quad];
    int row3 = idxp[48 + quad];

    const size_t hoff = (size_t)head * 32 + c * 8;  // u16 offset within a row

    // issue all gathers up front (quad-coalesced)
    uint4 k0 = *(const uint4*)(k + srcbase + (size_t)row0 * 256 + hoff);
    uint4 k1 = *(const uint4*)(k + srcbase + (size_t)row1 * 256 + hoff);
    uint4 k2 = *(const uint4*)(k + srcbase + (size_t)row2 * 256 + hoff);
    uint4 k3 = *(const uint4*)(k + srcbase + (size_t)row3 * 256 + hoff);
    uint4 v0 = *(const uint4*)(v + srcbase + (size_t)row0 * 256 + hoff);
    uint4 v1 = *(const uint4*)(v + srcbase + (size_t)row1 * 256 + hoff);
    uint4 v2 = *(const uint4*)(v + srcbase + (size_t)row2 * 256 + hoff);
    uint4 v3 = *(const uint4*)(v + srcbase + (size_t)row3 * 256 + hoff);
    uint4 qc = *(const uint4*)(q + (size_t)qi * 256 + hoff);

    // ---- scores: partial 8-dim f16 dots, completed within quad ----
    float s0 = 0.f, s1 = 0.f, s2 = 0.f, s3 = 0.f;
    s0 = dot2f16(k0.x, qc.x, s0); s0 = dot2f16(k0.y, qc.y, s0);
    s0 = dot2f16(k0.z, qc.z, s0); s0 = dot2f16(k0.w, qc.w, s0);
    s1 = dot2f16(k1.x, qc.x, s1); s1 = dot2f16(k1.y, qc.y, s1);
    s1 = dot2f16(k1.z, qc.z, s1); s1 = dot2f16(k1.w, qc.w, s1);
    s2 = dot2f16(k2.x, qc.x, s2); s2 = dot2f16(k2.y, qc.y, s2);
    s2 = dot2f16(k2.z, qc.z, s2); s2 = dot2f16(k2.w, qc.w, s2);
    s3 = dot2f16(k3.x, qc.x, s3); s3 = dot2f16(k3.y, qc.y, s3);
    s3 = dot2f16(k3.z, qc.z, s3); s3 = dot2f16(k3.w, qc.w, s3);

    s0 += __shfl_xor(s0, 1); s0 += __shfl_xor(s0, 2);
    s1 += __shfl_xor(s1, 1); s1 += __shfl_xor(s1, 2);
    s2 += __shfl_xor(s2, 1); s2 += __shfl_xor(s2, 2);
    s3 += __shfl_xor(s3, 1); s3 += __shfl_xor(s3, 2);

    const float scale = 0.17677669529663687f;
    s0 *= scale; s1 *= scale; s2 *= scale; s3 *= scale;

    // ---- softmax over 64 keys (quads hold disjoint key sets) ----
    float mx = fmaxf(fmaxf(s0, s1), fmaxf(s2, s3));
    mx = fmaxf(mx, __shfl_xor(mx, 4));
    mx = fmaxf(mx, __shfl_xor(mx, 8));
    mx = fmaxf(mx, __shfl_xor(mx, 16));
    mx = fmaxf(mx, __shfl_xor(mx, 32));
    float p0 = __expf(s0 - mx), p1 = __expf(s1 - mx);
    float p2 = __expf(s2 - mx), p3 = __expf(s3 - mx);
    float sum = p0 + p1 + p2 + p3;
    sum += __shfl_xor(sum, 4);
    sum += __shfl_xor(sum, 8);
    sum += __shfl_xor(sum, 16);
    sum += __shfl_xor(sum, 32);
    float inv = 1.f / sum;
    p0 *= inv; p1 *= inv; p2 *= inv; p3 *= inv;

    // ---- PV: f16 packed fma, 4 keys x 4 dim-pair-u32s per lane ----
    u32 pp0 = pkrtz(p0, p0), pp1 = pkrtz(p1, p1);
    u32 pp2 = pkrtz(p2, p2), pp3 = pkrtz(p3, p3);
    u32 A0 = 0, A1 = 0, A2 = 0, A3 = 0;
    A0 = pk_fma16(pp0, v0.x, A0); A1 = pk_fma16(pp0, v0.y, A1);
    A2 = pk_fma16(pp0, v0.z, A2); A3 = pk_fma16(pp0, v0.w, A3);
    A0 = pk_fma16(pp1, v1.x, A0); A1 = pk_fma16(pp1, v1.y, A1);
    A2 = pk_fma16(pp1, v1.z, A2); A3 = pk_fma16(pp1, v1.w, A3);
    A0 = pk_fma16(pp2, v2.x, A0); A1 = pk_fma16(pp2, v2.y, A1);
    A2 = pk_fma16(pp2, v2.z, A2); A3 = pk_fma16(pp2, v2.w, A3);
    A0 = pk_fma16(pp3, v3.x, A0); A1 = pk_fma16(pp3, v3.y, A1);
    A2 = pk_fma16(pp3, v3.z, A2); A3 = pk_fma16(pp3, v3.w, A3);

    // ---- butterfly-SPLIT reduce on packed u32s (5 shfl + 5 pk_add) ----
    const bool qb0 = (quad & 1) != 0;
    const bool qb1 = (quad & 2) != 0;
    {   // xor 4: 4 u32 -> 2
        u32 t0 = qb0 ? A0 : A2;
        u32 t1 = qb0 ? A1 : A3;
        t0 = __shfl_xor((int)t0, 4);
        t1 = __shfl_xor((int)t1, 4);
        A0 = pk_add16(qb0 ? A2 : A0, t0);
        A1 = pk_add16(qb0 ? A3 : A1, t1);
    }
    {   // xor 8: 2 u32 -> 1
        u32 u0 = qb1 ? A0 : A1;
        u0 = __shfl_xor((int)u0, 8);
        A0 = pk_add16(qb1 ? A1 : A0, u0);
    }
    A0 = pk_add16(A0, (u32)__shfl_xor((int)A0, 16));
    A0 = pk_add16(A0, (u32)__shfl_xor((int)A0, 32));

    // lane (quad<4, c) owns dim-pair j = 2*(quad&1) + ((quad>>1)&1) of chunk c
    if (quad < 4) {
        int j = 2 * (quad & 1) + ((quad >> 1) & 1);
        f16x2 hv = __builtin_bit_cast(f16x2, A0);
        u32 packed = (u32)f2bf((float)hv.x) | ((u32)f2bf((float)hv.y) << 16);
        *(u32*)(msg + (size_t)qi * 256 + head * 32 + c * 8 + j * 2) = packed;
    }
}

// ---------------------------------------------------------------------------
// LayerNorm over last dim (256), fp32 input. One block per row.
// ---------------------------------------------------------------------------
__global__ __launch_bounds__(256) void ln_kernel(
    const float* __restrict__ in, const float* __restrict__ g,
    const float* __restrict__ b, const float* __restrict__ xadd,
    void* __restrict__ out, int out_bf16)
{
    __shared__ float red[8];
    const int t = threadIdx.x;
    const size_t row = blockIdx.x;
    float val = in[row * 256 + t];

    float s = val;
#pragma unroll
    for (int off = 32; off; off >>= 1) s += __shfl_down(s, off, 64);
    if ((t & 63) == 0) red[t >> 6] = s;
    __syncthreads();
    float mu = (red[0] + red[1] + red[2] + red[3]) * 0.00390625f;

    float dv = val - mu;
    float s2 = dv * dv;
#pragma unroll
    for (int off = 32; off; off >>= 1) s2 += __shfl_down(s2, off, 64);
    if ((t & 63) == 0) red[4 + (t >> 6)] = s2;
    __syncthreads();
    float var = (red[4] + red[5] + red[6] + red[7]) * 0.00390625f;
    float rstd = rsqrtf(var + LN_EPS);

    float r = dv * rstd * g[t] + b[t];
    if (xadd) r += xadd[row * 256 + t];
    if (out_bf16) ((u16*)out)[row * 256 + t] = f2bf(r);
    else          ((float*)out)[row * 256 + t] = r;
}

// ---------------------------------------------------------------------------
extern "C" void kernel_launch(void* const* d_in, const int* in_sizes, int n_in,
                              void* d_out, int out_size, void* d_ws, size_t ws_size,
                              hipStream_t stream)
{
    const float* x      = (const float*)d_in[0];
    const float* source = (const float*)d_in[1];
    const int*   eidx   = (const int*)d_in[2];
    const float* Wq     = (const float*)d_in[3];
    const float* Wk     = (const float*)d_in[4];
    const float* Wv     = (const float*)d_in[5];
    const float* Wm     = (const float*)d_in[6];
    const float* W1     = (const float*)d_in[7];
    const float* W2     = (const float*)d_in[8];
    const float* g1     = (const float*)d_in[9];
    const float* b1     = (const float*)d_in[10];
    const float* g2     = (const float*)d_in[11];
    const float* b2     = (const float*)d_in[12];
    float* out = (float*)d_out;

    char* ws = (char*)d_ws;
    const size_t SZB = (size_t)MROWS * 256 * 2;    // 4.9 MB
    u16* xb     = (u16*)(ws);                      // bf16, live until W1 gemm
    u16* sb     = (u16*)(ws + SZB);                // bf16, dead after qkv gemm
    u16* qb     = (u16*)(ws + 2 * SZB);            // f16, qkv gemm routes here (seg 0)
    u16* kb     = (u16*)(ws + 3 * SZB);            // f16, seg 1
    u16* vb     = (u16*)(ws + 4 * SZB);            // f16, seg 2
    u16* msgb   = (u16*)(ws + 5 * SZB);            // bf16, dead after Wm gemm
    float* msgW = (float*)(ws + SZB);              // overlays sb+qb (dead)
    u16* msglnb = (u16*)(ws + 3 * SZB);            // overlays kb (dead)
    u16* h1b    = (u16*)(ws + 4 * SZB);            // [9600][512] overlays vb+msgb
    float* h2   = (float*)(ws + SZB);              // overlays msgW (dead)
    u16* Wqkvt  = (u16*)(ws + 6 * SZB);            // [768][256]
    u16* Wmt    = Wqkvt + 768 * 256;
    u16* W1t    = Wmt + 256 * 256;                 // [512][512]
    u16* W2t    = W1t + 512 * 512;                 // [256][512]

    dim3 blk(256);

    // fused prep: casts + all weight transposes
    prep_kernel<<<dim3(7360), blk, 0, stream>>>(x, source, Wq, Wk, Wv, Wm, W1, W2,
                                                xb, sb, Wqkvt, Wmt, W1t, W2t);

    // fused q|k|v projection, f16 out (A = xb for cols<256, sb for cols>=256)
    gemm_mfma_kernel<128, 128><<<dim3(6, 75), blk, 0, stream>>>(
        xb, 256, sb, 256, 0, 256, Wqkvt, 256, qb, MROWS, 768, 256, 8 | 4);

    // gathered attention -> msg (bf16); 2 blocks per query (4 heads each)
    attn_kernel<<<dim3(2 * MROWS), blk, 0, stream>>>(qb, kb, vb, eidx, msgb);

    // msg @ Wm -> fp32 (64x64 tiles: 600 blocks)
    gemm_mfma_kernel<64, 64><<<dim3(4, 150), blk, 0, stream>>>(
        msgb, 256, nullptr, 0, 0, 0, Wmt, 256, msgW, MROWS, 256, 256, 0);

    // LN1 -> bf16
    ln_kernel<<<dim3(MROWS), blk, 0, stream>>>(msgW, g1, b1, nullptr, msglnb, 1);

    // concat(x, msgln) @ W1, relu -> bf16 [9600,512] (64x64 tiles: 1200 blocks)
    gemm_mfma_kernel<64, 64><<<dim3(8, 150), blk, 0, stream>>>(
        xb, 256, msglnb, 256, 256, 0, W1t, 512, h1b, MROWS, 512, 512, 1 | 2);

    // h1 @ W2 -> fp32 (64x64 tiles: 600 blocks)
    gemm_mfma_kernel<64, 64><<<dim3(4, 150), blk, 0, stream>>>(
        h1b, 512, nullptr, 0, 0, 0, W2t, 512, h2, MROWS, 256, 512, 0);

    // out = x + LN2(h2)
    ln_kernel<<<dim3(MROWS), blk, 0, stream>>>(h2, g2, b2, x, out, 0);
}

// Round 10
// 108.263 us; speedup vs baseline: 1.6468x; 1.1649x over previous
//
#include <hip/hip_runtime.h>
#include <hip/hip_bf16.h>

#define D_MODEL 256
#define LQ 4800
#define NB 2
#define MROWS (NB * LQ)       // 9600
#define LN_EPS 1e-5f

typedef unsigned int u32;
typedef unsigned short u16;
typedef __attribute__((ext_vector_type(8))) short bf16x8;
typedef __attribute__((ext_vector_type(4))) float f32x4;
typedef __attribute__((ext_vector_type(2))) _Float16 f16x2;

__device__ __forceinline__ u16 f2bf(float f) {
    __hip_bfloat16 h = __float2bfloat16(f);
    return *reinterpret_cast<u16*>(&h);
}

// f16 pair dot into f32 (v_dot2_f32_f16)
__device__ __forceinline__ float dot2f16(u32 a, u32 b, float c) {
#if __has_builtin(__builtin_amdgcn_fdot2)
    return __builtin_amdgcn_fdot2(__builtin_bit_cast(f16x2, a),
                                  __builtin_bit_cast(f16x2, b), c, false);
#else
    f16x2 av = __builtin_bit_cast(f16x2, a), bv = __builtin_bit_cast(f16x2, b);
    c = fmaf((float)av.x, (float)bv.x, c);
    return fmaf((float)av.y, (float)bv.y, c);
#endif
}
__device__ __forceinline__ u32 pk_fma16(u32 a, u32 b, u32 c) {
    u32 d;
    asm("v_pk_fma_f16 %0, %1, %2, %3" : "=v"(d) : "v"(a), "v"(b), "v"(c));
    return d;
}
__device__ __forceinline__ u32 pk_add16(u32 a, u32 b) {
    u32 d;
    asm("v_pk_add_f16 %0, %1, %2" : "=v"(d) : "v"(a), "v"(b));
    return d;
}
__device__ __forceinline__ u32 pkrtz(float a, float b) {
    return __builtin_bit_cast(u32, __builtin_amdgcn_cvt_pkrtz(a, b));
}

// ---------------------------------------------------------------------------
// Fused prep: cast x & source to bf16; transpose+cast all weights.
// grid: [0,2400) cast x, [2400,4800) cast source, [4800,7360) weight tiles.
// Wqkvt is [768][256]: rows 0..255 Wq^T, 256..511 Wk^T, 512..767 Wv^T.
// ---------------------------------------------------------------------------
__global__ __launch_bounds__(256) void prep_kernel(
    const float* __restrict__ x, const float* __restrict__ source,
    const float* __restrict__ Wq, const float* __restrict__ Wk,
    const float* __restrict__ Wv, const float* __restrict__ Wm,
    const float* __restrict__ W1, const float* __restrict__ W2,
    u16* __restrict__ xb, u16* __restrict__ sb,
    u16* __restrict__ Wqkvt, u16* __restrict__ Wmt,
    u16* __restrict__ W1t, u16* __restrict__ W2t)
{
    __shared__ float tile[16][17];
    const int t = threadIdx.x;
    int bid = blockIdx.x;

    if (bid < 4800) {
        const float* src = bid < 2400 ? x : source;
        u16* dst = bid < 2400 ? xb : sb;
        int b = bid < 2400 ? bid : bid - 2400;
        int i = (b * 256 + t) * 4;
        float4 v = *reinterpret_cast<const float4*>(src + i);
        ushort4 o; o.x = f2bf(v.x); o.y = f2bf(v.y); o.z = f2bf(v.z); o.w = f2bf(v.w);
        *reinterpret_cast<ushort4*>(dst + i) = o;
        return;
    }
    int sub = bid - 4800;
    const float* W; u16* Wt; int Nd, ldt, rowoff;
    if      (sub < 256)  { W = Wq; Wt = Wqkvt; Nd = 256; ldt = 256; rowoff = 0;   }
    else if (sub < 512)  { W = Wk; Wt = Wqkvt; Nd = 256; ldt = 256; rowoff = 256; sub -= 256; }
    else if (sub < 768)  { W = Wv; Wt = Wqkvt; Nd = 256; ldt = 256; rowoff = 512; sub -= 512; }
    else if (sub < 1024) { W = Wm; Wt = Wmt;   Nd = 256; ldt = 256; rowoff = 0;   sub -= 768; }
    else if (sub < 2048) { W = W1; Wt = W1t;   Nd = 512; ldt = 512; rowoff = 0;   sub -= 1024; }
    else                 { W = W2; Wt = W2t;   Nd = 256; ldt = 512; rowoff = 0;   sub -= 2048; }
    int ntiles = Nd >> 4;
    int tn = sub % ntiles, tk = sub / ntiles;
    int tx = t & 15, ty = t >> 4;
    tile[ty][tx] = W[(size_t)(tk * 16 + ty) * Nd + tn * 16 + tx];
    __syncthreads();
    Wt[(size_t)(rowoff + tn * 16 + ty) * ldt + tk * 16 + tx] = f2bf(tile[tx][ty]);
}

// ---------------------------------------------------------------------------
// bf16 MFMA GEMM, templated tile: C = act(A @ Bt^T). BK=32, 256 threads,
// 2x2 waves. flags: 1=relu, 2=bf16 out, 4=route by col>>8, 8=f16 out.
// ---------------------------------------------------------------------------
template<int BM, int BN>
__global__ __launch_bounds__(256) void gemm_mfma_kernel(
    const u16* __restrict__ A0, int lda0,
    const u16* __restrict__ A1, int lda1, int splitK, int nsel,
    const u16* __restrict__ Bt, int ldb,
    void* __restrict__ Cout,
    int M, int N, int K, int flags)
{
    __shared__ __align__(16) u16 As[BM * 32];
    __shared__ __align__(16) u16 Bs[BN * 32];

    constexpr int WM = BM / 2, WN = BN / 2;
    constexpr int FI = WM / 16, FJ = WN / 16;

    const int t  = threadIdx.x;
    const int l  = t & 63;
    const int w  = t >> 6;
    const int m0 = blockIdx.y * BM;
    const int n0 = blockIdx.x * BN;
    const int wr = w >> 1, wc = w & 1;

    if (nsel && n0 >= nsel) { A0 = A1; lda0 = lda1; }

    const int srow = l >> 2;
    const int sch  = (l & 3) ^ (srow & 3);

    f32x4 acc[FI][FJ];
#pragma unroll
    for (int i = 0; i < FI; ++i)
#pragma unroll
        for (int j = 0; j < FJ; ++j) acc[i][j] = (f32x4){0.f, 0.f, 0.f, 0.f};

    for (int k0 = 0; k0 < K; k0 += 32) {
        const u16* Ap; int kk, lda;
        if (splitK && k0 >= splitK) { Ap = A1; kk = k0 - splitK; lda = lda1; }
        else                        { Ap = A0; kk = k0;          lda = lda0; }

#pragma unroll
        for (int g = 0; g < BM / 64; ++g) {
            int grp = w * (BM / 64) + g;
            int row = grp * 16 + srow;
            const u16* asrc = Ap + (size_t)(m0 + row) * lda + kk + sch * 8;
            u32* adst = (u32*)(As + grp * 512);
            __builtin_amdgcn_global_load_lds(
                (const __attribute__((address_space(1))) u32*)asrc,
                (__attribute__((address_space(3))) u32*)adst, 16, 0, 0);
        }
#pragma unroll
        for (int g = 0; g < BN / 64; ++g) {
            int grp = w * (BN / 64) + g;
            int row = grp * 16 + srow;
            const u16* bsrc = Bt + (size_t)(n0 + row) * ldb + k0 + sch * 8;
            u32* bdst = (u32*)(Bs + grp * 512);
            __builtin_amdgcn_global_load_lds(
                (const __attribute__((address_space(1))) u32*)bsrc,
                (__attribute__((address_space(3))) u32*)bdst, 16, 0, 0);
        }
        __syncthreads();

        const int r  = l & 15;
        const int ch = l >> 4;
        bf16x8 af[FI], bfr[FJ];
#pragma unroll
        for (int i = 0; i < FI; ++i) {
            int ar = wr * WM + i * 16 + r;
            af[i] = *(const bf16x8*)((const char*)As + ar * 64 + ((ch ^ (r & 3)) * 16));
        }
#pragma unroll
        for (int j = 0; j < FJ; ++j) {
            int br = wc * WN + j * 16 + r;
            bfr[j] = *(const bf16x8*)((const char*)Bs + br * 64 + ((ch ^ (r & 3)) * 16));
        }
#pragma unroll
        for (int i = 0; i < FI; ++i)
#pragma unroll
            for (int j = 0; j < FJ; ++j)
                acc[i][j] = __builtin_amdgcn_mfma_f32_16x16x32_bf16(af[i], bfr[j], acc[i][j], 0, 0, 0);
        __syncthreads();
    }

    const int r  = l & 15;
    const int q4 = l >> 4;
#pragma unroll
    for (int i = 0; i < FI; ++i)
#pragma unroll
        for (int j = 0; j < FJ; ++j) {
            int col = n0 + wc * WN + j * 16 + r;
#pragma unroll
            for (int reg = 0; reg < 4; ++reg) {
                int row = m0 + wr * WM + i * 16 + q4 * 4 + reg;
                float vv = acc[i][j][reg];
                if (flags & 1) vv = fmaxf(vv, 0.f);
                size_t off;
                int colw, Nw;
                if (flags & 4) { off = (size_t)(col >> 8) * M * 256; colw = col & 255; Nw = 256; }
                else           { off = 0; colw = col; Nw = N; }
                if (flags & 8) {
                    _Float16 hv = (_Float16)vv;
                    ((u16*)Cout)[off + (size_t)row * Nw + colw] = __builtin_bit_cast(u16, hv);
                } else if (flags & 2) {
                    ((u16*)Cout)[off + (size_t)row * Nw + colw] = f2bf(vv);
                } else {
                    ((float*)Cout)[off + (size_t)row * Nw + colw] = vv;
                }
            }
        }
}

// ---------------------------------------------------------------------------
// GEMM (BM=64, BN=256 full row) with fused LayerNorm epilogue.
// C_row = LN(A@Bt^T)[row] * g + b  (+ xres[row] if RESID). One block = 64 rows.
// OUT_BF16: write bf16, else fp32.
// ---------------------------------------------------------------------------
template<bool RESID, bool OUT_BF16>
__global__ __launch_bounds__(256) void gemm_ln_kernel(
    const u16* __restrict__ A, int lda,
    const u16* __restrict__ Bt, int ldb,
    const float* __restrict__ g, const float* __restrict__ b,
    const float* __restrict__ xres,
    void* __restrict__ Cout, int K)
{
    __shared__ __align__(16) u16 As[64 * 32];
    __shared__ __align__(16) u16 Bs[256 * 32];
    __shared__ float2 red[64][2];

    const int t  = threadIdx.x;
    const int l  = t & 63;
    const int w  = t >> 6;
    const int m0 = blockIdx.x * 64;
    const int wr = w >> 1, wc = w & 1;

    const int srow = l >> 2;
    const int sch  = (l & 3) ^ (srow & 3);

    f32x4 acc[2][8];
#pragma unroll
    for (int i = 0; i < 2; ++i)
#pragma unroll
        for (int j = 0; j < 8; ++j) acc[i][j] = (f32x4){0.f, 0.f, 0.f, 0.f};

    for (int k0 = 0; k0 < K; k0 += 32) {
        {   // A tile: 64 rows, one 16-row group per wave
            int row = w * 16 + srow;
            const u16* asrc = A + (size_t)(m0 + row) * lda + k0 + sch * 8;
            u32* adst = (u32*)(As + w * 512);
            __builtin_amdgcn_global_load_lds(
                (const __attribute__((address_space(1))) u32*)asrc,
                (__attribute__((address_space(3))) u32*)adst, 16, 0, 0);
        }
#pragma unroll
        for (int gg = 0; gg < 4; ++gg) {   // B tile: 256 rows
            int grp = w * 4 + gg;
            int row = grp * 16 + srow;
            const u16* bsrc = Bt + (size_t)row * ldb + k0 + sch * 8;
            u32* bdst = (u32*)(Bs + grp * 512);
            __builtin_amdgcn_global_load_lds(
                (const __attribute__((address_space(1))) u32*)bsrc,
                (__attribute__((address_space(3))) u32*)bdst, 16, 0, 0);
        }
        __syncthreads();

        const int r  = l & 15;
        const int ch = l >> 4;
        bf16x8 af[2], bfr[8];
#pragma unroll
        for (int i = 0; i < 2; ++i) {
            int ar = wr * 32 + i * 16 + r;
            af[i] = *(const bf16x8*)((const char*)As + ar * 64 + ((ch ^ (r & 3)) * 16));
        }
#pragma unroll
        for (int j = 0; j < 8; ++j) {
            int br = wc * 128 + j * 16 + r;
            bfr[j] = *(const bf16x8*)((const char*)Bs + br * 64 + ((ch ^ (r & 3)) * 16));
        }
#pragma unroll
        for (int i = 0; i < 2; ++i)
#pragma unroll
            for (int j = 0; j < 8; ++j)
                acc[i][j] = __builtin_amdgcn_mfma_f32_16x16x32_bf16(af[i], bfr[j], acc[i][j], 0, 0, 0);
        __syncthreads();
    }

    const int r  = l & 15;
    const int q4 = l >> 4;

    // ---- row partial sums over this thread's 8 cols per row-slot ----
    float rs[2][4], rq[2][4];
#pragma unroll
    for (int i = 0; i < 2; ++i)
#pragma unroll
        for (int reg = 0; reg < 4; ++reg) {
            float s = 0.f, sq = 0.f;
#pragma unroll
            for (int j = 0; j < 8; ++j) {
                float vv = acc[i][j][reg];
                s += vv; sq += vv * vv;
            }
            rs[i][reg] = s; rq[i][reg] = sq;
        }
#pragma unroll
    for (int off = 1; off <= 8; off <<= 1)
#pragma unroll
        for (int i = 0; i < 2; ++i)
#pragma unroll
            for (int reg = 0; reg < 4; ++reg) {
                rs[i][reg] += __shfl_xor(rs[i][reg], off);
                rq[i][reg] += __shfl_xor(rq[i][reg], off);
            }
    if (r == 0) {
#pragma unroll
        for (int i = 0; i < 2; ++i)
#pragma unroll
            for (int reg = 0; reg < 4; ++reg) {
                int row = wr * 32 + i * 16 + q4 * 4 + reg;
                red[row][wc] = make_float2(rs[i][reg], rq[i][reg]);
            }
    }
    __syncthreads();

    // preload g,b for this thread's 8 cols
    float gj[8], bj[8];
#pragma unroll
    for (int j = 0; j < 8; ++j) {
        int col = wc * 128 + j * 16 + r;
        gj[j] = g[col]; bj[j] = b[col];
    }

#pragma unroll
    for (int i = 0; i < 2; ++i)
#pragma unroll
        for (int reg = 0; reg < 4; ++reg) {
            int row = wr * 32 + i * 16 + q4 * 4 + reg;
            float2 t0 = red[row][0], t1 = red[row][1];
            float mu  = (t0.x + t1.x) * 0.00390625f;
            float var = (t0.y + t1.y) * 0.00390625f - mu * mu;
            float rstd = rsqrtf(var + LN_EPS);
#pragma unroll
            for (int j = 0; j < 8; ++j) {
                int col = wc * 128 + j * 16 + r;
                float vv = (acc[i][j][reg] - mu) * rstd * gj[j] + bj[j];
                size_t oidx = (size_t)(m0 + row) * 256 + col;
                if (RESID) vv += xres[oidx];
                if (OUT_BF16) ((u16*)Cout)[oidx] = f2bf(vv);
                else          ((float*)Cout)[oidx] = vv;
            }
        }
}

// ---------------------------------------------------------------------------
// Gathered attention: wave = (query, head-pair), 128B oct-coalesced gathers.
// q,k,v: [MROWS,256] fp16 head-major. msg out: bf16. Block = 1 query, 4 waves.
// Lane: o = l>>3 (key-set: keys {i*8+o}), c = l&7 (16B chunk of the 128B
// two-head slice). 8 lanes of an o-group read 8 contiguous 16B chunks of one
// key row -> 8 x 128B lines per gather instr (half of round-8's 16 x 64B).
// No LDS, no barriers. Scores dot2+xor1/2; softmax over o-bits (xor8/16/32);
// PV 32x v_pk_fma_f16 + packed split reduce (4 shfl).
// ---------------------------------------------------------------------------
__global__ __launch_bounds__(256) void attn_kernel(
    const u16* __restrict__ q, const u16* __restrict__ k,
    const u16* __restrict__ v, const int* __restrict__ idx,
    u16* __restrict__ msg)
{
    const int t  = threadIdx.x;
    const int l  = t & 63;
    const int hp = t >> 6;              // head-pair 0..3
    const int qi = blockIdx.x;
    const int n  = qi / LQ;
    const size_t srcbase = (size_t)n * LQ * 256;   // u16 units

    const int o = l >> 3;   // key-set 0..7
    const int c = l & 7;    // 16B chunk of 128B slice

    const int* idxp = idx + (size_t)qi * 64;
    int rows[8];
#pragma unroll
    for (int i = 0; i < 8; ++i) rows[i] = idxp[i * 8 + o];   // 8-lane broadcast

    const size_t hoff = (size_t)hp * 64 + c * 8;   // u16 offset in a row

    // issue all gathers up front
    uint4 kd[8], vd[8];
#pragma unroll
    for (int i = 0; i < 8; ++i)
        kd[i] = *(const uint4*)(k + srcbase + (size_t)rows[i] * 256 + hoff);
#pragma unroll
    for (int i = 0; i < 8; ++i)
        vd[i] = *(const uint4*)(v + srcbase + (size_t)rows[i] * 256 + hoff);
    uint4 qc = *(const uint4*)(q + (size_t)qi * 256 + hoff);

    // ---- scores: 8-dim partials completed within the 4-lane chunk group ----
    float s[8];
#pragma unroll
    for (int i = 0; i < 8; ++i) {
        float si = 0.f;
        si = dot2f16(kd[i].x, qc.x, si);
        si = dot2f16(kd[i].y, qc.y, si);
        si = dot2f16(kd[i].z, qc.z, si);
        si = dot2f16(kd[i].w, qc.w, si);
        si += __shfl_xor(si, 1);
        si += __shfl_xor(si, 2);
        s[i] = si * 0.17677669529663687f;
    }

    // ---- softmax over 64 keys (o-sets disjoint; reduce over o bits) ----
    float mx = s[0];
#pragma unroll
    for (int i = 1; i < 8; ++i) mx = fmaxf(mx, s[i]);
    mx = fmaxf(mx, __shfl_xor(mx, 8));
    mx = fmaxf(mx, __shfl_xor(mx, 16));
    mx = fmaxf(mx, __shfl_xor(mx, 32));
    float p[8], sum = 0.f;
#pragma unroll
    for (int i = 0; i < 8; ++i) { p[i] = __expf(s[i] - mx); sum += p[i]; }
    sum += __shfl_xor(sum, 8);
    sum += __shfl_xor(sum, 16);
    sum += __shfl_xor(sum, 32);
    float inv = 1.f / sum;

    // ---- PV: 8 keys x 4 dim-pair u32s, f16 packed fma ----
    u32 A0 = 0, A1 = 0, A2 = 0, A3 = 0;
#pragma unroll
    for (int i = 0; i < 8; ++i) {
        float pi = p[i] * inv;
        u32 pp = pkrtz(pi, pi);
        A0 = pk_fma16(pp, vd[i].x, A0);
        A1 = pk_fma16(pp, vd[i].y, A1);
        A2 = pk_fma16(pp, vd[i].z, A2);
        A3 = pk_fma16(pp, vd[i].w, A3);
    }

    // ---- split-reduce over the 8 o-sets (lane bits 3,4,5) ----
    const bool ob0 = (o & 1) != 0;
    const bool ob1 = (o & 2) != 0;
    {   // xor 8: 4 u32 -> 2
        u32 t0 = ob0 ? A0 : A2;
        u32 t1 = ob0 ? A1 : A3;
        t0 = __shfl_xor((int)t0, 8);
        t1 = __shfl_xor((int)t1, 8);
        A0 = pk_add16(ob0 ? A2 : A0, t0);
        A1 = pk_add16(ob0 ? A3 : A1, t1);
    }
    {   // xor 16: 2 u32 -> 1
        u32 u0 = ob1 ? A0 : A1;
        u0 = __shfl_xor((int)u0, 16);
        A0 = pk_add16(ob1 ? A1 : A0, u0);
    }
    A0 = pk_add16(A0, (u32)__shfl_xor((int)A0, 32));

    // lane (o<4, c) owns u32 slot j = 2*(o&1) + ((o>>1)&1) of chunk c
    if (o < 4) {
        int j = 2 * (o & 1) + ((o >> 1) & 1);
        f16x2 hv = __builtin_bit_cast(f16x2, A0);
        u32 packed = (u32)f2bf((float)hv.x) | ((u32)f2bf((float)hv.y) << 16);
        *(u32*)(msg + (size_t)qi * 256 + hp * 64 + c * 8 + j * 2) = packed;
    }
}

// ---------------------------------------------------------------------------
extern "C" void kernel_launch(void* const* d_in, const int* in_sizes, int n_in,
                              void* d_out, int out_size, void* d_ws, size_t ws_size,
                              hipStream_t stream)
{
    const float* x      = (const float*)d_in[0];
    const float* source = (const float*)d_in[1];
    const int*   eidx   = (const int*)d_in[2];
    const float* Wq     = (const float*)d_in[3];
    const float* Wk     = (const float*)d_in[4];
    const float* Wv     = (const float*)d_in[5];
    const float* Wm     = (const float*)d_in[6];
    const float* W1     = (const float*)d_in[7];
    const float* W2     = (const float*)d_in[8];
    const float* g1     = (const float*)d_in[9];
    const float* b1     = (const float*)d_in[10];
    const float* g2     = (const float*)d_in[11];
    const float* b2     = (const float*)d_in[12];
    float* out = (float*)d_out;

    char* ws = (char*)d_ws;
    const size_t SZB = (size_t)MROWS * 256 * 2;    // 4.9 MB
    u16* xb     = (u16*)(ws);                      // bf16, live until W1 gemm
    u16* sb     = (u16*)(ws + SZB);                // bf16, dead after qkv gemm
    u16* qb     = (u16*)(ws + 2 * SZB);            // f16, qkv gemm seg 0
    u16* kb     = (u16*)(ws + 3 * SZB);            // f16, seg 1
    u16* vb     = (u16*)(ws + 4 * SZB);            // f16, seg 2
    u16* msgb   = (u16*)(ws + 5 * SZB);            // bf16, dead after Wm gemm
    u16* msglnb = (u16*)(ws + 6 * SZB);            // bf16 LN1 output
    u16* h1b    = (u16*)(ws + 7 * SZB);            // bf16 [9600][512]
    u16* Wqkvt  = (u16*)(ws + 9 * SZB);            // [768][256]
    u16* Wmt    = Wqkvt + 768 * 256;
    u16* W1t    = Wmt + 256 * 256;                 // [512][512]
    u16* W2t    = W1t + 512 * 512;                 // [256][512]

    dim3 blk(256);

    // fused prep: casts + all weight transposes
    prep_kernel<<<dim3(7360), blk, 0, stream>>>(x, source, Wq, Wk, Wv, Wm, W1, W2,
                                                xb, sb, Wqkvt, Wmt, W1t, W2t);

    // fused q|k|v projection, f16 out (A = xb for cols<256, sb for cols>=256)
    gemm_mfma_kernel<128, 128><<<dim3(6, 75), blk, 0, stream>>>(
        xb, 256, sb, 256, 0, 256, Wqkvt, 256, qb, MROWS, 768, 256, 8 | 4);

    // gathered attention -> msg (bf16); one block per query
    attn_kernel<<<dim3(MROWS), blk, 0, stream>>>(qb, kb, vb, eidx, msgb);

    // msg @ Wm + LN1 fused -> bf16 msglnb (150 blocks of 64 rows)
    gemm_ln_kernel<false, true><<<dim3(150), blk, 0, stream>>>(
        msgb, 256, Wmt, 256, g1, b1, nullptr, msglnb, 256);

    // concat(x, msgln) @ W1, relu -> bf16 [9600,512] (64x64 tiles, 1200 blocks)
    gemm_mfma_kernel<64, 64><<<dim3(8, 150), blk, 0, stream>>>(
        xb, 256, msglnb, 256, 256, 0, W1t, 512, h1b, MROWS, 512, 512, 1 | 2);

    // h1 @ W2 + LN2 + residual fused -> fp32 out
    gemm_ln_kernel<true, false><<<dim3(150), blk, 0, stream>>>(
        h1b, 512, W2t, 512, g2, b2, x, out, 512);
}

// Round 11
// 101.173 us; speedup vs baseline: 1.7622x; 1.0701x over previous
//
#include <hip/hip_runtime.h>
#include <hip/hip_bf16.h>

#define D_MODEL 256
#define LQ 4800
#define NB 2
#define MROWS (NB * LQ)       // 9600
#define LN_EPS 1e-5f

typedef unsigned int u32;
typedef unsigned short u16;
typedef __attribute__((ext_vector_type(8))) short bf16x8;
typedef __attribute__((ext_vector_type(4))) float f32x4;
typedef __attribute__((ext_vector_type(2))) _Float16 f16x2;

__device__ __forceinline__ u16 f2bf(float f) {
    __hip_bfloat16 h = __float2bfloat16(f);
    return *reinterpret_cast<u16*>(&h);
}

// f16 pair dot into f32 (v_dot2_f32_f16)
__device__ __forceinline__ float dot2f16(u32 a, u32 b, float c) {
#if __has_builtin(__builtin_amdgcn_fdot2)
    return __builtin_amdgcn_fdot2(__builtin_bit_cast(f16x2, a),
                                  __builtin_bit_cast(f16x2, b), c, false);
#else
    f16x2 av = __builtin_bit_cast(f16x2, a), bv = __builtin_bit_cast(f16x2, b);
    c = fmaf((float)av.x, (float)bv.x, c);
    return fmaf((float)av.y, (float)bv.y, c);
#endif
}
__device__ __forceinline__ u32 pk_fma16(u32 a, u32 b, u32 c) {
    u32 d;
    asm("v_pk_fma_f16 %0, %1, %2, %3" : "=v"(d) : "v"(a), "v"(b), "v"(c));
    return d;
}
__device__ __forceinline__ u32 pk_add16(u32 a, u32 b) {
    u32 d;
    asm("v_pk_add_f16 %0, %1, %2" : "=v"(d) : "v"(a), "v"(b));
    return d;
}
__device__ __forceinline__ u32 pkrtz(float a, float b) {
    return __builtin_bit_cast(u32, __builtin_amdgcn_cvt_pkrtz(a, b));
}

// ---------------------------------------------------------------------------
// Fused prep: cast x & source to bf16; transpose+cast all weights.
// grid: [0,2400) cast x, [2400,4800) cast source, [4800,7360) weight tiles.
// Wqkvt is [768][256]: rows 0..255 Wq^T, 256..511 Wk^T, 512..767 Wv^T.
// ---------------------------------------------------------------------------
__global__ __launch_bounds__(256) void prep_kernel(
    const float* __restrict__ x, const float* __restrict__ source,
    const float* __restrict__ Wq, const float* __restrict__ Wk,
    const float* __restrict__ Wv, const float* __restrict__ Wm,
    const float* __restrict__ W1, const float* __restrict__ W2,
    u16* __restrict__ xb, u16* __restrict__ sb,
    u16* __restrict__ Wqkvt, u16* __restrict__ Wmt,
    u16* __restrict__ W1t, u16* __restrict__ W2t)
{
    __shared__ float tile[16][17];
    const int t = threadIdx.x;
    int bid = blockIdx.x;

    if (bid < 4800) {
        const float* src = bid < 2400 ? x : source;
        u16* dst = bid < 2400 ? xb : sb;
        int b = bid < 2400 ? bid : bid - 2400;
        int i = (b * 256 + t) * 4;
        float4 v = *reinterpret_cast<const float4*>(src + i);
        ushort4 o; o.x = f2bf(v.x); o.y = f2bf(v.y); o.z = f2bf(v.z); o.w = f2bf(v.w);
        *reinterpret_cast<ushort4*>(dst + i) = o;
        return;
    }
    int sub = bid - 4800;
    const float* W; u16* Wt; int Nd, ldt, rowoff;
    if      (sub < 256)  { W = Wq; Wt = Wqkvt; Nd = 256; ldt = 256; rowoff = 0;   }
    else if (sub < 512)  { W = Wk; Wt = Wqkvt; Nd = 256; ldt = 256; rowoff = 256; sub -= 256; }
    else if (sub < 768)  { W = Wv; Wt = Wqkvt; Nd = 256; ldt = 256; rowoff = 512; sub -= 512; }
    else if (sub < 1024) { W = Wm; Wt = Wmt;   Nd = 256; ldt = 256; rowoff = 0;   sub -= 768; }
    else if (sub < 2048) { W = W1; Wt = W1t;   Nd = 512; ldt = 512; rowoff = 0;   sub -= 1024; }
    else                 { W = W2; Wt = W2t;   Nd = 256; ldt = 512; rowoff = 0;   sub -= 2048; }
    int ntiles = Nd >> 4;
    int tn = sub % ntiles, tk = sub / ntiles;
    int tx = t & 15, ty = t >> 4;
    tile[ty][tx] = W[(size_t)(tk * 16 + ty) * Nd + tn * 16 + tx];
    __syncthreads();
    Wt[(size_t)(rowoff + tn * 16 + ty) * ldt + tk * 16 + tx] = f2bf(tile[tx][ty]);
}

// ---------------------------------------------------------------------------
// bf16 MFMA GEMM, templated tile: C = act(A @ Bt^T). BK=32, 256 threads,
// 2x2 waves. flags: 1=relu, 2=bf16 out, 4=route by col>>8, 8=f16 out.
// ---------------------------------------------------------------------------
template<int BM, int BN>
__global__ __launch_bounds__(256) void gemm_mfma_kernel(
    const u16* __restrict__ A0, int lda0,
    const u16* __restrict__ A1, int lda1, int splitK, int nsel,
    const u16* __restrict__ Bt, int ldb,
    void* __restrict__ Cout,
    int M, int N, int K, int flags)
{
    __shared__ __align__(16) u16 As[BM * 32];
    __shared__ __align__(16) u16 Bs[BN * 32];

    constexpr int WM = BM / 2, WN = BN / 2;
    constexpr int FI = WM / 16, FJ = WN / 16;

    const int t  = threadIdx.x;
    const int l  = t & 63;
    const int w  = t >> 6;
    const int m0 = blockIdx.y * BM;
    const int n0 = blockIdx.x * BN;
    const int wr = w >> 1, wc = w & 1;

    if (nsel && n0 >= nsel) { A0 = A1; lda0 = lda1; }

    const int srow = l >> 2;
    const int sch  = (l & 3) ^ (srow & 3);

    f32x4 acc[FI][FJ];
#pragma unroll
    for (int i = 0; i < FI; ++i)
#pragma unroll
        for (int j = 0; j < FJ; ++j) acc[i][j] = (f32x4){0.f, 0.f, 0.f, 0.f};

    for (int k0 = 0; k0 < K; k0 += 32) {
        const u16* Ap; int kk, lda;
        if (splitK && k0 >= splitK) { Ap = A1; kk = k0 - splitK; lda = lda1; }
        else                        { Ap = A0; kk = k0;          lda = lda0; }

        if (BM >= 64) {
#pragma unroll
            for (int g = 0; g < BM / 64; ++g) {
                int grp = w * (BM / 64) + g;
                int row = grp * 16 + srow;
                const u16* asrc = Ap + (size_t)(m0 + row) * lda + kk + sch * 8;
                u32* adst = (u32*)(As + grp * 512);
                __builtin_amdgcn_global_load_lds(
                    (const __attribute__((address_space(1))) u32*)asrc,
                    (__attribute__((address_space(3))) u32*)adst, 16, 0, 0);
            }
        } else if (w < BM / 16) {
            int row = w * 16 + srow;
            const u16* asrc = Ap + (size_t)(m0 + row) * lda + kk + sch * 8;
            u32* adst = (u32*)(As + w * 512);
            __builtin_amdgcn_global_load_lds(
                (const __attribute__((address_space(1))) u32*)asrc,
                (__attribute__((address_space(3))) u32*)adst, 16, 0, 0);
        }
#pragma unroll
        for (int g = 0; g < BN / 64; ++g) {
            int grp = w * (BN / 64) + g;
            int row = grp * 16 + srow;
            const u16* bsrc = Bt + (size_t)(n0 + row) * ldb + k0 + sch * 8;
            u32* bdst = (u32*)(Bs + grp * 512);
            __builtin_amdgcn_global_load_lds(
                (const __attribute__((address_space(1))) u32*)bsrc,
                (__attribute__((address_space(3))) u32*)bdst, 16, 0, 0);
        }
        __syncthreads();

        const int r  = l & 15;
        const int ch = l >> 4;
        bf16x8 af[FI], bfr[FJ];
#pragma unroll
        for (int i = 0; i < FI; ++i) {
            int ar = wr * WM + i * 16 + r;
            af[i] = *(const bf16x8*)((const char*)As + ar * 64 + ((ch ^ (r & 3)) * 16));
        }
#pragma unroll
        for (int j = 0; j < FJ; ++j) {
            int br = wc * WN + j * 16 + r;
            bfr[j] = *(const bf16x8*)((const char*)Bs + br * 64 + ((ch ^ (r & 3)) * 16));
        }
#pragma unroll
        for (int i = 0; i < FI; ++i)
#pragma unroll
            for (int j = 0; j < FJ; ++j)
                acc[i][j] = __builtin_amdgcn_mfma_f32_16x16x32_bf16(af[i], bfr[j], acc[i][j], 0, 0, 0);
        __syncthreads();
    }

    const int r  = l & 15;
    const int q4 = l >> 4;
#pragma unroll
    for (int i = 0; i < FI; ++i)
#pragma unroll
        for (int j = 0; j < FJ; ++j) {
            int col = n0 + wc * WN + j * 16 + r;
#pragma unroll
            for (int reg = 0; reg < 4; ++reg) {
                int row = m0 + wr * WM + i * 16 + q4 * 4 + reg;
                float vv = acc[i][j][reg];
                if (flags & 1) vv = fmaxf(vv, 0.f);
                size_t off;
                int colw, Nw;
                if (flags & 4) { off = (size_t)(col >> 8) * M * 256; colw = col & 255; Nw = 256; }
                else           { off = 0; colw = col; Nw = N; }
                if (flags & 8) {
                    _Float16 hv = (_Float16)vv;
                    ((u16*)Cout)[off + (size_t)row * Nw + colw] = __builtin_bit_cast(u16, hv);
                } else if (flags & 2) {
                    ((u16*)Cout)[off + (size_t)row * Nw + colw] = f2bf(vv);
                } else {
                    ((float*)Cout)[off + (size_t)row * Nw + colw] = vv;
                }
            }
        }
}

// ---------------------------------------------------------------------------
// GEMM (BM rows, BN=256 full row) with fused LayerNorm epilogue.
// C_row = LN(A@Bt^T)[row] * g + b  (+ xres[row] if RESID). One block = BM rows.
// BM in {32, 64}. OUT_BF16: write bf16, else fp32.
// ---------------------------------------------------------------------------
template<int BM, bool RESID, bool OUT_BF16>
__global__ __launch_bounds__(256) void gemm_ln_kernel(
    const u16* __restrict__ A, int lda,
    const u16* __restrict__ Bt, int ldb,
    const float* __restrict__ g, const float* __restrict__ b,
    const float* __restrict__ xres,
    void* __restrict__ Cout, int K)
{
    __shared__ __align__(16) u16 As[BM * 32];
    __shared__ __align__(16) u16 Bs[256 * 32];
    __shared__ float2 red[BM][2];

    constexpr int WM = BM / 2;      // 16 or 32
    constexpr int FI = WM / 16;     // 1 or 2

    const int t  = threadIdx.x;
    const int l  = t & 63;
    const int w  = t >> 6;
    const int m0 = blockIdx.x * BM;
    const int wr = w >> 1, wc = w & 1;

    const int srow = l >> 2;
    const int sch  = (l & 3) ^ (srow & 3);

    f32x4 acc[FI][8];
#pragma unroll
    for (int i = 0; i < FI; ++i)
#pragma unroll
        for (int j = 0; j < 8; ++j) acc[i][j] = (f32x4){0.f, 0.f, 0.f, 0.f};

    for (int k0 = 0; k0 < K; k0 += 32) {
        if (w < BM / 16) {   // A tile: BM rows, one 16-row group per wave
            int row = w * 16 + srow;
            const u16* asrc = A + (size_t)(m0 + row) * lda + k0 + sch * 8;
            u32* adst = (u32*)(As + w * 512);
            __builtin_amdgcn_global_load_lds(
                (const __attribute__((address_space(1))) u32*)asrc,
                (__attribute__((address_space(3))) u32*)adst, 16, 0, 0);
        }
#pragma unroll
        for (int gg = 0; gg < 4; ++gg) {   // B tile: 256 rows
            int grp = w * 4 + gg;
            int row = grp * 16 + srow;
            const u16* bsrc = Bt + (size_t)row * ldb + k0 + sch * 8;
            u32* bdst = (u32*)(Bs + grp * 512);
            __builtin_amdgcn_global_load_lds(
                (const __attribute__((address_space(1))) u32*)bsrc,
                (__attribute__((address_space(3))) u32*)bdst, 16, 0, 0);
        }
        __syncthreads();

        const int r  = l & 15;
        const int ch = l >> 4;
        bf16x8 af[FI], bfr[8];
#pragma unroll
        for (int i = 0; i < FI; ++i) {
            int ar = wr * WM + i * 16 + r;
            af[i] = *(const bf16x8*)((const char*)As + ar * 64 + ((ch ^ (r & 3)) * 16));
        }
#pragma unroll
        for (int j = 0; j < 8; ++j) {
            int br = wc * 128 + j * 16 + r;
            bfr[j] = *(const bf16x8*)((const char*)Bs + br * 64 + ((ch ^ (r & 3)) * 16));
        }
#pragma unroll
        for (int i = 0; i < FI; ++i)
#pragma unroll
            for (int j = 0; j < 8; ++j)
                acc[i][j] = __builtin_amdgcn_mfma_f32_16x16x32_bf16(af[i], bfr[j], acc[i][j], 0, 0, 0);
        __syncthreads();
    }

    const int r  = l & 15;
    const int q4 = l >> 4;

    // ---- row partial sums over this thread's 8 cols per row-slot ----
    float rs[FI][4], rq[FI][4];
#pragma unroll
    for (int i = 0; i < FI; ++i)
#pragma unroll
        for (int reg = 0; reg < 4; ++reg) {
            float s = 0.f, sq = 0.f;
#pragma unroll
            for (int j = 0; j < 8; ++j) {
                float vv = acc[i][j][reg];
                s += vv; sq += vv * vv;
            }
            rs[i][reg] = s; rq[i][reg] = sq;
        }
#pragma unroll
    for (int off = 1; off <= 8; off <<= 1)
#pragma unroll
        for (int i = 0; i < FI; ++i)
#pragma unroll
            for (int reg = 0; reg < 4; ++reg) {
                rs[i][reg] += __shfl_xor(rs[i][reg], off);
                rq[i][reg] += __shfl_xor(rq[i][reg], off);
            }
    if (r == 0) {
#pragma unroll
        for (int i = 0; i < FI; ++i)
#pragma unroll
            for (int reg = 0; reg < 4; ++reg) {
                int row = wr * WM + i * 16 + q4 * 4 + reg;
                red[row][wc] = make_float2(rs[i][reg], rq[i][reg]);
            }
    }
    __syncthreads();

    // preload g,b for this thread's 8 cols
    float gj[8], bj[8];
#pragma unroll
    for (int j = 0; j < 8; ++j) {
        int col = wc * 128 + j * 16 + r;
        gj[j] = g[col]; bj[j] = b[col];
    }

#pragma unroll
    for (int i = 0; i < FI; ++i)
#pragma unroll
        for (int reg = 0; reg < 4; ++reg) {
            int row = wr * WM + i * 16 + q4 * 4 + reg;
            float2 t0 = red[row][0], t1 = red[row][1];
            float mu  = (t0.x + t1.x) * 0.00390625f;
            float var = (t0.y + t1.y) * 0.00390625f - mu * mu;
            float rstd = rsqrtf(var + LN_EPS);
#pragma unroll
            for (int j = 0; j < 8; ++j) {
                int col = wc * 128 + j * 16 + r;
                float vv = (acc[i][j][reg] - mu) * rstd * gj[j] + bj[j];
                size_t oidx = (size_t)(m0 + row) * 256 + col;
                if (RESID) vv += xres[oidx];
                if (OUT_BF16) ((u16*)Cout)[oidx] = f2bf(vv);
                else          ((float*)Cout)[oidx] = vv;
            }
        }
}

// ---------------------------------------------------------------------------
// Gathered attention: wave = (query, head-pair), 128B oct-coalesced gathers.
// q,k,v: [MROWS,256] fp16 head-major. msg out: bf16. Block = 1 query, 4 waves.
// Lane: o = l>>3 (key-set), c = l&7 (16B chunk of the 128B two-head slice).
// No LDS, no barriers. Scores dot2+xor1/2; softmax over o-bits (xor8/16/32);
// PV 32x v_pk_fma_f16 + packed split reduce (4 shfl).
// ---------------------------------------------------------------------------
__global__ __launch_bounds__(256) void attn_kernel(
    const u16* __restrict__ q, const u16* __restrict__ k,
    const u16* __restrict__ v, const int* __restrict__ idx,
    u16* __restrict__ msg)
{
    const int t  = threadIdx.x;
    const int l  = t & 63;
    const int hp = t >> 6;              // head-pair 0..3
    const int qi = blockIdx.x;
    const int n  = qi / LQ;
    const size_t srcbase = (size_t)n * LQ * 256;   // u16 units

    const int o = l >> 3;   // key-set 0..7
    const int c = l & 7;    // 16B chunk of 128B slice

    const int* idxp = idx + (size_t)qi * 64;
    int rows[8];
#pragma unroll
    for (int i = 0; i < 8; ++i) rows[i] = idxp[i * 8 + o];   // 8-lane broadcast

    const size_t hoff = (size_t)hp * 64 + c * 8;   // u16 offset in a row

    // issue all gathers up front
    uint4 kd[8], vd[8];
#pragma unroll
    for (int i = 0; i < 8; ++i)
        kd[i] = *(const uint4*)(k + srcbase + (size_t)rows[i] * 256 + hoff);
#pragma unroll
    for (int i = 0; i < 8; ++i)
        vd[i] = *(const uint4*)(v + srcbase + (size_t)rows[i] * 256 + hoff);
    uint4 qc = *(const uint4*)(q + (size_t)qi * 256 + hoff);

    // ---- scores: 8-dim partials completed within the 4-lane chunk group ----
    float s[8];
#pragma unroll
    for (int i = 0; i < 8; ++i) {
        float si = 0.f;
        si = dot2f16(kd[i].x, qc.x, si);
        si = dot2f16(kd[i].y, qc.y, si);
        si = dot2f16(kd[i].z, qc.z, si);
        si = dot2f16(kd[i].w, qc.w, si);
        si += __shfl_xor(si, 1);
        si += __shfl_xor(si, 2);
        s[i] = si * 0.17677669529663687f;
    }

    // ---- softmax over 64 keys (o-sets disjoint; reduce over o bits) ----
    float mx = s[0];
#pragma unroll
    for (int i = 1; i < 8; ++i) mx = fmaxf(mx, s[i]);
    mx = fmaxf(mx, __shfl_xor(mx, 8));
    mx = fmaxf(mx, __shfl_xor(mx, 16));
    mx = fmaxf(mx, __shfl_xor(mx, 32));
    float p[8], sum = 0.f;
#pragma unroll
    for (int i = 0; i < 8; ++i) { p[i] = __expf(s[i] - mx); sum += p[i]; }
    sum += __shfl_xor(sum, 8);
    sum += __shfl_xor(sum, 16);
    sum += __shfl_xor(sum, 32);
    float inv = 1.f / sum;

    // ---- PV: 8 keys x 4 dim-pair u32s, f16 packed fma ----
    u32 A0 = 0, A1 = 0, A2 = 0, A3 = 0;
#pragma unroll
    for (int i = 0; i < 8; ++i) {
        float pi = p[i] * inv;
        u32 pp = pkrtz(pi, pi);
        A0 = pk_fma16(pp, vd[i].x, A0);
        A1 = pk_fma16(pp, vd[i].y, A1);
        A2 = pk_fma16(pp, vd[i].z, A2);
        A3 = pk_fma16(pp, vd[i].w, A3);
    }

    // ---- split-reduce over the 8 o-sets (lane bits 3,4,5) ----
    const bool ob0 = (o & 1) != 0;
    const bool ob1 = (o & 2) != 0;
    {   // xor 8: 4 u32 -> 2
        u32 t0 = ob0 ? A0 : A2;
        u32 t1 = ob0 ? A1 : A3;
        t0 = __shfl_xor((int)t0, 8);
        t1 = __shfl_xor((int)t1, 8);
        A0 = pk_add16(ob0 ? A2 : A0, t0);
        A1 = pk_add16(ob0 ? A3 : A1, t1);
    }
    {   // xor 16: 2 u32 -> 1
        u32 u0 = ob1 ? A0 : A1;
        u0 = __shfl_xor((int)u0, 16);
        A0 = pk_add16(ob1 ? A1 : A0, u0);
    }
    A0 = pk_add16(A0, (u32)__shfl_xor((int)A0, 32));

    // lane (o<4, c) owns u32 slot j = 2*(o&1) + ((o>>1)&1) of chunk c
    if (o < 4) {
        int j = 2 * (o & 1) + ((o >> 1) & 1);
        f16x2 hv = __builtin_bit_cast(f16x2, A0);
        u32 packed = (u32)f2bf((float)hv.x) | ((u32)f2bf((float)hv.y) << 16);
        *(u32*)(msg + (size_t)qi * 256 + hp * 64 + c * 8 + j * 2) = packed;
    }
}

// ---------------------------------------------------------------------------
extern "C" void kernel_launch(void* const* d_in, const int* in_sizes, int n_in,
                              void* d_out, int out_size, void* d_ws, size_t ws_size,
                              hipStream_t stream)
{
    const float* x      = (const float*)d_in[0];
    const float* source = (const float*)d_in[1];
    const int*   eidx   = (const int*)d_in[2];
    const float* Wq     = (const float*)d_in[3];
    const float* Wk     = (const float*)d_in[4];
    const float* Wv     = (const float*)d_in[5];
    const float* Wm     = (const float*)d_in[6];
    const float* W1     = (const float*)d_in[7];
    const float* W2     = (const float*)d_in[8];
    const float* g1     = (const float*)d_in[9];
    const float* b1     = (const float*)d_in[10];
    const float* g2     = (const float*)d_in[11];
    const float* b2     = (const float*)d_in[12];
    float* out = (float*)d_out;

    char* ws = (char*)d_ws;
    const size_t SZB = (size_t)MROWS * 256 * 2;    // 4.9 MB
    u16* xb     = (u16*)(ws);                      // bf16, live until W1 gemm
    u16* sb     = (u16*)(ws + SZB);                // bf16, dead after qkv gemm
    u16* qb     = (u16*)(ws + 2 * SZB);            // f16, qkv gemm seg 0
    u16* kb     = (u16*)(ws + 3 * SZB);            // f16, seg 1
    u16* vb     = (u16*)(ws + 4 * SZB);            // f16, seg 2
    u16* msgb   = (u16*)(ws + 5 * SZB);            // bf16, dead after Wm gemm
    u16* msglnb = (u16*)(ws + 6 * SZB);            // bf16 LN1 output
    u16* h1b    = (u16*)(ws + 7 * SZB);            // bf16 [9600][512]
    u16* Wqkvt  = (u16*)(ws + 9 * SZB);            // [768][256]
    u16* Wmt    = Wqkvt + 768 * 256;
    u16* W1t    = Wmt + 256 * 256;                 // [512][512]
    u16* W2t    = W1t + 512 * 512;                 // [256][512]

    dim3 blk(256);

    // fused prep: casts + all weight transposes
    prep_kernel<<<dim3(7360), blk, 0, stream>>>(x, source, Wq, Wk, Wv, Wm, W1, W2,
                                                xb, sb, Wqkvt, Wmt, W1t, W2t);

    // fused q|k|v projection, f16 out, 64x128 tiles (900 blocks)
    gemm_mfma_kernel<64, 128><<<dim3(6, 150), blk, 0, stream>>>(
        xb, 256, sb, 256, 0, 256, Wqkvt, 256, qb, MROWS, 768, 256, 8 | 4);

    // gathered attention -> msg (bf16); one block per query
    attn_kernel<<<dim3(MROWS), blk, 0, stream>>>(qb, kb, vb, eidx, msgb);

    // msg @ Wm + LN1 fused -> bf16 msglnb (300 blocks of 32 rows)
    gemm_ln_kernel<32, false, true><<<dim3(300), blk, 0, stream>>>(
        msgb, 256, Wmt, 256, g1, b1, nullptr, msglnb, 256);

    // concat(x, msgln) @ W1, relu -> bf16 [9600,512] (64x128 tiles, 600 blocks)
    gemm_mfma_kernel<64, 128><<<dim3(4, 150), blk, 0, stream>>>(
        xb, 256, msglnb, 256, 256, 0, W1t, 512, h1b, MROWS, 512, 512, 1 | 2);

    // h1 @ W2 + LN2 + residual fused -> fp32 out (300 blocks of 32 rows)
    gemm_ln_kernel<32, true, false><<<dim3(300), blk, 0, stream>>>(
        h1b, 512, W2t, 512, g2, b2, x, out, 512);
}

// Round 12
// 101.170 us; speedup vs baseline: 1.7623x; 1.0000x over previous
//
#include <hip/hip_runtime.h>
#include <hip/hip_bf16.h>

#define D_MODEL 256
#define LQ 4800
#define NB 2
#define MROWS (NB * LQ)       // 9600
#define LN_EPS 1e-5f

typedef unsigned int u32;
typedef unsigned short u16;
typedef __attribute__((ext_vector_type(8))) short bf16x8;
typedef __attribute__((ext_vector_type(4))) float f32x4;
typedef __attribute__((ext_vector_type(2))) _Float16 f16x2;

__device__ __forceinline__ u16 f2bf(float f) {
    __hip_bfloat16 h = __float2bfloat16(f);
    return *reinterpret_cast<u16*>(&h);
}

// f16 pair dot into f32 (v_dot2_f32_f16)
__device__ __forceinline__ float dot2f16(u32 a, u32 b, float c) {
#if __has_builtin(__builtin_amdgcn_fdot2)
    return __builtin_amdgcn_fdot2(__builtin_bit_cast(f16x2, a),
                                  __builtin_bit_cast(f16x2, b), c, false);
#else
    f16x2 av = __builtin_bit_cast(f16x2, a), bv = __builtin_bit_cast(f16x2, b);
    c = fmaf((float)av.x, (float)bv.x, c);
    return fmaf((float)av.y, (float)bv.y, c);
#endif
}
__device__ __forceinline__ u32 pk_fma16(u32 a, u32 b, u32 c) {
    u32 d;
    asm("v_pk_fma_f16 %0, %1, %2, %3" : "=v"(d) : "v"(a), "v"(b), "v"(c));
    return d;
}
__device__ __forceinline__ u32 pk_add16(u32 a, u32 b) {
    u32 d;
    asm("v_pk_add_f16 %0, %1, %2" : "=v"(d) : "v"(a), "v"(b));
    return d;
}
__device__ __forceinline__ u32 pkrtz(float a, float b) {
    return __builtin_bit_cast(u32, __builtin_amdgcn_cvt_pkrtz(a, b));
}

// ---------------------------------------------------------------------------
// Fused prep: cast x & source to bf16; transpose+cast all weights.
// grid: [0,2400) cast x, [2400,4800) cast source, [4800,7360) weight tiles.
// Wqkvt is [768][256]: rows 0..255 Wq^T, 256..511 Wk^T, 512..767 Wv^T.
// ---------------------------------------------------------------------------
__global__ __launch_bounds__(256) void prep_kernel(
    const float* __restrict__ x, const float* __restrict__ source,
    const float* __restrict__ Wq, const float* __restrict__ Wk,
    const float* __restrict__ Wv, const float* __restrict__ Wm,
    const float* __restrict__ W1, const float* __restrict__ W2,
    u16* __restrict__ xb, u16* __restrict__ sb,
    u16* __restrict__ Wqkvt, u16* __restrict__ Wmt,
    u16* __restrict__ W1t, u16* __restrict__ W2t)
{
    __shared__ float tile[16][17];
    const int t = threadIdx.x;
    int bid = blockIdx.x;

    if (bid < 4800) {
        const float* src = bid < 2400 ? x : source;
        u16* dst = bid < 2400 ? xb : sb;
        int b = bid < 2400 ? bid : bid - 2400;
        int i = (b * 256 + t) * 4;
        float4 v = *reinterpret_cast<const float4*>(src + i);
        ushort4 o; o.x = f2bf(v.x); o.y = f2bf(v.y); o.z = f2bf(v.z); o.w = f2bf(v.w);
        *reinterpret_cast<ushort4*>(dst + i) = o;
        return;
    }
    int sub = bid - 4800;
    const float* W; u16* Wt; int Nd, ldt, rowoff;
    if      (sub < 256)  { W = Wq; Wt = Wqkvt; Nd = 256; ldt = 256; rowoff = 0;   }
    else if (sub < 512)  { W = Wk; Wt = Wqkvt; Nd = 256; ldt = 256; rowoff = 256; sub -= 256; }
    else if (sub < 768)  { W = Wv; Wt = Wqkvt; Nd = 256; ldt = 256; rowoff = 512; sub -= 512; }
    else if (sub < 1024) { W = Wm; Wt = Wmt;   Nd = 256; ldt = 256; rowoff = 0;   sub -= 768; }
    else if (sub < 2048) { W = W1; Wt = W1t;   Nd = 512; ldt = 512; rowoff = 0;   sub -= 1024; }
    else                 { W = W2; Wt = W2t;   Nd = 256; ldt = 512; rowoff = 0;   sub -= 2048; }
    int ntiles = Nd >> 4;
    int tn = sub % ntiles, tk = sub / ntiles;
    int tx = t & 15, ty = t >> 4;
    tile[ty][tx] = W[(size_t)(tk * 16 + ty) * Nd + tn * 16 + tx];
    __syncthreads();
    Wt[(size_t)(rowoff + tn * 16 + ty) * ldt + tk * 16 + tx] = f2bf(tile[tx][ty]);
}

// ---------------------------------------------------------------------------
// bf16 MFMA GEMM, templated tile: C = act(A @ Bt^T). BK=32, 256 threads,
// 2x2 waves. flags: 1=relu, 2=bf16 out, 4=route by col>>8, 8=f16 out.
// ---------------------------------------------------------------------------
template<int BM, int BN>
__global__ __launch_bounds__(256) void gemm_mfma_kernel(
    const u16* __restrict__ A0, int lda0,
    const u16* __restrict__ A1, int lda1, int splitK, int nsel,
    const u16* __restrict__ Bt, int ldb,
    void* __restrict__ Cout,
    int M, int N, int K, int flags)
{
    __shared__ __align__(16) u16 As[BM * 32];
    __shared__ __align__(16) u16 Bs[BN * 32];

    constexpr int WM = BM / 2, WN = BN / 2;
    constexpr int FI = WM / 16, FJ = WN / 16;

    const int t  = threadIdx.x;
    const int l  = t & 63;
    const int w  = t >> 6;
    const int m0 = blockIdx.y * BM;
    const int n0 = blockIdx.x * BN;
    const int wr = w >> 1, wc = w & 1;

    if (nsel && n0 >= nsel) { A0 = A1; lda0 = lda1; }

    const int srow = l >> 2;
    const int sch  = (l & 3) ^ (srow & 3);

    f32x4 acc[FI][FJ];
#pragma unroll
    for (int i = 0; i < FI; ++i)
#pragma unroll
        for (int j = 0; j < FJ; ++j) acc[i][j] = (f32x4){0.f, 0.f, 0.f, 0.f};

    for (int k0 = 0; k0 < K; k0 += 32) {
        const u16* Ap; int kk, lda;
        if (splitK && k0 >= splitK) { Ap = A1; kk = k0 - splitK; lda = lda1; }
        else                        { Ap = A0; kk = k0;          lda = lda0; }

        if (BM >= 64) {
#pragma unroll
            for (int g = 0; g < BM / 64; ++g) {
                int grp = w * (BM / 64) + g;
                int row = grp * 16 + srow;
                const u16* asrc = Ap + (size_t)(m0 + row) * lda + kk + sch * 8;
                u32* adst = (u32*)(As + grp * 512);
                __builtin_amdgcn_global_load_lds(
                    (const __attribute__((address_space(1))) u32*)asrc,
                    (__attribute__((address_space(3))) u32*)adst, 16, 0, 0);
            }
        } else if (w < BM / 16) {
            int row = w * 16 + srow;
            const u16* asrc = Ap + (size_t)(m0 + row) * lda + kk + sch * 8;
            u32* adst = (u32*)(As + w * 512);
            __builtin_amdgcn_global_load_lds(
                (const __attribute__((address_space(1))) u32*)asrc,
                (__attribute__((address_space(3))) u32*)adst, 16, 0, 0);
        }
#pragma unroll
        for (int g = 0; g < BN / 64; ++g) {
            int grp = w * (BN / 64) + g;
            int row = grp * 16 + srow;
            const u16* bsrc = Bt + (size_t)(n0 + row) * ldb + k0 + sch * 8;
            u32* bdst = (u32*)(Bs + grp * 512);
            __builtin_amdgcn_global_load_lds(
                (const __attribute__((address_space(1))) u32*)bsrc,
                (__attribute__((address_space(3))) u32*)bdst, 16, 0, 0);
        }
        __syncthreads();

        const int r  = l & 15;
        const int ch = l >> 4;
        bf16x8 af[FI], bfr[FJ];
#pragma unroll
        for (int i = 0; i < FI; ++i) {
            int ar = wr * WM + i * 16 + r;
            af[i] = *(const bf16x8*)((const char*)As + ar * 64 + ((ch ^ (r & 3)) * 16));
        }
#pragma unroll
        for (int j = 0; j < FJ; ++j) {
            int br = wc * WN + j * 16 + r;
            bfr[j] = *(const bf16x8*)((const char*)Bs + br * 64 + ((ch ^ (r & 3)) * 16));
        }
#pragma unroll
        for (int i = 0; i < FI; ++i)
#pragma unroll
            for (int j = 0; j < FJ; ++j)
                acc[i][j] = __builtin_amdgcn_mfma_f32_16x16x32_bf16(af[i], bfr[j], acc[i][j], 0, 0, 0);
        __syncthreads();
    }

    const int r  = l & 15;
    const int q4 = l >> 4;
#pragma unroll
    for (int i = 0; i < FI; ++i)
#pragma unroll
        for (int j = 0; j < FJ; ++j) {
            int col = n0 + wc * WN + j * 16 + r;
#pragma unroll
            for (int reg = 0; reg < 4; ++reg) {
                int row = m0 + wr * WM + i * 16 + q4 * 4 + reg;
                float vv = acc[i][j][reg];
                if (flags & 1) vv = fmaxf(vv, 0.f);
                size_t off;
                int colw, Nw;
                if (flags & 4) { off = (size_t)(col >> 8) * M * 256; colw = col & 255; Nw = 256; }
                else           { off = 0; colw = col; Nw = N; }
                if (flags & 8) {
                    _Float16 hv = (_Float16)vv;
                    ((u16*)Cout)[off + (size_t)row * Nw + colw] = __builtin_bit_cast(u16, hv);
                } else if (flags & 2) {
                    ((u16*)Cout)[off + (size_t)row * Nw + colw] = f2bf(vv);
                } else {
                    ((float*)Cout)[off + (size_t)row * Nw + colw] = vv;
                }
            }
        }
}

// ---------------------------------------------------------------------------
// GEMM (BM rows, BN=256 full row) with fused LayerNorm epilogue.
// C_row = LN(A@Bt^T)[row] * g + b  (+ xres[row] if RESID). One block = BM rows.
// BM in {32, 64}. OUT_BF16: write bf16, else fp32.
// ---------------------------------------------------------------------------
template<int BM, bool RESID, bool OUT_BF16>
__global__ __launch_bounds__(256) void gemm_ln_kernel(
    const u16* __restrict__ A, int lda,
    const u16* __restrict__ Bt, int ldb,
    const float* __restrict__ g, const float* __restrict__ b,
    const float* __restrict__ xres,
    void* __restrict__ Cout, int K)
{
    __shared__ __align__(16) u16 As[BM * 32];
    __shared__ __align__(16) u16 Bs[256 * 32];
    __shared__ float2 red[BM][2];

    constexpr int WM = BM / 2;      // 16 or 32
    constexpr int FI = WM / 16;     // 1 or 2

    const int t  = threadIdx.x;
    const int l  = t & 63;
    const int w  = t >> 6;
    const int m0 = blockIdx.x * BM;
    const int wr = w >> 1, wc = w & 1;

    const int srow = l >> 2;
    const int sch  = (l & 3) ^ (srow & 3);

    f32x4 acc[FI][8];
#pragma unroll
    for (int i = 0; i < FI; ++i)
#pragma unroll
        for (int j = 0; j < 8; ++j) acc[i][j] = (f32x4){0.f, 0.f, 0.f, 0.f};

    for (int k0 = 0; k0 < K; k0 += 32) {
        if (w < BM / 16) {   // A tile: BM rows, one 16-row group per wave
            int row = w * 16 + srow;
            const u16* asrc = A + (size_t)(m0 + row) * lda + k0 + sch * 8;
            u32* adst = (u32*)(As + w * 512);
            __builtin_amdgcn_global_load_lds(
                (const __attribute__((address_space(1))) u32*)asrc,
                (__attribute__((address_space(3))) u32*)adst, 16, 0, 0);
        }
#pragma unroll
        for (int gg = 0; gg < 4; ++gg) {   // B tile: 256 rows
            int grp = w * 4 + gg;
            int row = grp * 16 + srow;
            const u16* bsrc = Bt + (size_t)row * ldb + k0 + sch * 8;
            u32* bdst = (u32*)(Bs + grp * 512);
            __builtin_amdgcn_global_load_lds(
                (const __attribute__((address_space(1))) u32*)bsrc,
                (__attribute__((address_space(3))) u32*)bdst, 16, 0, 0);
        }
        __syncthreads();

        const int r  = l & 15;
        const int ch = l >> 4;
        bf16x8 af[FI], bfr[8];
#pragma unroll
        for (int i = 0; i < FI; ++i) {
            int ar = wr * WM + i * 16 + r;
            af[i] = *(const bf16x8*)((const char*)As + ar * 64 + ((ch ^ (r & 3)) * 16));
        }
#pragma unroll
        for (int j = 0; j < 8; ++j) {
            int br = wc * 128 + j * 16 + r;
            bfr[j] = *(const bf16x8*)((const char*)Bs + br * 64 + ((ch ^ (r & 3)) * 16));
        }
#pragma unroll
        for (int i = 0; i < FI; ++i)
#pragma unroll
            for (int j = 0; j < 8; ++j)
                acc[i][j] = __builtin_amdgcn_mfma_f32_16x16x32_bf16(af[i], bfr[j], acc[i][j], 0, 0, 0);
        __syncthreads();
    }

    const int r  = l & 15;
    const int q4 = l >> 4;

    // ---- row partial sums over this thread's 8 cols per row-slot ----
    float rs[FI][4], rq[FI][4];
#pragma unroll
    for (int i = 0; i < FI; ++i)
#pragma unroll
        for (int reg = 0; reg < 4; ++reg) {
            float s = 0.f, sq = 0.f;
#pragma unroll
            for (int j = 0; j < 8; ++j) {
                float vv = acc[i][j][reg];
                s += vv; sq += vv * vv;
            }
            rs[i][reg] = s; rq[i][reg] = sq;
        }
#pragma unroll
    for (int off = 1; off <= 8; off <<= 1)
#pragma unroll
        for (int i = 0; i < FI; ++i)
#pragma unroll
            for (int reg = 0; reg < 4; ++reg) {
                rs[i][reg] += __shfl_xor(rs[i][reg], off);
                rq[i][reg] += __shfl_xor(rq[i][reg], off);
            }
    if (r == 0) {
#pragma unroll
        for (int i = 0; i < FI; ++i)
#pragma unroll
            for (int reg = 0; reg < 4; ++reg) {
                int row = wr * WM + i * 16 + q4 * 4 + reg;
                red[row][wc] = make_float2(rs[i][reg], rq[i][reg]);
            }
    }
    __syncthreads();

    // preload g,b for this thread's 8 cols
    float gj[8], bj[8];
#pragma unroll
    for (int j = 0; j < 8; ++j) {
        int col = wc * 128 + j * 16 + r;
        gj[j] = g[col]; bj[j] = b[col];
    }

#pragma unroll
    for (int i = 0; i < FI; ++i)
#pragma unroll
        for (int reg = 0; reg < 4; ++reg) {
            int row = wr * WM + i * 16 + q4 * 4 + reg;
            float2 t0 = red[row][0], t1 = red[row][1];
            float mu  = (t0.x + t1.x) * 0.00390625f;
            float var = (t0.y + t1.y) * 0.00390625f - mu * mu;
            float rstd = rsqrtf(var + LN_EPS);
#pragma unroll
            for (int j = 0; j < 8; ++j) {
                int col = wc * 128 + j * 16 + r;
                float vv = (acc[i][j][reg] - mu) * rstd * gj[j] + bj[j];
                size_t oidx = (size_t)(m0 + row) * 256 + col;
                if (RESID) vv += xres[oidx];
                if (OUT_BF16) ((u16*)Cout)[oidx] = f2bf(vv);
                else          ((float*)Cout)[oidx] = vv;
            }
        }
}

// ---------------------------------------------------------------------------
// Gathered attention: wave = (query, head-pair), 128B oct-coalesced gathers.
// q,k,v: [MROWS,256] fp16 head-major. msg out: bf16. Block = 1 query, 4 waves.
// Lane: o = l>>3 (key-set), c = l&7 (16B chunk of the 128B two-head slice).
// V gathers DEFERRED until after the score phase: halves peak VGPR pressure
// (kd dead before vd issued) -> 8 waves/SIMD via __launch_bounds__(256,8).
// No LDS, no barriers.
// ---------------------------------------------------------------------------
__global__ __launch_bounds__(256, 8) void attn_kernel(
    const u16* __restrict__ q, const u16* __restrict__ k,
    const u16* __restrict__ v, const int* __restrict__ idx,
    u16* __restrict__ msg)
{
    const int t  = threadIdx.x;
    const int l  = t & 63;
    const int hp = t >> 6;              // head-pair 0..3
    const int qi = blockIdx.x;
    const int n  = qi / LQ;
    const size_t srcbase = (size_t)n * LQ * 256;   // u16 units

    const int o = l >> 3;   // key-set 0..7
    const int c = l & 7;    // 16B chunk of 128B slice

    const int* idxp = idx + (size_t)qi * 64;
    int rows[8];
#pragma unroll
    for (int i = 0; i < 8; ++i) rows[i] = idxp[i * 8 + o];   // 8-lane broadcast

    const size_t hoff = (size_t)hp * 64 + c * 8;   // u16 offset in a row

    // ---- K phase: issue K gathers + q slice ----
    uint4 kd[8];
#pragma unroll
    for (int i = 0; i < 8; ++i)
        kd[i] = *(const uint4*)(k + srcbase + (size_t)rows[i] * 256 + hoff);
    uint4 qc = *(const uint4*)(q + (size_t)qi * 256 + hoff);

    // ---- scores: 8-dim partials completed within the 4-lane chunk group ----
    float s[8];
#pragma unroll
    for (int i = 0; i < 8; ++i) {
        float si = 0.f;
        si = dot2f16(kd[i].x, qc.x, si);
        si = dot2f16(kd[i].y, qc.y, si);
        si = dot2f16(kd[i].z, qc.z, si);
        si = dot2f16(kd[i].w, qc.w, si);
        si += __shfl_xor(si, 1);
        si += __shfl_xor(si, 2);
        s[i] = si * 0.17677669529663687f;
    }

    // ---- V phase: kd now dead; issue V gathers (latency hides under softmax) ----
    uint4 vd[8];
#pragma unroll
    for (int i = 0; i < 8; ++i)
        vd[i] = *(const uint4*)(v + srcbase + (size_t)rows[i] * 256 + hoff);

    // ---- softmax over 64 keys (o-sets disjoint; reduce over o bits) ----
    float mx = s[0];
#pragma unroll
    for (int i = 1; i < 8; ++i) mx = fmaxf(mx, s[i]);
    mx = fmaxf(mx, __shfl_xor(mx, 8));
    mx = fmaxf(mx, __shfl_xor(mx, 16));
    mx = fmaxf(mx, __shfl_xor(mx, 32));
    float p[8], sum = 0.f;
#pragma unroll
    for (int i = 0; i < 8; ++i) { p[i] = __expf(s[i] - mx); sum += p[i]; }
    sum += __shfl_xor(sum, 8);
    sum += __shfl_xor(sum, 16);
    sum += __shfl_xor(sum, 32);
    float inv = 1.f / sum;

    // ---- PV: 8 keys x 4 dim-pair u32s, f16 packed fma ----
    u32 A0 = 0, A1 = 0, A2 = 0, A3 = 0;
#pragma unroll
    for (int i = 0; i < 8; ++i) {
        float pi = p[i] * inv;
        u32 pp = pkrtz(pi, pi);
        A0 = pk_fma16(pp, vd[i].x, A0);
        A1 = pk_fma16(pp, vd[i].y, A1);
        A2 = pk_fma16(pp, vd[i].z, A2);
        A3 = pk_fma16(pp, vd[i].w, A3);
    }

    // ---- split-reduce over the 8 o-sets (lane bits 3,4,5) ----
    const bool ob0 = (o & 1) != 0;
    const bool ob1 = (o & 2) != 0;
    {   // xor 8: 4 u32 -> 2
        u32 t0 = ob0 ? A0 : A2;
        u32 t1 = ob0 ? A1 : A3;
        t0 = __shfl_xor((int)t0, 8);
        t1 = __shfl_xor((int)t1, 8);
        A0 = pk_add16(ob0 ? A2 : A0, t0);
        A1 = pk_add16(ob0 ? A3 : A1, t1);
    }
    {   // xor 16: 2 u32 -> 1
        u32 u0 = ob1 ? A0 : A1;
        u0 = __shfl_xor((int)u0, 16);
        A0 = pk_add16(ob1 ? A1 : A0, u0);
    }
    A0 = pk_add16(A0, (u32)__shfl_xor((int)A0, 32));

    // lane (o<4, c) owns u32 slot j = 2*(o&1) + ((o>>1)&1) of chunk c
    if (o < 4) {
        int j = 2 * (o & 1) + ((o >> 1) & 1);
        f16x2 hv = __builtin_bit_cast(f16x2, A0);
        u32 packed = (u32)f2bf((float)hv.x) | ((u32)f2bf((float)hv.y) << 16);
        *(u32*)(msg + (size_t)qi * 256 + hp * 64 + c * 8 + j * 2) = packed;
    }
}

// ---------------------------------------------------------------------------
extern "C" void kernel_launch(void* const* d_in, const int* in_sizes, int n_in,
                              void* d_out, int out_size, void* d_ws, size_t ws_size,
                              hipStream_t stream)
{
    const float* x      = (const float*)d_in[0];
    const float* source = (const float*)d_in[1];
    const int*   eidx   = (const int*)d_in[2];
    const float* Wq     = (const float*)d_in[3];
    const float* Wk     = (const float*)d_in[4];
    const float* Wv     = (const float*)d_in[5];
    const float* Wm     = (const float*)d_in[6];
    const float* W1     = (const float*)d_in[7];
    const float* W2     = (const float*)d_in[8];
    const float* g1     = (const float*)d_in[9];
    const float* b1     = (const float*)d_in[10];
    const float* g2     = (const float*)d_in[11];
    const float* b2     = (const float*)d_in[12];
    float* out = (float*)d_out;

    char* ws = (char*)d_ws;
    const size_t SZB = (size_t)MROWS * 256 * 2;    // 4.9 MB
    u16* xb     = (u16*)(ws);                      // bf16, live until W1 gemm
    u16* sb     = (u16*)(ws + SZB);                // bf16, dead after qkv gemm
    u16* qb     = (u16*)(ws + 2 * SZB);            // f16, qkv gemm seg 0
    u16* kb     = (u16*)(ws + 3 * SZB);            // f16, seg 1
    u16* vb     = (u16*)(ws + 4 * SZB);            // f16, seg 2
    u16* msgb   = (u16*)(ws + 5 * SZB);            // bf16, dead after Wm gemm
    u16* msglnb = (u16*)(ws + 6 * SZB);            // bf16 LN1 output
    u16* h1b    = (u16*)(ws + 7 * SZB);            // bf16 [9600][512]
    u16* Wqkvt  = (u16*)(ws + 9 * SZB);            // [768][256]
    u16* Wmt    = Wqkvt + 768 * 256;
    u16* W1t    = Wmt + 256 * 256;                 // [512][512]
    u16* W2t    = W1t + 512 * 512;                 // [256][512]

    dim3 blk(256);

    // fused prep: casts + all weight transposes
    prep_kernel<<<dim3(7360), blk, 0, stream>>>(x, source, Wq, Wk, Wv, Wm, W1, W2,
                                                xb, sb, Wqkvt, Wmt, W1t, W2t);

    // fused q|k|v projection, f16 out, 64x128 tiles (900 blocks)
    gemm_mfma_kernel<64, 128><<<dim3(6, 150), blk, 0, stream>>>(
        xb, 256, sb, 256, 0, 256, Wqkvt, 256, qb, MROWS, 768, 256, 8 | 4);

    // gathered attention -> msg (bf16); one block per query
    attn_kernel<<<dim3(MROWS), blk, 0, stream>>>(qb, kb, vb, eidx, msgb);

    // msg @ Wm + LN1 fused -> bf16 msglnb (300 blocks of 32 rows)
    gemm_ln_kernel<32, false, true><<<dim3(300), blk, 0, stream>>>(
        msgb, 256, Wmt, 256, g1, b1, nullptr, msglnb, 256);

    // concat(x, msgln) @ W1, relu -> bf16 [9600,512] (64x128 tiles, 600 blocks)
    gemm_mfma_kernel<64, 128><<<dim3(4, 150), blk, 0, stream>>>(
        xb, 256, msglnb, 256, 256, 0, W1t, 512, h1b, MROWS, 512, 512, 1 | 2);

    // h1 @ W2 + LN2 + residual fused -> fp32 out (300 blocks of 32 rows)
    gemm_ln_kernel<32, true, false><<<dim3(300), blk, 0, stream>>>(
        h1b, 512, W2t, 512, g2, b2, x, out, 512);
}

// Round 13
// 100.142 us; speedup vs baseline: 1.7803x; 1.0103x over previous
//
#include <hip/hip_runtime.h>
#include <hip/hip_bf16.h>

#define D_MODEL 256
#define LQ 4800
#define NB 2
#define MROWS (NB * LQ)       // 9600
#define LN_EPS 1e-5f

typedef unsigned int u32;
typedef unsigned short u16;
typedef __attribute__((ext_vector_type(8))) short bf16x8;
typedef __attribute__((ext_vector_type(4))) float f32x4;
typedef __attribute__((ext_vector_type(2))) _Float16 f16x2;

__device__ __forceinline__ u16 f2bf(float f) {
    __hip_bfloat16 h = __float2bfloat16(f);
    return *reinterpret_cast<u16*>(&h);
}

// f16 pair dot into f32 (v_dot2_f32_f16)
__device__ __forceinline__ float dot2f16(u32 a, u32 b, float c) {
#if __has_builtin(__builtin_amdgcn_fdot2)
    return __builtin_amdgcn_fdot2(__builtin_bit_cast(f16x2, a),
                                  __builtin_bit_cast(f16x2, b), c, false);
#else
    f16x2 av = __builtin_bit_cast(f16x2, a), bv = __builtin_bit_cast(f16x2, b);
    c = fmaf((float)av.x, (float)bv.x, c);
    return fmaf((float)av.y, (float)bv.y, c);
#endif
}
__device__ __forceinline__ u32 pk_fma16(u32 a, u32 b, u32 c) {
    u32 d;
    asm("v_pk_fma_f16 %0, %1, %2, %3" : "=v"(d) : "v"(a), "v"(b), "v"(c));
    return d;
}
__device__ __forceinline__ u32 pk_add16(u32 a, u32 b) {
    u32 d;
    asm("v_pk_add_f16 %0, %1, %2" : "=v"(d) : "v"(a), "v"(b));
    return d;
}
__device__ __forceinline__ u32 pkrtz(float a, float b) {
    return __builtin_bit_cast(u32, __builtin_amdgcn_cvt_pkrtz(a, b));
}
__device__ __forceinline__ void gload_lds(const u16* src, u16* dst) {
    __builtin_amdgcn_global_load_lds(
        (const __attribute__((address_space(1))) u32*)src,
        (__attribute__((address_space(3))) u32*)dst, 16, 0, 0);
}

// ---------------------------------------------------------------------------
// Fused prep: cast x & source to bf16; transpose+cast all weights.
// grid: [0,2400) cast x, [2400,4800) cast source, [4800,7360) weight tiles.
// Wqkvt is [768][256]: rows 0..255 Wq^T, 256..511 Wk^T, 512..767 Wv^T.
// ---------------------------------------------------------------------------
__global__ __launch_bounds__(256) void prep_kernel(
    const float* __restrict__ x, const float* __restrict__ source,
    const float* __restrict__ Wq, const float* __restrict__ Wk,
    const float* __restrict__ Wv, const float* __restrict__ Wm,
    const float* __restrict__ W1, const float* __restrict__ W2,
    u16* __restrict__ xb, u16* __restrict__ sb,
    u16* __restrict__ Wqkvt, u16* __restrict__ Wmt,
    u16* __restrict__ W1t, u16* __restrict__ W2t)
{
    __shared__ float tile[16][17];
    const int t = threadIdx.x;
    int bid = blockIdx.x;

    if (bid < 4800) {
        const float* src = bid < 2400 ? x : source;
        u16* dst = bid < 2400 ? xb : sb;
        int b = bid < 2400 ? bid : bid - 2400;
        int i = (b * 256 + t) * 4;
        float4 v = *reinterpret_cast<const float4*>(src + i);
        ushort4 o; o.x = f2bf(v.x); o.y = f2bf(v.y); o.z = f2bf(v.z); o.w = f2bf(v.w);
        *reinterpret_cast<ushort4*>(dst + i) = o;
        return;
    }
    int sub = bid - 4800;
    const float* W; u16* Wt; int Nd, ldt, rowoff;
    if      (sub < 256)  { W = Wq; Wt = Wqkvt; Nd = 256; ldt = 256; rowoff = 0;   }
    else if (sub < 512)  { W = Wk; Wt = Wqkvt; Nd = 256; ldt = 256; rowoff = 256; sub -= 256; }
    else if (sub < 768)  { W = Wv; Wt = Wqkvt; Nd = 256; ldt = 256; rowoff = 512; sub -= 512; }
    else if (sub < 1024) { W = Wm; Wt = Wmt;   Nd = 256; ldt = 256; rowoff = 0;   sub -= 768; }
    else if (sub < 2048) { W = W1; Wt = W1t;   Nd = 512; ldt = 512; rowoff = 0;   sub -= 1024; }
    else                 { W = W2; Wt = W2t;   Nd = 256; ldt = 512; rowoff = 0;   sub -= 2048; }
    int ntiles = Nd >> 4;
    int tn = sub % ntiles, tk = sub / ntiles;
    int tx = t & 15, ty = t >> 4;
    tile[ty][tx] = W[(size_t)(tk * 16 + ty) * Nd + tn * 16 + tx];
    __syncthreads();
    Wt[(size_t)(rowoff + tn * 16 + ty) * ldt + tk * 16 + tx] = f2bf(tile[tx][ty]);
}

// ---------------------------------------------------------------------------
// bf16 MFMA GEMM, templated tile: C = act(A @ Bt^T). BK=32, 256 threads,
// 2x2 waves. flags: 1=relu, 2=bf16 out, 4=route by col>>8, 8=f16 out.
// (Used for the fused q|k|v projection only.)
// ---------------------------------------------------------------------------
template<int BM, int BN>
__global__ __launch_bounds__(256) void gemm_mfma_kernel(
    const u16* __restrict__ A0, int lda0,
    const u16* __restrict__ A1, int lda1, int splitK, int nsel,
    const u16* __restrict__ Bt, int ldb,
    void* __restrict__ Cout,
    int M, int N, int K, int flags)
{
    __shared__ __align__(16) u16 As[BM * 32];
    __shared__ __align__(16) u16 Bs[BN * 32];

    constexpr int WM = BM / 2, WN = BN / 2;
    constexpr int FI = WM / 16, FJ = WN / 16;

    const int t  = threadIdx.x;
    const int l  = t & 63;
    const int w  = t >> 6;
    const int m0 = blockIdx.y * BM;
    const int n0 = blockIdx.x * BN;
    const int wr = w >> 1, wc = w & 1;

    if (nsel && n0 >= nsel) { A0 = A1; lda0 = lda1; }

    const int srow = l >> 2;
    const int sch  = (l & 3) ^ (srow & 3);

    f32x4 acc[FI][FJ];
#pragma unroll
    for (int i = 0; i < FI; ++i)
#pragma unroll
        for (int j = 0; j < FJ; ++j) acc[i][j] = (f32x4){0.f, 0.f, 0.f, 0.f};

    for (int k0 = 0; k0 < K; k0 += 32) {
        const u16* Ap; int kk, lda;
        if (splitK && k0 >= splitK) { Ap = A1; kk = k0 - splitK; lda = lda1; }
        else                        { Ap = A0; kk = k0;          lda = lda0; }

        if (BM >= 64) {
#pragma unroll
            for (int g = 0; g < BM / 64; ++g) {
                int grp = w * (BM / 64) + g;
                int row = grp * 16 + srow;
                gload_lds(Ap + (size_t)(m0 + row) * lda + kk + sch * 8, As + grp * 512);
            }
        } else if (w < BM / 16) {
            int row = w * 16 + srow;
            gload_lds(Ap + (size_t)(m0 + row) * lda + kk + sch * 8, As + w * 512);
        }
#pragma unroll
        for (int g = 0; g < BN / 64; ++g) {
            int grp = w * (BN / 64) + g;
            int row = grp * 16 + srow;
            gload_lds(Bt + (size_t)(n0 + row) * ldb + k0 + sch * 8, Bs + grp * 512);
        }
        __syncthreads();

        const int r  = l & 15;
        const int ch = l >> 4;
        bf16x8 af[FI], bfr[FJ];
#pragma unroll
        for (int i = 0; i < FI; ++i) {
            int ar = wr * WM + i * 16 + r;
            af[i] = *(const bf16x8*)((const char*)As + ar * 64 + ((ch ^ (r & 3)) * 16));
        }
#pragma unroll
        for (int j = 0; j < FJ; ++j) {
            int br = wc * WN + j * 16 + r;
            bfr[j] = *(const bf16x8*)((const char*)Bs + br * 64 + ((ch ^ (r & 3)) * 16));
        }
#pragma unroll
        for (int i = 0; i < FI; ++i)
#pragma unroll
            for (int j = 0; j < FJ; ++j)
                acc[i][j] = __builtin_amdgcn_mfma_f32_16x16x32_bf16(af[i], bfr[j], acc[i][j], 0, 0, 0);
        __syncthreads();
    }

    const int r  = l & 15;
    const int q4 = l >> 4;
#pragma unroll
    for (int i = 0; i < FI; ++i)
#pragma unroll
        for (int j = 0; j < FJ; ++j) {
            int col = n0 + wc * WN + j * 16 + r;
#pragma unroll
            for (int reg = 0; reg < 4; ++reg) {
                int row = m0 + wr * WM + i * 16 + q4 * 4 + reg;
                float vv = acc[i][j][reg];
                if (flags & 1) vv = fmaxf(vv, 0.f);
                size_t off;
                int colw, Nw;
                if (flags & 4) { off = (size_t)(col >> 8) * M * 256; colw = col & 255; Nw = 256; }
                else           { off = 0; colw = col; Nw = N; }
                if (flags & 8) {
                    _Float16 hv = (_Float16)vv;
                    ((u16*)Cout)[off + (size_t)row * Nw + colw] = __builtin_bit_cast(u16, hv);
                } else if (flags & 2) {
                    ((u16*)Cout)[off + (size_t)row * Nw + colw] = f2bf(vv);
                } else {
                    ((float*)Cout)[off + (size_t)row * Nw + colw] = vv;
                }
            }
        }
}

// ---------------------------------------------------------------------------
// One MFMA phase of the fused tail: 32 rows x (FJ*32) cols, BK=32.
// A = concat(A0, A1) along K at splitK. Bt is [N][K] row-major, ldb = K.
// ---------------------------------------------------------------------------
template<int FJ>
__device__ __forceinline__ void mm_loop(
    const u16* __restrict__ A0, int lda0,
    const u16* __restrict__ A1, int lda1, int splitK,
    const u16* __restrict__ Bt, int ldb, int K, int m0,
    u16* As, u16* Bs, f32x4 (&acc)[FJ])
{
    const int t = threadIdx.x;
    const int l = t & 63, w = t >> 6;
    const int wr = w >> 1, wc = w & 1;
    const int srow = l >> 2;
    const int sch  = (l & 3) ^ (srow & 3);
    const int r = l & 15, ch = l >> 4;

#pragma unroll
    for (int j = 0; j < FJ; ++j) acc[j] = (f32x4){0.f, 0.f, 0.f, 0.f};

    for (int k0 = 0; k0 < K; k0 += 32) {
        const u16* Ap; int kk, lda;
        if (splitK && k0 >= splitK) { Ap = A1; kk = k0 - splitK; lda = lda1; }
        else                        { Ap = A0; kk = k0;          lda = lda0; }
        if (w < 2) {
            int row = w * 16 + srow;
            gload_lds(Ap + (size_t)(m0 + row) * lda + kk + sch * 8, As + w * 512);
        }
#pragma unroll
        for (int g = 0; g < FJ / 2; ++g) {     // N/64 groups per wave
            int grp = w * (FJ / 2) + g;
            int row = grp * 16 + srow;
            gload_lds(Bt + (size_t)row * ldb + k0 + sch * 8, Bs + grp * 512);
        }
        __syncthreads();
        bf16x8 af = *(const bf16x8*)((const char*)As + (wr * 16 + r) * 64 + ((ch ^ (r & 3)) * 16));
#pragma unroll
        for (int j = 0; j < FJ; ++j) {
            int br = wc * (FJ * 16) + j * 16 + r;
            bf16x8 bf = *(const bf16x8*)((const char*)Bs + br * 64 + ((ch ^ (r & 3)) * 16));
            acc[j] = __builtin_amdgcn_mfma_f32_16x16x32_bf16(af, bf, acc[j], 0, 0, 0);
        }
        __syncthreads();
    }
}

// ---------------------------------------------------------------------------
// Fused tail: per 32-row block, msg@Wm -> LN1 -> concat(x,·)@W1 -> relu ->
// @W2 -> LN2 -> +x -> out. Intermediates round-trip block-private global
// scratch (L2-resident); RAW safe via threadfence_block + vmcnt drain.
// ---------------------------------------------------------------------------
__global__ __launch_bounds__(256) void tail_kernel(
    const u16* __restrict__ msg, const u16* __restrict__ xb,
    const float* __restrict__ x,
    const u16* __restrict__ Wmt, const u16* __restrict__ W1t,
    const u16* __restrict__ W2t,
    const float* __restrict__ g1, const float* __restrict__ b1,
    const float* __restrict__ g2, const float* __restrict__ b2,
    u16* __restrict__ msglnb, u16* __restrict__ h1b,
    float* __restrict__ out)
{
    __shared__ __align__(16) u16 As[32 * 32];
    __shared__ __align__(16) u16 Bs[512 * 32];
    __shared__ float2 red[32][2];

    const int t = threadIdx.x;
    const int l = t & 63, w = t >> 6;
    const int wr = w >> 1, wc = w & 1;
    const int m0 = blockIdx.x * 32;
    const int r = l & 15, q4 = l >> 4;

    // ================= Phase A: msgln = LN1(msg @ Wm) ====================
    {
        f32x4 acc[8];
        mm_loop<8>(msg, 256, nullptr, 0, 0, Wmt, 256, 256, m0, As, Bs, acc);

        float rs[4], rq[4];
#pragma unroll
        for (int reg = 0; reg < 4; ++reg) {
            float s = 0.f, sq = 0.f;
#pragma unroll
            for (int j = 0; j < 8; ++j) { float vv = acc[j][reg]; s += vv; sq += vv * vv; }
            rs[reg] = s; rq[reg] = sq;
        }
#pragma unroll
        for (int off = 1; off <= 8; off <<= 1)
#pragma unroll
            for (int reg = 0; reg < 4; ++reg) {
                rs[reg] += __shfl_xor(rs[reg], off);
                rq[reg] += __shfl_xor(rq[reg], off);
            }
        if (r == 0)
#pragma unroll
            for (int reg = 0; reg < 4; ++reg)
                red[wr * 16 + q4 * 4 + reg][wc] = make_float2(rs[reg], rq[reg]);
        __syncthreads();

#pragma unroll
        for (int reg = 0; reg < 4; ++reg) {
            int row = wr * 16 + q4 * 4 + reg;
            float2 t0 = red[row][0], t1 = red[row][1];
            float mu  = (t0.x + t1.x) * 0.00390625f;
            float var = (t0.y + t1.y) * 0.00390625f - mu * mu;
            float rstd = rsqrtf(var + LN_EPS);
#pragma unroll
            for (int j = 0; j < 8; ++j) {
                int col = wc * 128 + j * 16 + r;
                float vv = (acc[j][reg] - mu) * rstd * g1[col] + b1[col];
                msglnb[(size_t)(m0 + row) * 256 + col] = f2bf(vv);
            }
        }
    }
    __threadfence_block();
    __syncthreads();

    // ============ Phase B: h1 = relu(concat(xb, msgln) @ W1) =============
    {
        f32x4 acc[16];
        mm_loop<16>(xb, 256, msglnb, 256, 256, W1t, 512, 512, m0, As, Bs, acc);
#pragma unroll
        for (int j = 0; j < 16; ++j) {
            int col = wc * 256 + j * 16 + r;
#pragma unroll
            for (int reg = 0; reg < 4; ++reg) {
                int row = wr * 16 + q4 * 4 + reg;
                float vv = fmaxf(acc[j][reg], 0.f);
                h1b[(size_t)(m0 + row) * 512 + col] = f2bf(vv);
            }
        }
    }
    __threadfence_block();
    __syncthreads();

    // ============ Phase C: out = x + LN2(h1 @ W2) ========================
    {
        f32x4 acc[8];
        mm_loop<8>(h1b, 512, nullptr, 0, 0, W2t, 512, 512, m0, As, Bs, acc);

        float rs[4], rq[4];
#pragma unroll
        for (int reg = 0; reg < 4; ++reg) {
            float s = 0.f, sq = 0.f;
#pragma unroll
            for (int j = 0; j < 8; ++j) { float vv = acc[j][reg]; s += vv; sq += vv * vv; }
            rs[reg] = s; rq[reg] = sq;
        }
#pragma unroll
        for (int off = 1; off <= 8; off <<= 1)
#pragma unroll
            for (int reg = 0; reg < 4; ++reg) {
                rs[reg] += __shfl_xor(rs[reg], off);
                rq[reg] += __shfl_xor(rq[reg], off);
            }
        __syncthreads();   // red reuse from phase A
        if (r == 0)
#pragma unroll
            for (int reg = 0; reg < 4; ++reg)
                red[wr * 16 + q4 * 4 + reg][wc] = make_float2(rs[reg], rq[reg]);
        __syncthreads();

#pragma unroll
        for (int reg = 0; reg < 4; ++reg) {
            int row = wr * 16 + q4 * 4 + reg;
            float2 t0 = red[row][0], t1 = red[row][1];
            float mu  = (t0.x + t1.x) * 0.00390625f;
            float var = (t0.y + t1.y) * 0.00390625f - mu * mu;
            float rstd = rsqrtf(var + LN_EPS);
#pragma unroll
            for (int j = 0; j < 8; ++j) {
                int col = wc * 128 + j * 16 + r;
                size_t oidx = (size_t)(m0 + row) * 256 + col;
                float vv = (acc[j][reg] - mu) * rstd * g2[col] + b2[col] + x[oidx];
                out[oidx] = vv;
            }
        }
    }
}

// ---------------------------------------------------------------------------
// Gathered attention: wave = (query, head-pair), 128B oct-coalesced gathers.
// q,k,v: [MROWS,256] fp16 head-major. msg out: bf16. Block = 1 query, 4 waves.
// No LDS, no barriers. At the random-access L2-BW practical floor (~34 us).
// ---------------------------------------------------------------------------
__global__ __launch_bounds__(256, 8) void attn_kernel(
    const u16* __restrict__ q, const u16* __restrict__ k,
    const u16* __restrict__ v, const int* __restrict__ idx,
    u16* __restrict__ msg)
{
    const int t  = threadIdx.x;
    const int l  = t & 63;
    const int hp = t >> 6;              // head-pair 0..3
    const int qi = blockIdx.x;
    const int n  = qi / LQ;
    const size_t srcbase = (size_t)n * LQ * 256;   // u16 units

    const int o = l >> 3;   // key-set 0..7
    const int c = l & 7;    // 16B chunk of 128B slice

    const int* idxp = idx + (size_t)qi * 64;
    int rows[8];
#pragma unroll
    for (int i = 0; i < 8; ++i) rows[i] = idxp[i * 8 + o];   // 8-lane broadcast

    const size_t hoff = (size_t)hp * 64 + c * 8;   // u16 offset in a row

    // ---- K phase ----
    uint4 kd[8];
#pragma unroll
    for (int i = 0; i < 8; ++i)
        kd[i] = *(const uint4*)(k + srcbase + (size_t)rows[i] * 256 + hoff);
    uint4 qc = *(const uint4*)(q + (size_t)qi * 256 + hoff);

    float s[8];
#pragma unroll
    for (int i = 0; i < 8; ++i) {
        float si = 0.f;
        si = dot2f16(kd[i].x, qc.x, si);
        si = dot2f16(kd[i].y, qc.y, si);
        si = dot2f16(kd[i].z, qc.z, si);
        si = dot2f16(kd[i].w, qc.w, si);
        si += __shfl_xor(si, 1);
        si += __shfl_xor(si, 2);
        s[i] = si * 0.17677669529663687f;
    }

    // ---- V phase ----
    uint4 vd[8];
#pragma unroll
    for (int i = 0; i < 8; ++i)
        vd[i] = *(const uint4*)(v + srcbase + (size_t)rows[i] * 256 + hoff);

    // ---- softmax over 64 keys ----
    float mx = s[0];
#pragma unroll
    for (int i = 1; i < 8; ++i) mx = fmaxf(mx, s[i]);
    mx = fmaxf(mx, __shfl_xor(mx, 8));
    mx = fmaxf(mx, __shfl_xor(mx, 16));
    mx = fmaxf(mx, __shfl_xor(mx, 32));
    float p[8], sum = 0.f;
#pragma unroll
    for (int i = 0; i < 8; ++i) { p[i] = __expf(s[i] - mx); sum += p[i]; }
    sum += __shfl_xor(sum, 8);
    sum += __shfl_xor(sum, 16);
    sum += __shfl_xor(sum, 32);
    float inv = 1.f / sum;

    // ---- PV ----
    u32 A0 = 0, A1 = 0, A2 = 0, A3 = 0;
#pragma unroll
    for (int i = 0; i < 8; ++i) {
        float pi = p[i] * inv;
        u32 pp = pkrtz(pi, pi);
        A0 = pk_fma16(pp, vd[i].x, A0);
        A1 = pk_fma16(pp, vd[i].y, A1);
        A2 = pk_fma16(pp, vd[i].z, A2);
        A3 = pk_fma16(pp, vd[i].w, A3);
    }

    // ---- split-reduce over the 8 o-sets ----
    const bool ob0 = (o & 1) != 0;
    const bool ob1 = (o & 2) != 0;
    {
        u32 t0 = ob0 ? A0 : A2;
        u32 t1 = ob0 ? A1 : A3;
        t0 = __shfl_xor((int)t0, 8);
        t1 = __shfl_xor((int)t1, 8);
        A0 = pk_add16(ob0 ? A2 : A0, t0);
        A1 = pk_add16(ob0 ? A3 : A1, t1);
    }
    {
        u32 u0 = ob1 ? A0 : A1;
        u0 = __shfl_xor((int)u0, 16);
        A0 = pk_add16(ob1 ? A1 : A0, u0);
    }
    A0 = pk_add16(A0, (u32)__shfl_xor((int)A0, 32));

    if (o < 4) {
        int j = 2 * (o & 1) + ((o >> 1) & 1);
        f16x2 hv = __builtin_bit_cast(f16x2, A0);
        u32 packed = (u32)f2bf((float)hv.x) | ((u32)f2bf((float)hv.y) << 16);
        *(u32*)(msg + (size_t)qi * 256 + hp * 64 + c * 8 + j * 2) = packed;
    }
}

// ---------------------------------------------------------------------------
extern "C" void kernel_launch(void* const* d_in, const int* in_sizes, int n_in,
                              void* d_out, int out_size, void* d_ws, size_t ws_size,
                              hipStream_t stream)
{
    const float* x      = (const float*)d_in[0];
    const float* source = (const float*)d_in[1];
    const int*   eidx   = (const int*)d_in[2];
    const float* Wq     = (const float*)d_in[3];
    const float* Wk     = (const float*)d_in[4];
    const float* Wv     = (const float*)d_in[5];
    const float* Wm     = (const float*)d_in[6];
    const float* W1     = (const float*)d_in[7];
    const float* W2     = (const float*)d_in[8];
    const float* g1     = (const float*)d_in[9];
    const float* b1     = (const float*)d_in[10];
    const float* g2     = (const float*)d_in[11];
    const float* b2     = (const float*)d_in[12];
    float* out = (float*)d_out;

    char* ws = (char*)d_ws;
    const size_t SZB = (size_t)MROWS * 256 * 2;    // 4.9 MB
    u16* xb     = (u16*)(ws);                      // bf16, live until tail
    u16* sb     = (u16*)(ws + SZB);                // bf16, dead after qkv gemm
    u16* qb     = (u16*)(ws + 2 * SZB);            // f16, qkv gemm seg 0
    u16* kb     = (u16*)(ws + 3 * SZB);            // f16, seg 1
    u16* vb     = (u16*)(ws + 4 * SZB);            // f16, seg 2
    u16* msgb   = (u16*)(ws + 5 * SZB);            // bf16 attn output
    u16* msglnb = (u16*)(ws + 6 * SZB);            // bf16 tail scratch
    u16* h1b    = (u16*)(ws + 7 * SZB);            // bf16 [9600][512] tail scratch
    u16* Wqkvt  = (u16*)(ws + 9 * SZB);            // [768][256]
    u16* Wmt    = Wqkvt + 768 * 256;
    u16* W1t    = Wmt + 256 * 256;                 // [512][512]
    u16* W2t    = W1t + 512 * 512;                 // [256][512]

    dim3 blk(256);

    // fused prep: casts + all weight transposes
    prep_kernel<<<dim3(7360), blk, 0, stream>>>(x, source, Wq, Wk, Wv, Wm, W1, W2,
                                                xb, sb, Wqkvt, Wmt, W1t, W2t);

    // fused q|k|v projection, f16 out, 64x128 tiles (900 blocks)
    gemm_mfma_kernel<64, 128><<<dim3(6, 150), blk, 0, stream>>>(
        xb, 256, sb, 256, 0, 256, Wqkvt, 256, qb, MROWS, 768, 256, 8 | 4);

    // gathered attention -> msg (bf16); one block per query
    attn_kernel<<<dim3(MROWS), blk, 0, stream>>>(qb, kb, vb, eidx, msgb);

    // fused tail: Wm+LN1+W1+relu+W2+LN2+residual in one kernel (300 blocks)
    tail_kernel<<<dim3(300), blk, 0, stream>>>(
        msgb, xb, x, Wmt, W1t, W2t, g1, b1, g2, b2, msglnb, h1b, out);
}